// Round 4
// baseline (1147.960 us; speedup 1.0000x reference)
//
#include <hip/hip_runtime.h>
#include <hip/hip_bf16.h>

#define DEV_INLINE __device__ __forceinline__

constexpr int NLAYERS = 2;
constexpr int DM = 512;
constexpr int NH = 8;
constexpr int DHD = 64;
constexpr int FF = 2048;
constexpr int TD = 8;
constexpr int BB = 8;
constexpr int LL = 512;
constexpr int ROWS = BB * LL;  // 4096
constexpr int QKVN = 3 * DM;   // 1536

constexpr float TWO_PI_F = 6.28318530717958647692f;
constexpr float INV_E8 = 3.3546262790251185e-4f;  // e^-8

typedef __attribute__((ext_vector_type(8))) short short8v;
typedef __attribute__((ext_vector_type(4))) float f32x4;

DEV_INLINE unsigned short bf16_rne(float x) {
  unsigned int u = __float_as_uint(x);
  unsigned int r = (u + 0x7fffu + ((u >> 16) & 1u)) >> 16;
  return (unsigned short)r;
}
DEV_INLINE float bf16_to_f(unsigned short h) {
  return __uint_as_float(((unsigned int)h) << 16);
}
DEV_INLINE void split_bf16(float x, unsigned short& h, unsigned short& l) {
  h = bf16_rne(x);
  float lo = x - bf16_to_f(h);
  l = bf16_rne(lo);
}

// ---------------------------------------------------------------------------
// Small FFNs on t
// ---------------------------------------------------------------------------
DEV_INLINE void ffn2_small(float tv,
                           const float* __restrict__ w1, const float* __restrict__ b1,
                           const float* __restrict__ w2, const float* __restrict__ b2,
                           float* out) {
  float h[TD];
#pragma unroll
  for (int d = 0; d < TD; ++d) h[d] = fmaxf(tv * w1[d] + b1[d], 0.f);
#pragma unroll
  for (int j = 0; j < TD; ++j) {
    float acc = b2[j];
#pragma unroll
    for (int d = 0; d < TD; ++d) acc += h[d] * w2[d * TD + j];
    out[j] = fmaxf(acc, 0.f);
  }
}

__global__ __launch_bounds__(256) void small_ffn_kernel(
    const float* __restrict__ t,
    const float* __restrict__ pw1, const float* __restrict__ pb1,
    const float* __restrict__ pw2, const float* __restrict__ pb2,
    const float* __restrict__ sw1, const float* __restrict__ sb1,
    const float* __restrict__ sw2, const float* __restrict__ sb2,
    const float* __restrict__ bw1, const float* __restrict__ bb1,
    const float* __restrict__ bw2, const float* __restrict__ bb2,
    float* __restrict__ tp, float* __restrict__ sg, float* __restrict__ be) {
  const int i = blockIdx.x * 256 + threadIdx.x;
  if (i >= ROWS) return;
  const float tv = t[i];
  float o[TD];
  ffn2_small(tv, pw1, pb1, pw2, pb2, o);
#pragma unroll
  for (int d = 0; d < TD; ++d) tp[(size_t)i * TD + d] = TWO_PI_F * o[d] * tv;
  ffn2_small(tv, sw1, sb1, sw2, sb2, o);
#pragma unroll
  for (int d = 0; d < TD; ++d) sg[(size_t)i * TD + d] = o[d] + 1e-6f;
  ffn2_small(tv, bw1, bb1, bw2, bb2, o);
#pragma unroll
  for (int d = 0; d < TD; ++d) be[(size_t)i * TD + d] = o[d];
}

// ---------------------------------------------------------------------------
// kern kernel
// ---------------------------------------------------------------------------
DEV_INLINE void load8(const float* __restrict__ p, float* o) {
  float4 a = *reinterpret_cast<const float4*>(p);
  float4 b = *reinterpret_cast<const float4*>(p + 4);
  o[0] = a.x; o[1] = a.y; o[2] = a.z; o[3] = a.w;
  o[4] = b.x; o[5] = b.y; o[6] = b.z; o[7] = b.w;
}

__global__ __launch_bounds__(256) void kern_kernel(
    const float* __restrict__ t, const float* __restrict__ tp,
    const float* __restrict__ sg, const float* __restrict__ be,
    float* __restrict__ kernS) {
  const int k = blockIdx.x * 256 + threadIdx.x;
  const int q = blockIdx.y;
  const int b = blockIdx.z;
  const size_t iq = (size_t)b * LL + q;
  const size_t ik = (size_t)b * LL + k;
  const float tq = t[iq], tk = t[ik];
  const float diff = tq - tk;
  const float d2 = diff * diff;

  float tpq[TD], sgq[TD], beq[TD], tpk[TD], sgk[TD], bek[TD];
  load8(tp + iq * TD, tpq);
  load8(sg + iq * TD, sgq);
  load8(be + iq * TD, beq);
  load8(tp + ik * TD, tpk);
  load8(sg + ik * TD, sgk);
  load8(be + ik * TD, bek);

  float acc = 0.f;
#pragma unroll
  for (int d = 0; d < TD; ++d) {
    const float sq = sgq[d], sk = sgk[d];
    const float denom = sq * sq + sk * sk;
    const float inv = 1.0f / denom;
    const float e = __expf(-d2 * inv);
    const float loc = sqrtf(2.0f * sq * sk * inv);
    const float c = __cosf(tpq[d] - tpk[d]);
    acc += beq[d] * bek[d] * loc * e * c;
  }
  kernS[((size_t)b * LL + q) * LL + k] = acc * INV_E8;
}

// ---------------------------------------------------------------------------
// Weight transpose + hi/lo bf16 decompose: W[K][N] fp32 -> Thi/Tlo[N][K] bf16
// ---------------------------------------------------------------------------
__global__ __launch_bounds__(256) void td_kernel(
    const float* __restrict__ W, unsigned short* __restrict__ Thi,
    unsigned short* __restrict__ Tlo, int K, int N) {
  __shared__ float tile[32][33];
  const int k0 = blockIdx.x * 32, n0 = blockIdx.y * 32;
  const int tx = threadIdx.x & 31, ty = threadIdx.x >> 5;
#pragma unroll
  for (int i = 0; i < 4; ++i)
    tile[ty + i * 8][tx] = W[(size_t)(k0 + ty + i * 8) * N + n0 + tx];
  __syncthreads();
#pragma unroll
  for (int i = 0; i < 4; ++i) {
    const int n = n0 + ty + i * 8;
    const float v = tile[tx][ty + i * 8];
    unsigned short h, l;
    split_bf16(v, h, l);
    Thi[(size_t)n * K + k0 + tx] = h;
    Tlo[(size_t)n * K + k0 + tx] = l;
  }
}

// ---------------------------------------------------------------------------
// Elementwise hi/lo decompose (for layer-0 x). 4 elems/thread.
// ---------------------------------------------------------------------------
__global__ __launch_bounds__(256) void decomp_kernel(
    const float* __restrict__ X, unsigned short* __restrict__ Hi,
    unsigned short* __restrict__ Lo, int n4) {
  const int i = blockIdx.x * 256 + threadIdx.x;
  if (i >= n4) return;
  const float4 v = *reinterpret_cast<const float4*>(X + (size_t)i * 4);
  unsigned short h0, h1, h2, h3, l0, l1, l2, l3;
  split_bf16(v.x, h0, l0);
  split_bf16(v.y, h1, l1);
  split_bf16(v.z, h2, l2);
  split_bf16(v.w, h3, l3);
  uint2 hv, lv;
  hv.x = (unsigned)h0 | ((unsigned)h1 << 16);
  hv.y = (unsigned)h2 | ((unsigned)h3 << 16);
  lv.x = (unsigned)l0 | ((unsigned)l1 << 16);
  lv.y = (unsigned)l2 | ((unsigned)l3 << 16);
  *reinterpret_cast<uint2*>(Hi + (size_t)i * 4) = hv;
  *reinterpret_cast<uint2*>(Lo + (size_t)i * 4) = lv;
}

__global__ __launch_bounds__(256) void qkvbias_kernel(
    const float* __restrict__ bq, const float* __restrict__ bk,
    const float* __restrict__ bv, float* __restrict__ out) {
  const int i = blockIdx.x * 256 + threadIdx.x;
  if (i >= QKVN) return;
  out[i] = i < DM ? bq[i] : (i < 2 * DM ? bk[i - DM] : bv[i - 2 * DM]);
}

// ---------------------------------------------------------------------------
// Split-bf16 MFMA GEMM, single K-pass:
//   C = Ahi@Bhi + Alo@Bhi + Ahi@Blo (+bias, opt relu)
// SINGLE-buffer LDS (64/48 KB -> 2-3 blocks/CU), register prefetch of next
// k-tile, 2 barriers per k-step. XCD-bijective block swizzle.
// ---------------------------------------------------------------------------
template <int BN, bool RELU, bool SPLIT_OUT>
__global__ __launch_bounds__(256) void gemm_mfma(
    const unsigned short* __restrict__ Ahi, const unsigned short* __restrict__ Alo,
    const unsigned short* __restrict__ Bhi, const unsigned short* __restrict__ Blo,
    const float* __restrict__ bias, float* __restrict__ C,
    unsigned short* __restrict__ Chi, unsigned short* __restrict__ Clo,
    int M, int N, int K) {
  constexpr int BM = 128, BK = 64;
  constexpr int WT_M = 64;
  constexpr int WT_N = BN / 2;
  constexpr int MI = WT_M / 16;   // 4
  constexpr int NI = WT_N / 16;   // 4 or 2
  constexpr int A_IT = BM * BK / (256 * 8);  // 4
  constexpr int B_IT = BN * BK / (256 * 8);  // 4 or 2

  __shared__ unsigned short AsH[BM * BK];
  __shared__ unsigned short AsL[BM * BK];
  __shared__ unsigned short BsH[BN * BK];
  __shared__ unsigned short BsL[BN * BK];

  const int nwg = gridDim.x * gridDim.y;
  const int orig = blockIdx.y * gridDim.x + blockIdx.x;
  const int swz = (orig & 7) * (nwg >> 3) + (orig >> 3);
  const int bx = swz % gridDim.x;
  const int by = swz / gridDim.x;

  const int tid = threadIdx.x;
  const int lane = tid & 63;
  const int wid = tid >> 6;
  const int wr = wid >> 1, wc = wid & 1;
  const int rowBase = by * BM;
  const int colBase = bx * BN;
  const int l15 = lane & 15, l4 = lane >> 4;

  const int sg_ = tid & 7;
  const int srA = tid >> 3;
  const int swg = sg_ ^ (srA & 7);

  f32x4 acc[MI][NI] = {};
  const int nt = K / BK;

  uint4 ahR[A_IT], alR[A_IT], bhR[B_IT], blR[B_IT];

  auto loadRegs = [&](int kt) {
    const int k0 = kt * BK;
#pragma unroll
    for (int it = 0; it < A_IT; ++it) {
      const size_t base = (size_t)(rowBase + it * 32 + srA) * K + k0 + sg_ * 8;
      ahR[it] = *reinterpret_cast<const uint4*>(Ahi + base);
      alR[it] = *reinterpret_cast<const uint4*>(Alo + base);
    }
#pragma unroll
    for (int it = 0; it < B_IT; ++it) {
      const size_t base = (size_t)(colBase + it * 32 + srA) * K + k0 + sg_ * 8;
      bhR[it] = *reinterpret_cast<const uint4*>(Bhi + base);
      blR[it] = *reinterpret_cast<const uint4*>(Blo + base);
    }
  };

  auto writeLDS = [&]() {
#pragma unroll
    for (int it = 0; it < A_IT; ++it) {
      const int off = ((it * 32 + srA) << 6) + (swg << 3);
      *reinterpret_cast<uint4*>(&AsH[off]) = ahR[it];
      *reinterpret_cast<uint4*>(&AsL[off]) = alR[it];
    }
#pragma unroll
    for (int it = 0; it < B_IT; ++it) {
      const int off = ((it * 32 + srA) << 6) + (swg << 3);
      *reinterpret_cast<uint4*>(&BsH[off]) = bhR[it];
      *reinterpret_cast<uint4*>(&BsL[off]) = blR[it];
    }
  };

  loadRegs(0);

  for (int t = 0; t < nt; ++t) {
    writeLDS();
    __syncthreads();
    if (t + 1 < nt) loadRegs(t + 1);

#pragma unroll
    for (int ks = 0; ks < 2; ++ks) {
      short8v ah[MI], al[MI], bh[NI], bl[NI];
#pragma unroll
      for (int mi = 0; mi < MI; ++mi) {
        const int r = wr * WT_M + mi * 16 + l15;
        const int off = (r << 6) + (((ks * 4 + l4) ^ (r & 7)) << 3);
        ah[mi] = *reinterpret_cast<const short8v*>(&AsH[off]);
        al[mi] = *reinterpret_cast<const short8v*>(&AsL[off]);
      }
#pragma unroll
      for (int ni = 0; ni < NI; ++ni) {
        const int r = wc * WT_N + ni * 16 + l15;
        const int off = (r << 6) + (((ks * 4 + l4) ^ (r & 7)) << 3);
        bh[ni] = *reinterpret_cast<const short8v*>(&BsH[off]);
        bl[ni] = *reinterpret_cast<const short8v*>(&BsL[off]);
      }
#pragma unroll
      for (int mi = 0; mi < MI; ++mi)
#pragma unroll
        for (int ni = 0; ni < NI; ++ni) {
          acc[mi][ni] = __builtin_amdgcn_mfma_f32_16x16x32_bf16(ah[mi], bh[ni], acc[mi][ni], 0, 0, 0);
          acc[mi][ni] = __builtin_amdgcn_mfma_f32_16x16x32_bf16(al[mi], bh[ni], acc[mi][ni], 0, 0, 0);
          acc[mi][ni] = __builtin_amdgcn_mfma_f32_16x16x32_bf16(ah[mi], bl[ni], acc[mi][ni], 0, 0, 0);
        }
    }
    if (t + 1 < nt) __syncthreads();
  }

#pragma unroll
  for (int mi = 0; mi < MI; ++mi) {
#pragma unroll
    for (int ni = 0; ni < NI; ++ni) {
      const int col = colBase + wc * WT_N + ni * 16 + l15;
      const float bv = bias[col];
#pragma unroll
      for (int j = 0; j < 4; ++j) {
        const int row = rowBase + wr * WT_M + mi * 16 + l4 * 4 + j;
        float v = acc[mi][ni][j] + bv;
        if (RELU) v = fmaxf(v, 0.f);
        if (SPLIT_OUT) {
          unsigned short h, l;
          split_bf16(v, h, l);
          Chi[(size_t)row * N + col] = h;
          Clo[(size_t)row * N + col] = l;
        } else {
          C[(size_t)row * N + col] = v;
        }
      }
    }
  }
}

// ---------------------------------------------------------------------------
// K transpose: qkvb k-slice -> ktb[bh][d][kk]  (fp32)
// ---------------------------------------------------------------------------
__global__ __launch_bounds__(256) void txp_kernel(
    const float* __restrict__ qkvb, float* __restrict__ ktb) {
  __shared__ float tile[32][33];
  const int bh = blockIdx.z;
  const int b = bh >> 3, h = bh & 7;
  const int kk0 = blockIdx.x * 32, d0 = blockIdx.y * 32;
  const int tx = threadIdx.x & 31, ty = threadIdx.x >> 5;
#pragma unroll
  for (int i = 0; i < 4; ++i) {
    const int kk = kk0 + ty + i * 8;
    tile[ty + i * 8][tx] = qkvb[(size_t)(b * LL + kk) * QKVN + DM + h * DHD + d0 + tx];
  }
  __syncthreads();
#pragma unroll
  for (int i = 0; i < 4; ++i) {
    const int d = d0 + ty + i * 8;
    ktb[((size_t)bh * DHD + d) * LL + kk0 + tx] = tile[tx][ty + i * 8];
  }
}

// ---------------------------------------------------------------------------
// Fused attention v2: 512 threads, one kk per thread in phase 1, in-register
// softmax reductions, 12-word LDS row stride (conflict-free b128), XCD-swizzle
// with h fastest so kernS rows / K/V slices stay in one XCD's L2.
// grid (NH, LL/TQ, BB) = (8, 64, 8).
// ---------------------------------------------------------------------------
constexpr int TQ = 8;

__global__ __launch_bounds__(512) void attn_kernel(
    const float* __restrict__ qkvb, const float* __restrict__ ktb,
    const float* __restrict__ kernS,
    unsigned short* __restrict__ ctxhi, unsigned short* __restrict__ ctxlo) {
  // XCD-aware remap: hw id -> logical work w; consecutive w (h fastest) share
  // kernS rows and land on the same XCD.
  const int id = blockIdx.x + 8 * (blockIdx.y + 64 * blockIdx.z);
  const int w = (id & 7) * 512 + (id >> 3);
  const int h = w & 7;
  const int qt = (w >> 3) & 63;
  const int b = w >> 9;
  const int tid = threadIdx.x;
  const int q0 = qt * TQ;

  __shared__ float qst[DHD][TQ];     // 2 KB
  __shared__ float lst[LL][12];      // 24.6 KB (stride 48B: b128-aligned, conflict-free)
  __shared__ float red[8][TQ][DHD];  // 16 KB
  __shared__ float wred[8][TQ];
  __shared__ float gmax[TQ], ginv[TQ];

  // load q transposed: consecutive tid -> consecutive LDS words
  {
    const int qq = tid & 7, d = tid >> 3;  // 512 threads cover [64][8]
    qst[d][qq] = qkvb[(size_t)(b * LL + q0 + qq) * QKVN + h * DHD + d];
  }
  __syncthreads();

  // phase 1: logits for kk = tid
  const int kk = tid;
  float dot[TQ] = {};
  {
    const float* kcol = ktb + (size_t)(b * NH + h) * DHD * LL + kk;
#pragma unroll 8
    for (int d = 0; d < DHD; ++d) {
      const float ka = kcol[(size_t)d * LL];
      const float4 qa = *reinterpret_cast<const float4*>(&qst[d][0]);
      const float4 qb = *reinterpret_cast<const float4*>(&qst[d][4]);
      dot[0] += qa.x * ka; dot[1] += qa.y * ka; dot[2] += qa.z * ka; dot[3] += qa.w * ka;
      dot[4] += qb.x * ka; dot[5] += qb.y * ka; dot[6] += qb.z * ka; dot[7] += qb.w * ka;
    }
    const size_t kbase = ((size_t)b * LL + q0) * LL + kk;
#pragma unroll
    for (int qq = 0; qq < TQ; ++qq)
      dot[qq] = dot[qq] * 0.125f + kernS[kbase + (size_t)qq * LL];
  }

  const int lane = tid & 63;
  const int wv = tid >> 6;

  // max reduce (in-register wave shuffle + cross-wave LDS)
  {
    float mv[TQ];
#pragma unroll
    for (int qq = 0; qq < TQ; ++qq) mv[qq] = dot[qq];
#pragma unroll
    for (int s = 1; s < 64; s <<= 1)
#pragma unroll
      for (int qq = 0; qq < TQ; ++qq) mv[qq] = fmaxf(mv[qq], __shfl_xor(mv[qq], s, 64));
    if (lane == 0) {
#pragma unroll
      for (int qq = 0; qq < TQ; ++qq) wred[wv][qq] = mv[qq];
    }
  }
  __syncthreads();
  if (tid < TQ) {
    float m = wred[0][tid];
#pragma unroll
    for (int w2 = 1; w2 < 8; ++w2) m = fmaxf(m, wred[w2][tid]);
    gmax[tid] = m;
  }
  __syncthreads();

  // exp + store P + sum reduce
  {
    float sv[TQ];
#pragma unroll
    for (int qq = 0; qq < TQ; ++qq) sv[qq] = __expf(dot[qq] - gmax[qq]);
    float4 p0, p1;
    p0.x = sv[0]; p0.y = sv[1]; p0.z = sv[2]; p0.w = sv[3];
    p1.x = sv[4]; p1.y = sv[5]; p1.z = sv[6]; p1.w = sv[7];
    *reinterpret_cast<float4*>(&lst[kk][0]) = p0;
    *reinterpret_cast<float4*>(&lst[kk][4]) = p1;
#pragma unroll
    for (int s = 1; s < 64; s <<= 1)
#pragma unroll
      for (int qq = 0; qq < TQ; ++qq) sv[qq] += __shfl_xor(sv[qq], s, 64);
    if (lane == 0) {
#pragma unroll
      for (int qq = 0; qq < TQ; ++qq) wred[wv][qq] = sv[qq];
    }
  }
  __syncthreads();
  if (tid < TQ) {
    float s = wred[0][tid];
#pragma unroll
    for (int w2 = 1; w2 < 8; ++w2) s += wred[w2][tid];
    ginv[tid] = 1.0f / s;
  }
  __syncthreads();

  // phase 2: ctx = P @ V, 8 chunks of 64 kk
  const int d = tid & 63;
  const int c = tid >> 6;
  float acc[TQ] = {};
  {
    const float* vbase = qkvb + (size_t)(b * LL) * QKVN + 2 * DM + h * DHD + d;
    for (int k2 = c * 64; k2 < c * 64 + 64; ++k2) {
      const float vvv = vbase[(size_t)k2 * QKVN];
      const float4 pa = *reinterpret_cast<const float4*>(&lst[k2][0]);
      const float4 pb = *reinterpret_cast<const float4*>(&lst[k2][4]);
      acc[0] += pa.x * vvv; acc[1] += pa.y * vvv; acc[2] += pa.z * vvv; acc[3] += pa.w * vvv;
      acc[4] += pb.x * vvv; acc[5] += pb.y * vvv; acc[6] += pb.z * vvv; acc[7] += pb.w * vvv;
    }
  }
#pragma unroll
  for (int qq = 0; qq < TQ; ++qq) red[c][qq][d] = acc[qq];
  __syncthreads();
  if (c == 0) {
#pragma unroll
    for (int qq = 0; qq < TQ; ++qq) {
      float r = red[0][qq][d];
#pragma unroll
      for (int cc = 1; cc < 8; ++cc) r += red[cc][qq][d];
      r *= ginv[qq];
      unsigned short hh, ll;
      split_bf16(r, hh, ll);
      const size_t o = (size_t)(b * LL + q0 + qq) * DM + h * DHD + d;
      ctxhi[o] = hh;
      ctxlo[o] = ll;
    }
  }
}

// ---------------------------------------------------------------------------
// Fused residual + LayerNorm; writes fp32 + bf16 hi/lo decomposition.
// ---------------------------------------------------------------------------
__global__ __launch_bounds__(256) void resid_ln_kernel(
    const float* __restrict__ X, const float* __restrict__ R,
    const float* __restrict__ g, const float* __restrict__ bta,
    float* __restrict__ Out, unsigned short* __restrict__ OutHi,
    unsigned short* __restrict__ OutLo) {
  const int row = blockIdx.x * 4 + (threadIdx.x >> 6);
  const int lane = threadIdx.x & 63;
  const float* x = X + (size_t)row * DM;
  const float* r = R + (size_t)row * DM;

  float v[8];
  float s = 0.f;
#pragma unroll
  for (int j = 0; j < 2; ++j) {
    const float4 a = *reinterpret_cast<const float4*>(x + lane * 8 + j * 4);
    const float4 c = *reinterpret_cast<const float4*>(r + lane * 8 + j * 4);
    v[j * 4 + 0] = a.x + c.x;
    v[j * 4 + 1] = a.y + c.y;
    v[j * 4 + 2] = a.z + c.z;
    v[j * 4 + 3] = a.w + c.w;
    s += v[j * 4 + 0] + v[j * 4 + 1] + v[j * 4 + 2] + v[j * 4 + 3];
  }
#pragma unroll
  for (int m = 1; m < 64; m <<= 1) s += __shfl_xor(s, m, 64);
  const float mean = s * (1.f / DM);
  float var = 0.f;
#pragma unroll
  for (int j = 0; j < 8; ++j) {
    const float dlt = v[j] - mean;
    var += dlt * dlt;
  }
#pragma unroll
  for (int m = 1; m < 64; m <<= 1) var += __shfl_xor(var, m, 64);
  var *= (1.f / DM);
  const float inv = 1.0f / sqrtf(var + 1e-6f);

  unsigned short hs[8], ls[8];
#pragma unroll
  for (int j = 0; j < 2; ++j) {
    const float4 gg = *reinterpret_cast<const float4*>(g + lane * 8 + j * 4);
    const float4 bb = *reinterpret_cast<const float4*>(bta + lane * 8 + j * 4);
    float4 o;
    o.x = (v[j * 4 + 0] - mean) * inv * gg.x + bb.x;
    o.y = (v[j * 4 + 1] - mean) * inv * gg.y + bb.y;
    o.z = (v[j * 4 + 2] - mean) * inv * gg.z + bb.z;
    o.w = (v[j * 4 + 3] - mean) * inv * gg.w + bb.w;
    *reinterpret_cast<float4*>(Out + (size_t)row * DM + lane * 8 + j * 4) = o;
    split_bf16(o.x, hs[j * 4 + 0], ls[j * 4 + 0]);
    split_bf16(o.y, hs[j * 4 + 1], ls[j * 4 + 1]);
    split_bf16(o.z, hs[j * 4 + 2], ls[j * 4 + 2]);
    split_bf16(o.w, hs[j * 4 + 3], ls[j * 4 + 3]);
  }
  uint4 hv, lv;
  hv.x = (unsigned)hs[0] | ((unsigned)hs[1] << 16);
  hv.y = (unsigned)hs[2] | ((unsigned)hs[3] << 16);
  hv.z = (unsigned)hs[4] | ((unsigned)hs[5] << 16);
  hv.w = (unsigned)hs[6] | ((unsigned)hs[7] << 16);
  lv.x = (unsigned)ls[0] | ((unsigned)ls[1] << 16);
  lv.y = (unsigned)ls[2] | ((unsigned)ls[3] << 16);
  lv.z = (unsigned)ls[4] | ((unsigned)ls[5] << 16);
  lv.w = (unsigned)ls[6] | ((unsigned)ls[7] << 16);
  *reinterpret_cast<uint4*>(OutHi + (size_t)row * DM + lane * 8) = hv;
  *reinterpret_cast<uint4*>(OutLo + (size_t)row * DM + lane * 8) = lv;
}

// ---------------------------------------------------------------------------
// launch
// ---------------------------------------------------------------------------
extern "C" void kernel_launch(void* const* d_in, const int* in_sizes, int n_in,
                              void* d_out, int out_size, void* d_ws, size_t ws_size,
                              hipStream_t stream) {
  const float* x_in = (const float*)d_in[0];
  const float* t = (const float*)d_in[1];
  const float* wq = (const float*)d_in[2];
  const float* bq = (const float*)d_in[3];
  const float* wk = (const float*)d_in[4];
  const float* bk = (const float*)d_in[5];
  const float* wv = (const float*)d_in[6];
  const float* bv = (const float*)d_in[7];
  const float* wo = (const float*)d_in[8];
  const float* bo = (const float*)d_in[9];
  const float* w1 = (const float*)d_in[10];
  const float* b1 = (const float*)d_in[11];
  const float* w2 = (const float*)d_in[12];
  const float* b2 = (const float*)d_in[13];
  const float* ln1g = (const float*)d_in[14];
  const float* ln1b = (const float*)d_in[15];
  const float* ln2g = (const float*)d_in[16];
  const float* ln2b = (const float*)d_in[17];
  const float* pw1 = (const float*)d_in[18];
  const float* pb1 = (const float*)d_in[19];
  const float* pw2 = (const float*)d_in[20];
  const float* pb2 = (const float*)d_in[21];
  const float* sw1 = (const float*)d_in[22];
  const float* sb1 = (const float*)d_in[23];
  const float* sw2 = (const float*)d_in[24];
  const float* sb2 = (const float*)d_in[25];
  const float* bw1 = (const float*)d_in[26];
  const float* bb1 = (const float*)d_in[27];
  const float* bw2 = (const float*)d_in[28];
  const float* bb2 = (const float*)d_in[29];

  char* wsb = (char*)d_ws;
  size_t off = 0;
  auto allocB = [&](size_t bytes) {
    char* p = wsb + off;
    off += (bytes + 255) & ~(size_t)255;
    return p;
  };
  float* tpb = (float*)allocB(ROWS * TD * 4);
  float* sgb = (float*)allocB(ROWS * TD * 4);
  float* beb = (float*)allocB(ROWS * TD * 4);
  float* kernS = (float*)allocB((size_t)BB * LL * LL * 4);
  float* qkvb = (float*)allocB((size_t)ROWS * QKVN * 4);        // } h hi/lo aliases
  float* ktb = (float*)allocB((size_t)BB * NH * DHD * LL * 4);  // } this region
  float* ao = (float*)allocB((size_t)ROWS * DM * 4);
  float* xb = (float*)allocB((size_t)ROWS * DM * 4);
  float* fb = (float*)allocB((size_t)ROWS * DM * 4);
  float* xn = (float*)allocB((size_t)ROWS * DM * 4);
  float* qkvbias = (float*)allocB(QKVN * 4);
  unsigned short* qkvwt_hi = (unsigned short*)allocB((size_t)QKVN * DM * 2);
  unsigned short* qkvwt_lo = (unsigned short*)allocB((size_t)QKVN * DM * 2);
  unsigned short* wot_hi = (unsigned short*)allocB((size_t)DM * DM * 2);
  unsigned short* wot_lo = (unsigned short*)allocB((size_t)DM * DM * 2);
  unsigned short* w1t_hi = (unsigned short*)allocB((size_t)FF * DM * 2);
  unsigned short* w1t_lo = (unsigned short*)allocB((size_t)FF * DM * 2);
  unsigned short* w2t_hi = (unsigned short*)allocB((size_t)DM * FF * 2);
  unsigned short* w2t_lo = (unsigned short*)allocB((size_t)DM * FF * 2);
  unsigned short* xhi = (unsigned short*)allocB((size_t)ROWS * DM * 2);
  unsigned short* xlo = (unsigned short*)allocB((size_t)ROWS * DM * 2);
  unsigned short* ctxhi = (unsigned short*)allocB((size_t)ROWS * DM * 2);
  unsigned short* ctxlo = (unsigned short*)allocB((size_t)ROWS * DM * 2);
  unsigned short* hhi = (unsigned short*)qkvb;
  unsigned short* hlo = hhi + (size_t)ROWS * FF;

  const float* xcur = x_in;

  for (int i = 0; i < NLAYERS; ++i) {
    td_kernel<<<dim3(16, 16), 256, 0, stream>>>(wq + (size_t)i * DM * DM, qkvwt_hi, qkvwt_lo, DM, DM);
    td_kernel<<<dim3(16, 16), 256, 0, stream>>>(wk + (size_t)i * DM * DM, qkvwt_hi + (size_t)DM * DM, qkvwt_lo + (size_t)DM * DM, DM, DM);
    td_kernel<<<dim3(16, 16), 256, 0, stream>>>(wv + (size_t)i * DM * DM, qkvwt_hi + (size_t)2 * DM * DM, qkvwt_lo + (size_t)2 * DM * DM, DM, DM);
    td_kernel<<<dim3(16, 16), 256, 0, stream>>>(wo + (size_t)i * DM * DM, wot_hi, wot_lo, DM, DM);
    td_kernel<<<dim3(16, 64), 256, 0, stream>>>(w1 + (size_t)i * DM * FF, w1t_hi, w1t_lo, DM, FF);
    td_kernel<<<dim3(64, 16), 256, 0, stream>>>(w2 + (size_t)i * FF * DM, w2t_hi, w2t_lo, FF, DM);
    qkvbias_kernel<<<(QKVN + 255) / 256, 256, 0, stream>>>(bq + i * DM, bk + i * DM, bv + i * DM, qkvbias);

    small_ffn_kernel<<<ROWS / 256, 256, 0, stream>>>(
        t, pw1 + i * TD, pb1 + i * TD, pw2 + i * TD * TD, pb2 + i * TD,
        sw1 + i * TD, sb1 + i * TD, sw2 + i * TD * TD, sb2 + i * TD,
        bw1 + i * TD, bb1 + i * TD, bw2 + i * TD * TD, bb2 + i * TD,
        tpb, sgb, beb);
    kern_kernel<<<dim3(LL / 256, LL, BB), 256, 0, stream>>>(t, tpb, sgb, beb, kernS);

    if (i == 0) {
      decomp_kernel<<<(ROWS * DM / 4 + 255) / 256, 256, 0, stream>>>(x_in, xhi, xlo, ROWS * DM / 4);
    }

    gemm_mfma<128, false, false><<<dim3(QKVN / 128, ROWS / 128), 256, 0, stream>>>(
        xhi, xlo, qkvwt_hi, qkvwt_lo, qkvbias, qkvb, nullptr, nullptr, ROWS, QKVN, DM);

    txp_kernel<<<dim3(LL / 32, DHD / 32, BB * NH), 256, 0, stream>>>(qkvb, ktb);

    attn_kernel<<<dim3(NH, LL / TQ, BB), 512, 0, stream>>>(qkvb, ktb, kernS, ctxhi, ctxlo);

    gemm_mfma<64, false, false><<<dim3(DM / 64, ROWS / 128), 256, 0, stream>>>(
        ctxhi, ctxlo, wot_hi, wot_lo, bo + i * DM, ao, nullptr, nullptr, ROWS, DM, DM);

    resid_ln_kernel<<<ROWS / 4, 256, 0, stream>>>(
        xcur, ao, ln1g + i * DM, ln1b + i * DM, xb, xhi, xlo);

    gemm_mfma<128, true, true><<<dim3(FF / 128, ROWS / 128), 256, 0, stream>>>(
        xhi, xlo, w1t_hi, w1t_lo, b1 + i * FF, nullptr, hhi, hlo, ROWS, FF, DM);

    gemm_mfma<64, false, false><<<dim3(DM / 64, ROWS / 128), 256, 0, stream>>>(
        hhi, hlo, w2t_hi, w2t_lo, b2 + i * DM, fb, nullptr, nullptr, ROWS, DM, FF);

    float* ln2_out = (i == NLAYERS - 1) ? (float*)d_out : xn;
    resid_ln_kernel<<<ROWS / 4, 256, 0, stream>>>(
        xb, fb, ln2g + i * DM, ln2b + i * DM, ln2_out, xhi, xlo);

    xcur = xn;
  }
}

// Round 5
// 990.064 us; speedup vs baseline: 1.1595x; 1.1595x over previous
//
#include <hip/hip_runtime.h>
#include <hip/hip_bf16.h>

#define DEV_INLINE __device__ __forceinline__

constexpr int NLAYERS = 2;
constexpr int DM = 512;
constexpr int NH = 8;
constexpr int DHD = 64;
constexpr int FF = 2048;
constexpr int TD = 8;
constexpr int BB = 8;
constexpr int LL = 512;
constexpr int ROWS = BB * LL;  // 4096
constexpr int QKVN = 3 * DM;   // 1536

constexpr float TWO_PI_F = 6.28318530717958647692f;
constexpr float INV_E8 = 3.3546262790251185e-4f;  // e^-8

typedef __attribute__((ext_vector_type(8))) short short8v;
typedef __attribute__((ext_vector_type(4))) float f32x4;

DEV_INLINE unsigned short bf16_rne(float x) {
  unsigned int u = __float_as_uint(x);
  unsigned int r = (u + 0x7fffu + ((u >> 16) & 1u)) >> 16;
  return (unsigned short)r;
}
DEV_INLINE float bf16_to_f(unsigned short h) {
  return __uint_as_float(((unsigned int)h) << 16);
}
DEV_INLINE void split_bf16(float x, unsigned short& h, unsigned short& l) {
  h = bf16_rne(x);
  float lo = x - bf16_to_f(h);
  l = bf16_rne(lo);
}

// ---------------------------------------------------------------------------
// Small FFNs on t
// ---------------------------------------------------------------------------
DEV_INLINE void ffn2_small(float tv,
                           const float* __restrict__ w1, const float* __restrict__ b1,
                           const float* __restrict__ w2, const float* __restrict__ b2,
                           float* out) {
  float h[TD];
#pragma unroll
  for (int d = 0; d < TD; ++d) h[d] = fmaxf(tv * w1[d] + b1[d], 0.f);
#pragma unroll
  for (int j = 0; j < TD; ++j) {
    float acc = b2[j];
#pragma unroll
    for (int d = 0; d < TD; ++d) acc += h[d] * w2[d * TD + j];
    out[j] = fmaxf(acc, 0.f);
  }
}

__global__ __launch_bounds__(256) void small_ffn_kernel(
    const float* __restrict__ t,
    const float* __restrict__ pw1, const float* __restrict__ pb1,
    const float* __restrict__ pw2, const float* __restrict__ pb2,
    const float* __restrict__ sw1, const float* __restrict__ sb1,
    const float* __restrict__ sw2, const float* __restrict__ sb2,
    const float* __restrict__ bw1, const float* __restrict__ bb1,
    const float* __restrict__ bw2, const float* __restrict__ bb2,
    float* __restrict__ tp, float* __restrict__ sg, float* __restrict__ be) {
  const int i = blockIdx.x * 256 + threadIdx.x;
  if (i >= ROWS) return;
  const float tv = t[i];
  float o[TD];
  ffn2_small(tv, pw1, pb1, pw2, pb2, o);
#pragma unroll
  for (int d = 0; d < TD; ++d) tp[(size_t)i * TD + d] = TWO_PI_F * o[d] * tv;
  ffn2_small(tv, sw1, sb1, sw2, sb2, o);
#pragma unroll
  for (int d = 0; d < TD; ++d) sg[(size_t)i * TD + d] = o[d] + 1e-6f;
  ffn2_small(tv, bw1, bb1, bw2, bb2, o);
#pragma unroll
  for (int d = 0; d < TD; ++d) be[(size_t)i * TD + d] = o[d];
}

// ---------------------------------------------------------------------------
// kern kernel
// ---------------------------------------------------------------------------
DEV_INLINE void load8(const float* __restrict__ p, float* o) {
  float4 a = *reinterpret_cast<const float4*>(p);
  float4 b = *reinterpret_cast<const float4*>(p + 4);
  o[0] = a.x; o[1] = a.y; o[2] = a.z; o[3] = a.w;
  o[4] = b.x; o[5] = b.y; o[6] = b.z; o[7] = b.w;
}

__global__ __launch_bounds__(256) void kern_kernel(
    const float* __restrict__ t, const float* __restrict__ tp,
    const float* __restrict__ sg, const float* __restrict__ be,
    float* __restrict__ kernS) {
  const int k = blockIdx.x * 256 + threadIdx.x;
  const int q = blockIdx.y;
  const int b = blockIdx.z;
  const size_t iq = (size_t)b * LL + q;
  const size_t ik = (size_t)b * LL + k;
  const float tq = t[iq], tk = t[ik];
  const float diff = tq - tk;
  const float d2 = diff * diff;

  float tpq[TD], sgq[TD], beq[TD], tpk[TD], sgk[TD], bek[TD];
  load8(tp + iq * TD, tpq);
  load8(sg + iq * TD, sgq);
  load8(be + iq * TD, beq);
  load8(tp + ik * TD, tpk);
  load8(sg + ik * TD, sgk);
  load8(be + ik * TD, bek);

  float acc = 0.f;
#pragma unroll
  for (int d = 0; d < TD; ++d) {
    const float sq = sgq[d], sk = sgk[d];
    const float denom = sq * sq + sk * sk;
    const float inv = 1.0f / denom;
    const float e = __expf(-d2 * inv);
    const float loc = sqrtf(2.0f * sq * sk * inv);
    const float c = __cosf(tpq[d] - tpk[d]);
    acc += beq[d] * bek[d] * loc * e * c;
  }
  kernS[((size_t)b * LL + q) * LL + k] = acc * INV_E8;
}

// ---------------------------------------------------------------------------
// Weight transpose + hi/lo bf16 decompose: W[K][N] fp32 -> Thi/Tlo[N][K] bf16
// ---------------------------------------------------------------------------
__global__ __launch_bounds__(256) void td_kernel(
    const float* __restrict__ W, unsigned short* __restrict__ Thi,
    unsigned short* __restrict__ Tlo, int K, int N) {
  __shared__ float tile[32][33];
  const int k0 = blockIdx.x * 32, n0 = blockIdx.y * 32;
  const int tx = threadIdx.x & 31, ty = threadIdx.x >> 5;
#pragma unroll
  for (int i = 0; i < 4; ++i)
    tile[ty + i * 8][tx] = W[(size_t)(k0 + ty + i * 8) * N + n0 + tx];
  __syncthreads();
#pragma unroll
  for (int i = 0; i < 4; ++i) {
    const int n = n0 + ty + i * 8;
    const float v = tile[tx][ty + i * 8];
    unsigned short h, l;
    split_bf16(v, h, l);
    Thi[(size_t)n * K + k0 + tx] = h;
    Tlo[(size_t)n * K + k0 + tx] = l;
  }
}

// ---------------------------------------------------------------------------
// Elementwise hi/lo decompose (for layer-0 x). 4 elems/thread.
// ---------------------------------------------------------------------------
__global__ __launch_bounds__(256) void decomp_kernel(
    const float* __restrict__ X, unsigned short* __restrict__ Hi,
    unsigned short* __restrict__ Lo, int n4) {
  const int i = blockIdx.x * 256 + threadIdx.x;
  if (i >= n4) return;
  const float4 v = *reinterpret_cast<const float4*>(X + (size_t)i * 4);
  unsigned short h0, h1, h2, h3, l0, l1, l2, l3;
  split_bf16(v.x, h0, l0);
  split_bf16(v.y, h1, l1);
  split_bf16(v.z, h2, l2);
  split_bf16(v.w, h3, l3);
  uint2 hv, lv;
  hv.x = (unsigned)h0 | ((unsigned)h1 << 16);
  hv.y = (unsigned)h2 | ((unsigned)h3 << 16);
  lv.x = (unsigned)l0 | ((unsigned)l1 << 16);
  lv.y = (unsigned)l2 | ((unsigned)l3 << 16);
  *reinterpret_cast<uint2*>(Hi + (size_t)i * 4) = hv;
  *reinterpret_cast<uint2*>(Lo + (size_t)i * 4) = lv;
}

__global__ __launch_bounds__(256) void qkvbias_kernel(
    const float* __restrict__ bq, const float* __restrict__ bk,
    const float* __restrict__ bv, float* __restrict__ out) {
  const int i = blockIdx.x * 256 + threadIdx.x;
  if (i >= QKVN) return;
  out[i] = i < DM ? bq[i] : (i < 2 * DM ? bk[i - DM] : bv[i - 2 * DM]);
}

// ---------------------------------------------------------------------------
// Split-bf16 MFMA GEMM, SINGLE K-pass with interleaved hi/lo products:
//   C = Ahi@Bhi + Alo@Bhi + Ahi@Blo (+bias, opt relu)
// Round-3 proven structure: double-buffered LDS, ONE barrier per k-tile,
// register prefetch two tiles ahead. XCD-bijective block swizzle.
// ---------------------------------------------------------------------------
template <int BN, bool RELU, bool SPLIT_OUT>
__global__ __launch_bounds__(256) void gemm_mfma(
    const unsigned short* __restrict__ Ahi, const unsigned short* __restrict__ Alo,
    const unsigned short* __restrict__ Bhi, const unsigned short* __restrict__ Blo,
    const float* __restrict__ bias, float* __restrict__ C,
    unsigned short* __restrict__ Chi, unsigned short* __restrict__ Clo,
    int M, int N, int K) {
  constexpr int BM = 128, BK = 64;
  constexpr int WT_M = 64;
  constexpr int WT_N = BN / 2;
  constexpr int MI = WT_M / 16;   // 4
  constexpr int NI = WT_N / 16;   // 4 or 2
  constexpr int A_IT = BM * BK / (256 * 8);  // 4
  constexpr int B_IT = BN * BK / (256 * 8);  // 4 or 2

  __shared__ unsigned short AsH[2][BM * BK];
  __shared__ unsigned short AsL[2][BM * BK];
  __shared__ unsigned short BsH[2][BN * BK];
  __shared__ unsigned short BsL[2][BN * BK];

  const int nwg = gridDim.x * gridDim.y;
  const int orig = blockIdx.y * gridDim.x + blockIdx.x;
  const int swz = (orig & 7) * (nwg >> 3) + (orig >> 3);
  const int bx = swz % gridDim.x;
  const int by = swz / gridDim.x;

  const int tid = threadIdx.x;
  const int lane = tid & 63;
  const int wid = tid >> 6;
  const int wr = wid >> 1, wc = wid & 1;
  const int rowBase = by * BM;
  const int colBase = bx * BN;
  const int l15 = lane & 15, l4 = lane >> 4;

  const int sg_ = tid & 7;
  const int srA = tid >> 3;
  const int swg = sg_ ^ (srA & 7);

  f32x4 acc[MI][NI] = {};
  const int nt = K / BK;

  uint4 ahR[A_IT], alR[A_IT], bhR[B_IT], blR[B_IT];

  auto loadRegs = [&](int kt) {
    const int k0 = kt * BK;
#pragma unroll
    for (int it = 0; it < A_IT; ++it) {
      const size_t base = (size_t)(rowBase + it * 32 + srA) * K + k0 + sg_ * 8;
      ahR[it] = *reinterpret_cast<const uint4*>(Ahi + base);
      alR[it] = *reinterpret_cast<const uint4*>(Alo + base);
    }
#pragma unroll
    for (int it = 0; it < B_IT; ++it) {
      const size_t base = (size_t)(colBase + it * 32 + srA) * K + k0 + sg_ * 8;
      bhR[it] = *reinterpret_cast<const uint4*>(Bhi + base);
      blR[it] = *reinterpret_cast<const uint4*>(Blo + base);
    }
  };

  auto writeLDS = [&](int buf) {
#pragma unroll
    for (int it = 0; it < A_IT; ++it) {
      const int off = ((it * 32 + srA) << 6) + (swg << 3);
      *reinterpret_cast<uint4*>(&AsH[buf][off]) = ahR[it];
      *reinterpret_cast<uint4*>(&AsL[buf][off]) = alR[it];
    }
#pragma unroll
    for (int it = 0; it < B_IT; ++it) {
      const int off = ((it * 32 + srA) << 6) + (swg << 3);
      *reinterpret_cast<uint4*>(&BsH[buf][off]) = bhR[it];
      *reinterpret_cast<uint4*>(&BsL[buf][off]) = blR[it];
    }
  };

  // prologue: tile0 -> LDS buf0; tile1 -> regs
  loadRegs(0);
  writeLDS(0);
  if (nt > 1) loadRegs(1);

  for (int t = 0; t < nt; ++t) {
    __syncthreads();
    const int cur = t & 1;
    if (t + 1 < nt) writeLDS(cur ^ 1);
    if (t + 2 < nt) loadRegs(t + 2);

#pragma unroll
    for (int ks = 0; ks < 2; ++ks) {
      short8v ah[MI], al[MI], bh[NI], bl[NI];
#pragma unroll
      for (int mi = 0; mi < MI; ++mi) {
        const int r = wr * WT_M + mi * 16 + l15;
        const int off = (r << 6) + (((ks * 4 + l4) ^ (r & 7)) << 3);
        ah[mi] = *reinterpret_cast<const short8v*>(&AsH[cur][off]);
        al[mi] = *reinterpret_cast<const short8v*>(&AsL[cur][off]);
      }
#pragma unroll
      for (int ni = 0; ni < NI; ++ni) {
        const int r = wc * WT_N + ni * 16 + l15;
        const int off = (r << 6) + (((ks * 4 + l4) ^ (r & 7)) << 3);
        bh[ni] = *reinterpret_cast<const short8v*>(&BsH[cur][off]);
        bl[ni] = *reinterpret_cast<const short8v*>(&BsL[cur][off]);
      }
#pragma unroll
      for (int mi = 0; mi < MI; ++mi)
#pragma unroll
        for (int ni = 0; ni < NI; ++ni) {
          acc[mi][ni] = __builtin_amdgcn_mfma_f32_16x16x32_bf16(ah[mi], bh[ni], acc[mi][ni], 0, 0, 0);
          acc[mi][ni] = __builtin_amdgcn_mfma_f32_16x16x32_bf16(al[mi], bh[ni], acc[mi][ni], 0, 0, 0);
          acc[mi][ni] = __builtin_amdgcn_mfma_f32_16x16x32_bf16(ah[mi], bl[ni], acc[mi][ni], 0, 0, 0);
        }
    }
  }

#pragma unroll
  for (int mi = 0; mi < MI; ++mi) {
#pragma unroll
    for (int ni = 0; ni < NI; ++ni) {
      const int col = colBase + wc * WT_N + ni * 16 + l15;
      const float bv = bias[col];
#pragma unroll
      for (int j = 0; j < 4; ++j) {
        const int row = rowBase + wr * WT_M + mi * 16 + l4 * 4 + j;
        float v = acc[mi][ni][j] + bv;
        if (RELU) v = fmaxf(v, 0.f);
        if (SPLIT_OUT) {
          unsigned short h, l;
          split_bf16(v, h, l);
          Chi[(size_t)row * N + col] = h;
          Clo[(size_t)row * N + col] = l;
        } else {
          C[(size_t)row * N + col] = v;
        }
      }
    }
  }
}

// ---------------------------------------------------------------------------
// K transpose: qkvb k-slice -> ktb[bh][d][kk]  (fp32)
// ---------------------------------------------------------------------------
__global__ __launch_bounds__(256) void txp_kernel(
    const float* __restrict__ qkvb, float* __restrict__ ktb) {
  __shared__ float tile[32][33];
  const int bh = blockIdx.z;
  const int b = bh >> 3, h = bh & 7;
  const int kk0 = blockIdx.x * 32, d0 = blockIdx.y * 32;
  const int tx = threadIdx.x & 31, ty = threadIdx.x >> 5;
#pragma unroll
  for (int i = 0; i < 4; ++i) {
    const int kk = kk0 + ty + i * 8;
    tile[ty + i * 8][tx] = qkvb[(size_t)(b * LL + kk) * QKVN + DM + h * DHD + d0 + tx];
  }
  __syncthreads();
#pragma unroll
  for (int i = 0; i < 4; ++i) {
    const int d = d0 + ty + i * 8;
    ktb[((size_t)bh * DHD + d) * LL + kk0 + tx] = tile[tx][ty + i * 8];
  }
}

// ---------------------------------------------------------------------------
// Fused attention (round-3 structure, 256 threads, 2 kk/thread) +
//  (a) XCD remap: h fastest -> kernS rows / K / V L2-resident per XCD
//  (b) lst row stride 12 words, float4 phase-1 stores (conflict-free writes)
// grid (NH, LL/TQ, BB), 256 threads.
// ---------------------------------------------------------------------------
constexpr int TQ = 8;

__global__ __launch_bounds__(256) void attn_kernel(
    const float* __restrict__ qkvb, const float* __restrict__ ktb,
    const float* __restrict__ kernS,
    unsigned short* __restrict__ ctxhi, unsigned short* __restrict__ ctxlo) {
  const int id = blockIdx.x + 8 * (blockIdx.y + 64 * blockIdx.z);
  const int w = (id & 7) * 512 + (id >> 3);
  const int h = w & 7;
  const int qt = (w >> 3) & 63;
  const int b = w >> 9;
  const int tid = threadIdx.x;
  const int q0 = qt * TQ;

  __shared__ float qst[DHD][TQ];   // 2 KB
  __shared__ float lst[LL][12];    // 24 KB, 48B row stride
  __shared__ float red[4][TQ][DHD];
  __shared__ float invS[TQ];

  {
    const int d = tid & 63;
    const int qq0 = tid >> 6;
#pragma unroll
    for (int rep = 0; rep < 2; ++rep) {
      const int qq = qq0 + rep * 4;
      qst[d][qq] = qkvb[(size_t)(b * LL + q0 + qq) * QKVN + h * DHD + d];
    }
  }
  __syncthreads();

  // phase 1: logits for kk = tid and kk+256
  {
    const int kk = tid;
    const float* kcol = ktb + (size_t)(b * NH + h) * DHD * LL;
    float dot0[TQ] = {}, dot1[TQ] = {};
#pragma unroll 4
    for (int d = 0; d < DHD; ++d) {
      const float ka = kcol[(size_t)d * LL + kk];
      const float kb2 = kcol[(size_t)d * LL + kk + 256];
      const float4 qa = *reinterpret_cast<const float4*>(&qst[d][0]);
      const float4 qb2 = *reinterpret_cast<const float4*>(&qst[d][4]);
      dot0[0] += qa.x * ka; dot0[1] += qa.y * ka; dot0[2] += qa.z * ka; dot0[3] += qa.w * ka;
      dot0[4] += qb2.x * ka; dot0[5] += qb2.y * ka; dot0[6] += qb2.z * ka; dot0[7] += qb2.w * ka;
      dot1[0] += qa.x * kb2; dot1[1] += qa.y * kb2; dot1[2] += qa.z * kb2; dot1[3] += qa.w * kb2;
      dot1[4] += qb2.x * kb2; dot1[5] += qb2.y * kb2; dot1[6] += qb2.z * kb2; dot1[7] += qb2.w * kb2;
    }
#pragma unroll
    for (int qq = 0; qq < TQ; ++qq) {
      const size_t kbase = ((size_t)b * LL + q0 + qq) * LL;
      dot0[qq] = dot0[qq] * 0.125f + kernS[kbase + kk];
      dot1[qq] = dot1[qq] * 0.125f + kernS[kbase + kk + 256];
    }
    float4 p;
    p.x = dot0[0]; p.y = dot0[1]; p.z = dot0[2]; p.w = dot0[3];
    *reinterpret_cast<float4*>(&lst[kk][0]) = p;
    p.x = dot0[4]; p.y = dot0[5]; p.z = dot0[6]; p.w = dot0[7];
    *reinterpret_cast<float4*>(&lst[kk][4]) = p;
    p.x = dot1[0]; p.y = dot1[1]; p.z = dot1[2]; p.w = dot1[3];
    *reinterpret_cast<float4*>(&lst[kk + 256][0]) = p;
    p.x = dot1[4]; p.y = dot1[5]; p.z = dot1[6]; p.w = dot1[7];
    *reinterpret_cast<float4*>(&lst[kk + 256][4]) = p;
  }
  __syncthreads();

  // softmax: 8 rows x 32 lanes
  {
    const int row = tid >> 5;
    const int l32 = tid & 31;
    float m = -1e30f;
#pragma unroll
    for (int j = 0; j < 16; ++j) m = fmaxf(m, lst[l32 + j * 32][row]);
#pragma unroll
    for (int s = 16; s; s >>= 1) m = fmaxf(m, __shfl_xor(m, s, 32));
    float sum = 0.f;
#pragma unroll
    for (int j = 0; j < 16; ++j) {
      const float e = __expf(lst[l32 + j * 32][row] - m);
      lst[l32 + j * 32][row] = e;
      sum += e;
    }
#pragma unroll
    for (int s = 16; s; s >>= 1) sum += __shfl_xor(sum, s, 32);
    if (l32 == 0) invS[row] = 1.0f / sum;
  }
  __syncthreads();

  // phase 2: ctx = P @ V
  const int d = tid & 63;
  const int c = tid >> 6;
  float acc[TQ] = {};
  {
    const float* vbase = qkvb + (size_t)(b * LL) * QKVN + 2 * DM + h * DHD + d;
    for (int kk = c * 128; kk < c * 128 + 128; ++kk) {
      const float vv = vbase[(size_t)kk * QKVN];
      const float4 pa = *reinterpret_cast<const float4*>(&lst[kk][0]);
      const float4 pb2 = *reinterpret_cast<const float4*>(&lst[kk][4]);
      acc[0] += pa.x * vv; acc[1] += pa.y * vv; acc[2] += pa.z * vv; acc[3] += pa.w * vv;
      acc[4] += pb2.x * vv; acc[5] += pb2.y * vv; acc[6] += pb2.z * vv; acc[7] += pb2.w * vv;
    }
  }
#pragma unroll
  for (int qq = 0; qq < TQ; ++qq) red[c][qq][d] = acc[qq];
  __syncthreads();
  if (c == 0) {
#pragma unroll
    for (int qq = 0; qq < TQ; ++qq) {
      const float r = ((red[0][qq][d] + red[1][qq][d]) + (red[2][qq][d] + red[3][qq][d])) * invS[qq];
      unsigned short hh, ll;
      split_bf16(r, hh, ll);
      const size_t o = (size_t)(b * LL + q0 + qq) * DM + h * DHD + d;
      ctxhi[o] = hh;
      ctxlo[o] = ll;
    }
  }
}

// ---------------------------------------------------------------------------
// Fused residual + LayerNorm; writes fp32 + bf16 hi/lo decomposition.
// ---------------------------------------------------------------------------
__global__ __launch_bounds__(256) void resid_ln_kernel(
    const float* __restrict__ X, const float* __restrict__ R,
    const float* __restrict__ g, const float* __restrict__ bta,
    float* __restrict__ Out, unsigned short* __restrict__ OutHi,
    unsigned short* __restrict__ OutLo) {
  const int row = blockIdx.x * 4 + (threadIdx.x >> 6);
  const int lane = threadIdx.x & 63;
  const float* x = X + (size_t)row * DM;
  const float* r = R + (size_t)row * DM;

  float v[8];
  float s = 0.f;
#pragma unroll
  for (int j = 0; j < 2; ++j) {
    const float4 a = *reinterpret_cast<const float4*>(x + lane * 8 + j * 4);
    const float4 c = *reinterpret_cast<const float4*>(r + lane * 8 + j * 4);
    v[j * 4 + 0] = a.x + c.x;
    v[j * 4 + 1] = a.y + c.y;
    v[j * 4 + 2] = a.z + c.z;
    v[j * 4 + 3] = a.w + c.w;
    s += v[j * 4 + 0] + v[j * 4 + 1] + v[j * 4 + 2] + v[j * 4 + 3];
  }
#pragma unroll
  for (int m = 1; m < 64; m <<= 1) s += __shfl_xor(s, m, 64);
  const float mean = s * (1.f / DM);
  float var = 0.f;
#pragma unroll
  for (int j = 0; j < 8; ++j) {
    const float dlt = v[j] - mean;
    var += dlt * dlt;
  }
#pragma unroll
  for (int m = 1; m < 64; m <<= 1) var += __shfl_xor(var, m, 64);
  var *= (1.f / DM);
  const float inv = 1.0f / sqrtf(var + 1e-6f);

  unsigned short hs[8], ls[8];
#pragma unroll
  for (int j = 0; j < 2; ++j) {
    const float4 gg = *reinterpret_cast<const float4*>(g + lane * 8 + j * 4);
    const float4 bb = *reinterpret_cast<const float4*>(bta + lane * 8 + j * 4);
    float4 o;
    o.x = (v[j * 4 + 0] - mean) * inv * gg.x + bb.x;
    o.y = (v[j * 4 + 1] - mean) * inv * gg.y + bb.y;
    o.z = (v[j * 4 + 2] - mean) * inv * gg.z + bb.z;
    o.w = (v[j * 4 + 3] - mean) * inv * gg.w + bb.w;
    *reinterpret_cast<float4*>(Out + (size_t)row * DM + lane * 8 + j * 4) = o;
    split_bf16(o.x, hs[j * 4 + 0], ls[j * 4 + 0]);
    split_bf16(o.y, hs[j * 4 + 1], ls[j * 4 + 1]);
    split_bf16(o.z, hs[j * 4 + 2], ls[j * 4 + 2]);
    split_bf16(o.w, hs[j * 4 + 3], ls[j * 4 + 3]);
  }
  uint4 hv, lv;
  hv.x = (unsigned)hs[0] | ((unsigned)hs[1] << 16);
  hv.y = (unsigned)hs[2] | ((unsigned)hs[3] << 16);
  hv.z = (unsigned)hs[4] | ((unsigned)hs[5] << 16);
  hv.w = (unsigned)hs[6] | ((unsigned)hs[7] << 16);
  lv.x = (unsigned)ls[0] | ((unsigned)ls[1] << 16);
  lv.y = (unsigned)ls[2] | ((unsigned)ls[3] << 16);
  lv.z = (unsigned)ls[4] | ((unsigned)ls[5] << 16);
  lv.w = (unsigned)ls[6] | ((unsigned)ls[7] << 16);
  *reinterpret_cast<uint4*>(OutHi + (size_t)row * DM + lane * 8) = hv;
  *reinterpret_cast<uint4*>(OutLo + (size_t)row * DM + lane * 8) = lv;
}

// ---------------------------------------------------------------------------
// launch
// ---------------------------------------------------------------------------
extern "C" void kernel_launch(void* const* d_in, const int* in_sizes, int n_in,
                              void* d_out, int out_size, void* d_ws, size_t ws_size,
                              hipStream_t stream) {
  const float* x_in = (const float*)d_in[0];
  const float* t = (const float*)d_in[1];
  const float* wq = (const float*)d_in[2];
  const float* bq = (const float*)d_in[3];
  const float* wk = (const float*)d_in[4];
  const float* bk = (const float*)d_in[5];
  const float* wv = (const float*)d_in[6];
  const float* bv = (const float*)d_in[7];
  const float* wo = (const float*)d_in[8];
  const float* bo = (const float*)d_in[9];
  const float* w1 = (const float*)d_in[10];
  const float* b1 = (const float*)d_in[11];
  const float* w2 = (const float*)d_in[12];
  const float* b2 = (const float*)d_in[13];
  const float* ln1g = (const float*)d_in[14];
  const float* ln1b = (const float*)d_in[15];
  const float* ln2g = (const float*)d_in[16];
  const float* ln2b = (const float*)d_in[17];
  const float* pw1 = (const float*)d_in[18];
  const float* pb1 = (const float*)d_in[19];
  const float* pw2 = (const float*)d_in[20];
  const float* pb2 = (const float*)d_in[21];
  const float* sw1 = (const float*)d_in[22];
  const float* sb1 = (const float*)d_in[23];
  const float* sw2 = (const float*)d_in[24];
  const float* sb2 = (const float*)d_in[25];
  const float* bw1 = (const float*)d_in[26];
  const float* bb1 = (const float*)d_in[27];
  const float* bw2 = (const float*)d_in[28];
  const float* bb2 = (const float*)d_in[29];

  char* wsb = (char*)d_ws;
  size_t off = 0;
  auto allocB = [&](size_t bytes) {
    char* p = wsb + off;
    off += (bytes + 255) & ~(size_t)255;
    return p;
  };
  float* tpb = (float*)allocB(ROWS * TD * 4);
  float* sgb = (float*)allocB(ROWS * TD * 4);
  float* beb = (float*)allocB(ROWS * TD * 4);
  float* kernS = (float*)allocB((size_t)BB * LL * LL * 4);
  float* qkvb = (float*)allocB((size_t)ROWS * QKVN * 4);        // } h hi/lo aliases
  float* ktb = (float*)allocB((size_t)BB * NH * DHD * LL * 4);  // } this region
  float* ao = (float*)allocB((size_t)ROWS * DM * 4);
  float* xb = (float*)allocB((size_t)ROWS * DM * 4);
  float* fb = (float*)allocB((size_t)ROWS * DM * 4);
  float* xn = (float*)allocB((size_t)ROWS * DM * 4);
  float* qkvbias = (float*)allocB(QKVN * 4);
  unsigned short* qkvwt_hi = (unsigned short*)allocB((size_t)QKVN * DM * 2);
  unsigned short* qkvwt_lo = (unsigned short*)allocB((size_t)QKVN * DM * 2);
  unsigned short* wot_hi = (unsigned short*)allocB((size_t)DM * DM * 2);
  unsigned short* wot_lo = (unsigned short*)allocB((size_t)DM * DM * 2);
  unsigned short* w1t_hi = (unsigned short*)allocB((size_t)FF * DM * 2);
  unsigned short* w1t_lo = (unsigned short*)allocB((size_t)FF * DM * 2);
  unsigned short* w2t_hi = (unsigned short*)allocB((size_t)DM * FF * 2);
  unsigned short* w2t_lo = (unsigned short*)allocB((size_t)DM * FF * 2);
  unsigned short* xhi = (unsigned short*)allocB((size_t)ROWS * DM * 2);
  unsigned short* xlo = (unsigned short*)allocB((size_t)ROWS * DM * 2);
  unsigned short* ctxhi = (unsigned short*)allocB((size_t)ROWS * DM * 2);
  unsigned short* ctxlo = (unsigned short*)allocB((size_t)ROWS * DM * 2);
  unsigned short* hhi = (unsigned short*)qkvb;
  unsigned short* hlo = hhi + (size_t)ROWS * FF;

  const float* xcur = x_in;

  for (int i = 0; i < NLAYERS; ++i) {
    td_kernel<<<dim3(16, 16), 256, 0, stream>>>(wq + (size_t)i * DM * DM, qkvwt_hi, qkvwt_lo, DM, DM);
    td_kernel<<<dim3(16, 16), 256, 0, stream>>>(wk + (size_t)i * DM * DM, qkvwt_hi + (size_t)DM * DM, qkvwt_lo + (size_t)DM * DM, DM, DM);
    td_kernel<<<dim3(16, 16), 256, 0, stream>>>(wv + (size_t)i * DM * DM, qkvwt_hi + (size_t)2 * DM * DM, qkvwt_lo + (size_t)2 * DM * DM, DM, DM);
    td_kernel<<<dim3(16, 16), 256, 0, stream>>>(wo + (size_t)i * DM * DM, wot_hi, wot_lo, DM, DM);
    td_kernel<<<dim3(16, 64), 256, 0, stream>>>(w1 + (size_t)i * DM * FF, w1t_hi, w1t_lo, DM, FF);
    td_kernel<<<dim3(64, 16), 256, 0, stream>>>(w2 + (size_t)i * FF * DM, w2t_hi, w2t_lo, FF, DM);
    qkvbias_kernel<<<(QKVN + 255) / 256, 256, 0, stream>>>(bq + i * DM, bk + i * DM, bv + i * DM, qkvbias);

    small_ffn_kernel<<<ROWS / 256, 256, 0, stream>>>(
        t, pw1 + i * TD, pb1 + i * TD, pw2 + i * TD * TD, pb2 + i * TD,
        sw1 + i * TD, sb1 + i * TD, sw2 + i * TD * TD, sb2 + i * TD,
        bw1 + i * TD, bb1 + i * TD, bw2 + i * TD * TD, bb2 + i * TD,
        tpb, sgb, beb);
    kern_kernel<<<dim3(LL / 256, LL, BB), 256, 0, stream>>>(t, tpb, sgb, beb, kernS);

    if (i == 0) {
      decomp_kernel<<<(ROWS * DM / 4 + 255) / 256, 256, 0, stream>>>(x_in, xhi, xlo, ROWS * DM / 4);
    }

    gemm_mfma<128, false, false><<<dim3(QKVN / 128, ROWS / 128), 256, 0, stream>>>(
        xhi, xlo, qkvwt_hi, qkvwt_lo, qkvbias, qkvb, nullptr, nullptr, ROWS, QKVN, DM);

    txp_kernel<<<dim3(LL / 32, DHD / 32, BB * NH), 256, 0, stream>>>(qkvb, ktb);

    attn_kernel<<<dim3(NH, LL / TQ, BB), 256, 0, stream>>>(qkvb, ktb, kernS, ctxhi, ctxlo);

    gemm_mfma<64, false, false><<<dim3(DM / 64, ROWS / 128), 256, 0, stream>>>(
        ctxhi, ctxlo, wot_hi, wot_lo, bo + i * DM, ao, nullptr, nullptr, ROWS, DM, DM);

    resid_ln_kernel<<<ROWS / 4, 256, 0, stream>>>(
        xcur, ao, ln1g + i * DM, ln1b + i * DM, xb, xhi, xlo);

    gemm_mfma<128, true, true><<<dim3(FF / 128, ROWS / 128), 256, 0, stream>>>(
        xhi, xlo, w1t_hi, w1t_lo, b1 + i * FF, nullptr, hhi, hlo, ROWS, FF, DM);

    gemm_mfma<64, false, false><<<dim3(DM / 64, ROWS / 128), 256, 0, stream>>>(
        hhi, hlo, w2t_hi, w2t_lo, b2 + i * DM, fb, nullptr, nullptr, ROWS, DM, FF);

    float* ln2_out = (i == NLAYERS - 1) ? (float*)d_out : xn;
    resid_ln_kernel<<<ROWS / 4, 256, 0, stream>>>(
        xb, fb, ln2g + i * DM, ln2b + i * DM, ln2_out, xhi, xlo);

    xcur = xn;
  }
}

// Round 6
// 872.495 us; speedup vs baseline: 1.3157x; 1.1347x over previous
//
#include <hip/hip_runtime.h>
#include <hip/hip_bf16.h>

#define DEV_INLINE __device__ __forceinline__

constexpr int NLAYERS = 2;
constexpr int DM = 512;
constexpr int NH = 8;
constexpr int DHD = 64;
constexpr int FF = 2048;
constexpr int TD = 8;
constexpr int BB = 8;
constexpr int LL = 512;
constexpr int ROWS = BB * LL;  // 4096
constexpr int QKVN = 3 * DM;   // 1536

constexpr float TWO_PI_F = 6.28318530717958647692f;
constexpr float INV_E8 = 3.3546262790251185e-4f;  // e^-8

typedef __attribute__((ext_vector_type(8))) short short8v;
typedef __attribute__((ext_vector_type(4))) float f32x4;

DEV_INLINE unsigned short bf16_rne(float x) {
  unsigned int u = __float_as_uint(x);
  unsigned int r = (u + 0x7fffu + ((u >> 16) & 1u)) >> 16;
  return (unsigned short)r;
}
DEV_INLINE float bf16_to_f(unsigned short h) {
  return __uint_as_float(((unsigned int)h) << 16);
}
DEV_INLINE void split_bf16(float x, unsigned short& h, unsigned short& l) {
  h = bf16_rne(x);
  float lo = x - bf16_to_f(h);
  l = bf16_rne(lo);
}

// ---------------------------------------------------------------------------
// Small FFNs on t
// ---------------------------------------------------------------------------
DEV_INLINE void ffn2_small(float tv,
                           const float* __restrict__ w1, const float* __restrict__ b1,
                           const float* __restrict__ w2, const float* __restrict__ b2,
                           float* out) {
  float h[TD];
#pragma unroll
  for (int d = 0; d < TD; ++d) h[d] = fmaxf(tv * w1[d] + b1[d], 0.f);
#pragma unroll
  for (int j = 0; j < TD; ++j) {
    float acc = b2[j];
#pragma unroll
    for (int d = 0; d < TD; ++d) acc += h[d] * w2[d * TD + j];
    out[j] = fmaxf(acc, 0.f);
  }
}

__global__ __launch_bounds__(256) void small_ffn_kernel(
    const float* __restrict__ t,
    const float* __restrict__ pw1, const float* __restrict__ pb1,
    const float* __restrict__ pw2, const float* __restrict__ pb2,
    const float* __restrict__ sw1, const float* __restrict__ sb1,
    const float* __restrict__ sw2, const float* __restrict__ sb2,
    const float* __restrict__ bw1, const float* __restrict__ bb1,
    const float* __restrict__ bw2, const float* __restrict__ bb2,
    float* __restrict__ tp, float* __restrict__ sg, float* __restrict__ be) {
  const int i = blockIdx.x * 256 + threadIdx.x;
  if (i >= ROWS) return;
  const float tv = t[i];
  float o[TD];
  ffn2_small(tv, pw1, pb1, pw2, pb2, o);
#pragma unroll
  for (int d = 0; d < TD; ++d) tp[(size_t)i * TD + d] = TWO_PI_F * o[d] * tv;
  ffn2_small(tv, sw1, sb1, sw2, sb2, o);
#pragma unroll
  for (int d = 0; d < TD; ++d) sg[(size_t)i * TD + d] = o[d] + 1e-6f;
  ffn2_small(tv, bw1, bb1, bw2, bb2, o);
#pragma unroll
  for (int d = 0; d < TD; ++d) be[(size_t)i * TD + d] = o[d];
}

// ---------------------------------------------------------------------------
// kern kernel
// ---------------------------------------------------------------------------
DEV_INLINE void load8(const float* __restrict__ p, float* o) {
  float4 a = *reinterpret_cast<const float4*>(p);
  float4 b = *reinterpret_cast<const float4*>(p + 4);
  o[0] = a.x; o[1] = a.y; o[2] = a.z; o[3] = a.w;
  o[4] = b.x; o[5] = b.y; o[6] = b.z; o[7] = b.w;
}

__global__ __launch_bounds__(256) void kern_kernel(
    const float* __restrict__ t, const float* __restrict__ tp,
    const float* __restrict__ sg, const float* __restrict__ be,
    float* __restrict__ kernS) {
  const int k = blockIdx.x * 256 + threadIdx.x;
  const int q = blockIdx.y;
  const int b = blockIdx.z;
  const size_t iq = (size_t)b * LL + q;
  const size_t ik = (size_t)b * LL + k;
  const float tq = t[iq], tk = t[ik];
  const float diff = tq - tk;
  const float d2 = diff * diff;

  float tpq[TD], sgq[TD], beq[TD], tpk[TD], sgk[TD], bek[TD];
  load8(tp + iq * TD, tpq);
  load8(sg + iq * TD, sgq);
  load8(be + iq * TD, beq);
  load8(tp + ik * TD, tpk);
  load8(sg + ik * TD, sgk);
  load8(be + ik * TD, bek);

  float acc = 0.f;
#pragma unroll
  for (int d = 0; d < TD; ++d) {
    const float sq = sgq[d], sk = sgk[d];
    const float denom = sq * sq + sk * sk;
    const float inv = 1.0f / denom;
    const float e = __expf(-d2 * inv);
    const float loc = sqrtf(2.0f * sq * sk * inv);
    const float c = __cosf(tpq[d] - tpk[d]);
    acc += beq[d] * bek[d] * loc * e * c;
  }
  kernS[((size_t)b * LL + q) * LL + k] = acc * INV_E8;
}

// ---------------------------------------------------------------------------
// Weight transpose + hi/lo bf16 decompose: W[K][N] fp32 -> Thi/Tlo[N][K] bf16
// ---------------------------------------------------------------------------
__global__ __launch_bounds__(256) void td_kernel(
    const float* __restrict__ W, unsigned short* __restrict__ Thi,
    unsigned short* __restrict__ Tlo, int K, int N) {
  __shared__ float tile[32][33];
  const int k0 = blockIdx.x * 32, n0 = blockIdx.y * 32;
  const int tx = threadIdx.x & 31, ty = threadIdx.x >> 5;
#pragma unroll
  for (int i = 0; i < 4; ++i)
    tile[ty + i * 8][tx] = W[(size_t)(k0 + ty + i * 8) * N + n0 + tx];
  __syncthreads();
#pragma unroll
  for (int i = 0; i < 4; ++i) {
    const int n = n0 + ty + i * 8;
    const float v = tile[tx][ty + i * 8];
    unsigned short h, l;
    split_bf16(v, h, l);
    Thi[(size_t)n * K + k0 + tx] = h;
    Tlo[(size_t)n * K + k0 + tx] = l;
  }
}

// ---------------------------------------------------------------------------
// Elementwise hi/lo decompose (for layer-0 x). 4 elems/thread.
// ---------------------------------------------------------------------------
__global__ __launch_bounds__(256) void decomp_kernel(
    const float* __restrict__ X, unsigned short* __restrict__ Hi,
    unsigned short* __restrict__ Lo, int n4) {
  const int i = blockIdx.x * 256 + threadIdx.x;
  if (i >= n4) return;
  const float4 v = *reinterpret_cast<const float4*>(X + (size_t)i * 4);
  unsigned short h0, h1, h2, h3, l0, l1, l2, l3;
  split_bf16(v.x, h0, l0);
  split_bf16(v.y, h1, l1);
  split_bf16(v.z, h2, l2);
  split_bf16(v.w, h3, l3);
  uint2 hv, lv;
  hv.x = (unsigned)h0 | ((unsigned)h1 << 16);
  hv.y = (unsigned)h2 | ((unsigned)h3 << 16);
  lv.x = (unsigned)l0 | ((unsigned)l1 << 16);
  lv.y = (unsigned)l2 | ((unsigned)l3 << 16);
  *reinterpret_cast<uint2*>(Hi + (size_t)i * 4) = hv;
  *reinterpret_cast<uint2*>(Lo + (size_t)i * 4) = lv;
}

__global__ __launch_bounds__(256) void qkvbias_kernel(
    const float* __restrict__ bq, const float* __restrict__ bk,
    const float* __restrict__ bv, float* __restrict__ out) {
  const int i = blockIdx.x * 256 + threadIdx.x;
  if (i >= QKVN) return;
  out[i] = i < DM ? bq[i] : (i < 2 * DM ? bk[i - DM] : bv[i - 2 * DM]);
}

// ---------------------------------------------------------------------------
// Split-bf16 MFMA GEMM: C = Ahi@Bhi + Alo@Bhi + Ahi@Blo (+bias, opt relu)
// BK=32 (64/48 KB LDS -> 2-3 blocks/CU), double-buffered LDS, ONE barrier per
// k-tile, register prefetch two tiles ahead. XCD-bijective block swizzle.
// LDS row = 32 elems (64B); granule swizzle g ^= (r&3)^((r>>2)&3):
// both b128 writes and MFMA fragment reads are 2-way (free).
// ---------------------------------------------------------------------------
template <int BN, bool RELU, bool SPLIT_OUT>
__global__ __launch_bounds__(256) void gemm_mfma(
    const unsigned short* __restrict__ Ahi, const unsigned short* __restrict__ Alo,
    const unsigned short* __restrict__ Bhi, const unsigned short* __restrict__ Blo,
    const float* __restrict__ bias, float* __restrict__ C,
    unsigned short* __restrict__ Chi, unsigned short* __restrict__ Clo,
    int M, int N, int K) {
  constexpr int BM = 128, BK = 32;
  constexpr int WT_M = 64;
  constexpr int WT_N = BN / 2;
  constexpr int MI = WT_M / 16;   // 4
  constexpr int NI = WT_N / 16;   // 4 or 2
  constexpr int A_IT = BM * BK / (256 * 8);  // 2
  constexpr int B_IT = BN * BK / (256 * 8);  // 2 or 1

  __shared__ unsigned short AsH[2][BM * BK];
  __shared__ unsigned short AsL[2][BM * BK];
  __shared__ unsigned short BsH[2][BN * BK];
  __shared__ unsigned short BsL[2][BN * BK];

  const int nwg = gridDim.x * gridDim.y;
  const int orig = blockIdx.y * gridDim.x + blockIdx.x;
  const int swz = (orig & 7) * (nwg >> 3) + (orig >> 3);
  const int bx = swz % gridDim.x;
  const int by = swz / gridDim.x;

  const int tid = threadIdx.x;
  const int lane = tid & 63;
  const int wid = tid >> 6;
  const int wr = wid >> 1, wc = wid & 1;
  const int rowBase = by * BM;
  const int colBase = bx * BN;
  const int l15 = lane & 15, l4 = lane >> 4;

  // staging geometry: 4 granules of 8 elems per 32-elem row; 64 rows / 256 thr
  const int sg_ = tid & 3;                       // granule 0..3
  const int srA = tid >> 2;                      // row 0..63 within group
  const int swg = sg_ ^ (srA & 3) ^ ((srA >> 2) & 3);  // swizzled granule

  f32x4 acc[MI][NI] = {};
  const int nt = K / BK;

  uint4 ahR[A_IT], alR[A_IT], bhR[B_IT], blR[B_IT];

  auto loadRegs = [&](int kt) {
    const int k0 = kt * BK;
#pragma unroll
    for (int it = 0; it < A_IT; ++it) {
      const size_t base = (size_t)(rowBase + it * 64 + srA) * K + k0 + sg_ * 8;
      ahR[it] = *reinterpret_cast<const uint4*>(Ahi + base);
      alR[it] = *reinterpret_cast<const uint4*>(Alo + base);
    }
#pragma unroll
    for (int it = 0; it < B_IT; ++it) {
      const size_t base = (size_t)(colBase + it * 64 + srA) * K + k0 + sg_ * 8;
      bhR[it] = *reinterpret_cast<const uint4*>(Bhi + base);
      blR[it] = *reinterpret_cast<const uint4*>(Blo + base);
    }
  };

  auto writeLDS = [&](int buf) {
#pragma unroll
    for (int it = 0; it < A_IT; ++it) {
      const int off = ((it * 64 + srA) << 5) + (swg << 3);
      *reinterpret_cast<uint4*>(&AsH[buf][off]) = ahR[it];
      *reinterpret_cast<uint4*>(&AsL[buf][off]) = alR[it];
    }
#pragma unroll
    for (int it = 0; it < B_IT; ++it) {
      const int off = ((it * 64 + srA) << 5) + (swg << 3);
      *reinterpret_cast<uint4*>(&BsH[buf][off]) = bhR[it];
      *reinterpret_cast<uint4*>(&BsL[buf][off]) = blR[it];
    }
  };

  // prologue: tile0 -> LDS buf0; tile1 -> regs
  loadRegs(0);
  writeLDS(0);
  if (nt > 1) loadRegs(1);

  for (int t = 0; t < nt; ++t) {
    __syncthreads();
    const int cur = t & 1;
    if (t + 1 < nt) writeLDS(cur ^ 1);
    if (t + 2 < nt) loadRegs(t + 2);

    short8v ah[MI], al[MI], bh[NI], bl[NI];
#pragma unroll
    for (int mi = 0; mi < MI; ++mi) {
      const int r = wr * WT_M + mi * 16 + l15;
      const int g = l4 ^ (r & 3) ^ ((r >> 2) & 3);
      const int off = (r << 5) + (g << 3);
      ah[mi] = *reinterpret_cast<const short8v*>(&AsH[cur][off]);
      al[mi] = *reinterpret_cast<const short8v*>(&AsL[cur][off]);
    }
#pragma unroll
    for (int ni = 0; ni < NI; ++ni) {
      const int r = wc * WT_N + ni * 16 + l15;
      const int g = l4 ^ (r & 3) ^ ((r >> 2) & 3);
      const int off = (r << 5) + (g << 3);
      bh[ni] = *reinterpret_cast<const short8v*>(&BsH[cur][off]);
      bl[ni] = *reinterpret_cast<const short8v*>(&BsL[cur][off]);
    }
#pragma unroll
    for (int mi = 0; mi < MI; ++mi)
#pragma unroll
      for (int ni = 0; ni < NI; ++ni) {
        acc[mi][ni] = __builtin_amdgcn_mfma_f32_16x16x32_bf16(ah[mi], bh[ni], acc[mi][ni], 0, 0, 0);
        acc[mi][ni] = __builtin_amdgcn_mfma_f32_16x16x32_bf16(al[mi], bh[ni], acc[mi][ni], 0, 0, 0);
        acc[mi][ni] = __builtin_amdgcn_mfma_f32_16x16x32_bf16(ah[mi], bl[ni], acc[mi][ni], 0, 0, 0);
      }
  }

#pragma unroll
  for (int mi = 0; mi < MI; ++mi) {
#pragma unroll
    for (int ni = 0; ni < NI; ++ni) {
      const int col = colBase + wc * WT_N + ni * 16 + l15;
      const float bv = bias[col];
#pragma unroll
      for (int j = 0; j < 4; ++j) {
        const int row = rowBase + wr * WT_M + mi * 16 + l4 * 4 + j;
        float v = acc[mi][ni][j] + bv;
        if (RELU) v = fmaxf(v, 0.f);
        if (SPLIT_OUT) {
          unsigned short h, l;
          split_bf16(v, h, l);
          Chi[(size_t)row * N + col] = h;
          Clo[(size_t)row * N + col] = l;
        } else {
          C[(size_t)row * N + col] = v;
        }
      }
    }
  }
}

// ---------------------------------------------------------------------------
// K transpose: qkvb k-slice -> ktb[bh][d][kk]  (fp32)
// ---------------------------------------------------------------------------
__global__ __launch_bounds__(256) void txp_kernel(
    const float* __restrict__ qkvb, float* __restrict__ ktb) {
  __shared__ float tile[32][33];
  const int bh = blockIdx.z;
  const int b = bh >> 3, h = bh & 7;
  const int kk0 = blockIdx.x * 32, d0 = blockIdx.y * 32;
  const int tx = threadIdx.x & 31, ty = threadIdx.x >> 5;
#pragma unroll
  for (int i = 0; i < 4; ++i) {
    const int kk = kk0 + ty + i * 8;
    tile[ty + i * 8][tx] = qkvb[(size_t)(b * LL + kk) * QKVN + DM + h * DHD + d0 + tx];
  }
  __syncthreads();
#pragma unroll
  for (int i = 0; i < 4; ++i) {
    const int d = d0 + ty + i * 8;
    ktb[((size_t)bh * DHD + d) * LL + kk0 + tx] = tile[tx][ty + i * 8];
  }
}

// ---------------------------------------------------------------------------
// Fused attention (256 threads, 2 kk/thread) + XCD remap (h fastest) +
// lst row stride 12 words, float4 phase-1 stores.
// grid (NH, LL/TQ, BB), 256 threads.
// ---------------------------------------------------------------------------
constexpr int TQ = 8;

__global__ __launch_bounds__(256) void attn_kernel(
    const float* __restrict__ qkvb, const float* __restrict__ ktb,
    const float* __restrict__ kernS,
    unsigned short* __restrict__ ctxhi, unsigned short* __restrict__ ctxlo) {
  const int id = blockIdx.x + 8 * (blockIdx.y + 64 * blockIdx.z);
  const int w = (id & 7) * 512 + (id >> 3);
  const int h = w & 7;
  const int qt = (w >> 3) & 63;
  const int b = w >> 9;
  const int tid = threadIdx.x;
  const int q0 = qt * TQ;

  __shared__ float qst[DHD][TQ];   // 2 KB
  __shared__ float lst[LL][12];    // 24 KB, 48B row stride
  __shared__ float red[4][TQ][DHD];
  __shared__ float invS[TQ];

  {
    const int d = tid & 63;
    const int qq0 = tid >> 6;
#pragma unroll
    for (int rep = 0; rep < 2; ++rep) {
      const int qq = qq0 + rep * 4;
      qst[d][qq] = qkvb[(size_t)(b * LL + q0 + qq) * QKVN + h * DHD + d];
    }
  }
  __syncthreads();

  // phase 1: logits for kk = tid and kk+256
  {
    const int kk = tid;
    const float* kcol = ktb + (size_t)(b * NH + h) * DHD * LL;
    float dot0[TQ] = {}, dot1[TQ] = {};
#pragma unroll 4
    for (int d = 0; d < DHD; ++d) {
      const float ka = kcol[(size_t)d * LL + kk];
      const float kb2 = kcol[(size_t)d * LL + kk + 256];
      const float4 qa = *reinterpret_cast<const float4*>(&qst[d][0]);
      const float4 qb2 = *reinterpret_cast<const float4*>(&qst[d][4]);
      dot0[0] += qa.x * ka; dot0[1] += qa.y * ka; dot0[2] += qa.z * ka; dot0[3] += qa.w * ka;
      dot0[4] += qb2.x * ka; dot0[5] += qb2.y * ka; dot0[6] += qb2.z * ka; dot0[7] += qb2.w * ka;
      dot1[0] += qa.x * kb2; dot1[1] += qa.y * kb2; dot1[2] += qa.z * kb2; dot1[3] += qa.w * kb2;
      dot1[4] += qb2.x * kb2; dot1[5] += qb2.y * kb2; dot1[6] += qb2.z * kb2; dot1[7] += qb2.w * kb2;
    }
#pragma unroll
    for (int qq = 0; qq < TQ; ++qq) {
      const size_t kbase = ((size_t)b * LL + q0 + qq) * LL;
      dot0[qq] = dot0[qq] * 0.125f + kernS[kbase + kk];
      dot1[qq] = dot1[qq] * 0.125f + kernS[kbase + kk + 256];
    }
    float4 p;
    p.x = dot0[0]; p.y = dot0[1]; p.z = dot0[2]; p.w = dot0[3];
    *reinterpret_cast<float4*>(&lst[kk][0]) = p;
    p.x = dot0[4]; p.y = dot0[5]; p.z = dot0[6]; p.w = dot0[7];
    *reinterpret_cast<float4*>(&lst[kk][4]) = p;
    p.x = dot1[0]; p.y = dot1[1]; p.z = dot1[2]; p.w = dot1[3];
    *reinterpret_cast<float4*>(&lst[kk + 256][0]) = p;
    p.x = dot1[4]; p.y = dot1[5]; p.z = dot1[6]; p.w = dot1[7];
    *reinterpret_cast<float4*>(&lst[kk + 256][4]) = p;
  }
  __syncthreads();

  // softmax: 8 rows x 32 lanes
  {
    const int row = tid >> 5;
    const int l32 = tid & 31;
    float m = -1e30f;
#pragma unroll
    for (int j = 0; j < 16; ++j) m = fmaxf(m, lst[l32 + j * 32][row]);
#pragma unroll
    for (int s = 16; s; s >>= 1) m = fmaxf(m, __shfl_xor(m, s, 32));
    float sum = 0.f;
#pragma unroll
    for (int j = 0; j < 16; ++j) {
      const float e = __expf(lst[l32 + j * 32][row] - m);
      lst[l32 + j * 32][row] = e;
      sum += e;
    }
#pragma unroll
    for (int s = 16; s; s >>= 1) sum += __shfl_xor(sum, s, 32);
    if (l32 == 0) invS[row] = 1.0f / sum;
  }
  __syncthreads();

  // phase 2: ctx = P @ V
  const int d = tid & 63;
  const int c = tid >> 6;
  float acc[TQ] = {};
  {
    const float* vbase = qkvb + (size_t)(b * LL) * QKVN + 2 * DM + h * DHD + d;
    for (int kk = c * 128; kk < c * 128 + 128; ++kk) {
      const float vv = vbase[(size_t)kk * QKVN];
      const float4 pa = *reinterpret_cast<const float4*>(&lst[kk][0]);
      const float4 pb2 = *reinterpret_cast<const float4*>(&lst[kk][4]);
      acc[0] += pa.x * vv; acc[1] += pa.y * vv; acc[2] += pa.z * vv; acc[3] += pa.w * vv;
      acc[4] += pb2.x * vv; acc[5] += pb2.y * vv; acc[6] += pb2.z * vv; acc[7] += pb2.w * vv;
    }
  }
#pragma unroll
  for (int qq = 0; qq < TQ; ++qq) red[c][qq][d] = acc[qq];
  __syncthreads();
  if (c == 0) {
#pragma unroll
    for (int qq = 0; qq < TQ; ++qq) {
      const float r = ((red[0][qq][d] + red[1][qq][d]) + (red[2][qq][d] + red[3][qq][d])) * invS[qq];
      unsigned short hh, ll;
      split_bf16(r, hh, ll);
      const size_t o = (size_t)(b * LL + q0 + qq) * DM + h * DHD + d;
      ctxhi[o] = hh;
      ctxlo[o] = ll;
    }
  }
}

// ---------------------------------------------------------------------------
// Fused residual + LayerNorm; writes fp32 + bf16 hi/lo decomposition.
// ---------------------------------------------------------------------------
__global__ __launch_bounds__(256) void resid_ln_kernel(
    const float* __restrict__ X, const float* __restrict__ R,
    const float* __restrict__ g, const float* __restrict__ bta,
    float* __restrict__ Out, unsigned short* __restrict__ OutHi,
    unsigned short* __restrict__ OutLo) {
  const int row = blockIdx.x * 4 + (threadIdx.x >> 6);
  const int lane = threadIdx.x & 63;
  const float* x = X + (size_t)row * DM;
  const float* r = R + (size_t)row * DM;

  float v[8];
  float s = 0.f;
#pragma unroll
  for (int j = 0; j < 2; ++j) {
    const float4 a = *reinterpret_cast<const float4*>(x + lane * 8 + j * 4);
    const float4 c = *reinterpret_cast<const float4*>(r + lane * 8 + j * 4);
    v[j * 4 + 0] = a.x + c.x;
    v[j * 4 + 1] = a.y + c.y;
    v[j * 4 + 2] = a.z + c.z;
    v[j * 4 + 3] = a.w + c.w;
    s += v[j * 4 + 0] + v[j * 4 + 1] + v[j * 4 + 2] + v[j * 4 + 3];
  }
#pragma unroll
  for (int m = 1; m < 64; m <<= 1) s += __shfl_xor(s, m, 64);
  const float mean = s * (1.f / DM);
  float var = 0.f;
#pragma unroll
  for (int j = 0; j < 8; ++j) {
    const float dlt = v[j] - mean;
    var += dlt * dlt;
  }
#pragma unroll
  for (int m = 1; m < 64; m <<= 1) var += __shfl_xor(var, m, 64);
  var *= (1.f / DM);
  const float inv = 1.0f / sqrtf(var + 1e-6f);

  unsigned short hs[8], ls[8];
#pragma unroll
  for (int j = 0; j < 2; ++j) {
    const float4 gg = *reinterpret_cast<const float4*>(g + lane * 8 + j * 4);
    const float4 bb = *reinterpret_cast<const float4*>(bta + lane * 8 + j * 4);
    float4 o;
    o.x = (v[j * 4 + 0] - mean) * inv * gg.x + bb.x;
    o.y = (v[j * 4 + 1] - mean) * inv * gg.y + bb.y;
    o.z = (v[j * 4 + 2] - mean) * inv * gg.z + bb.z;
    o.w = (v[j * 4 + 3] - mean) * inv * gg.w + bb.w;
    *reinterpret_cast<float4*>(Out + (size_t)row * DM + lane * 8 + j * 4) = o;
    split_bf16(o.x, hs[j * 4 + 0], ls[j * 4 + 0]);
    split_bf16(o.y, hs[j * 4 + 1], ls[j * 4 + 1]);
    split_bf16(o.z, hs[j * 4 + 2], ls[j * 4 + 2]);
    split_bf16(o.w, hs[j * 4 + 3], ls[j * 4 + 3]);
  }
  uint4 hv, lv;
  hv.x = (unsigned)hs[0] | ((unsigned)hs[1] << 16);
  hv.y = (unsigned)hs[2] | ((unsigned)hs[3] << 16);
  hv.z = (unsigned)hs[4] | ((unsigned)hs[5] << 16);
  hv.w = (unsigned)hs[6] | ((unsigned)hs[7] << 16);
  lv.x = (unsigned)ls[0] | ((unsigned)ls[1] << 16);
  lv.y = (unsigned)ls[2] | ((unsigned)ls[3] << 16);
  lv.z = (unsigned)ls[4] | ((unsigned)ls[5] << 16);
  lv.w = (unsigned)ls[6] | ((unsigned)ls[7] << 16);
  *reinterpret_cast<uint4*>(OutHi + (size_t)row * DM + lane * 8) = hv;
  *reinterpret_cast<uint4*>(OutLo + (size_t)row * DM + lane * 8) = lv;
}

// ---------------------------------------------------------------------------
// launch
// ---------------------------------------------------------------------------
extern "C" void kernel_launch(void* const* d_in, const int* in_sizes, int n_in,
                              void* d_out, int out_size, void* d_ws, size_t ws_size,
                              hipStream_t stream) {
  const float* x_in = (const float*)d_in[0];
  const float* t = (const float*)d_in[1];
  const float* wq = (const float*)d_in[2];
  const float* bq = (const float*)d_in[3];
  const float* wk = (const float*)d_in[4];
  const float* bk = (const float*)d_in[5];
  const float* wv = (const float*)d_in[6];
  const float* bv = (const float*)d_in[7];
  const float* wo = (const float*)d_in[8];
  const float* bo = (const float*)d_in[9];
  const float* w1 = (const float*)d_in[10];
  const float* b1 = (const float*)d_in[11];
  const float* w2 = (const float*)d_in[12];
  const float* b2 = (const float*)d_in[13];
  const float* ln1g = (const float*)d_in[14];
  const float* ln1b = (const float*)d_in[15];
  const float* ln2g = (const float*)d_in[16];
  const float* ln2b = (const float*)d_in[17];
  const float* pw1 = (const float*)d_in[18];
  const float* pb1 = (const float*)d_in[19];
  const float* pw2 = (const float*)d_in[20];
  const float* pb2 = (const float*)d_in[21];
  const float* sw1 = (const float*)d_in[22];
  const float* sb1 = (const float*)d_in[23];
  const float* sw2 = (const float*)d_in[24];
  const float* sb2 = (const float*)d_in[25];
  const float* bw1 = (const float*)d_in[26];
  const float* bb1 = (const float*)d_in[27];
  const float* bw2 = (const float*)d_in[28];
  const float* bb2 = (const float*)d_in[29];

  char* wsb = (char*)d_ws;
  size_t off = 0;
  auto allocB = [&](size_t bytes) {
    char* p = wsb + off;
    off += (bytes + 255) & ~(size_t)255;
    return p;
  };
  float* tpb = (float*)allocB(ROWS * TD * 4);
  float* sgb = (float*)allocB(ROWS * TD * 4);
  float* beb = (float*)allocB(ROWS * TD * 4);
  float* kernS = (float*)allocB((size_t)BB * LL * LL * 4);
  float* qkvb = (float*)allocB((size_t)ROWS * QKVN * 4);        // } h hi/lo aliases
  float* ktb = (float*)allocB((size_t)BB * NH * DHD * LL * 4);  // } this region
  float* ao = (float*)allocB((size_t)ROWS * DM * 4);
  float* xb = (float*)allocB((size_t)ROWS * DM * 4);
  float* fb = (float*)allocB((size_t)ROWS * DM * 4);
  float* xn = (float*)allocB((size_t)ROWS * DM * 4);
  float* qkvbias = (float*)allocB(QKVN * 4);
  unsigned short* qkvwt_hi = (unsigned short*)allocB((size_t)QKVN * DM * 2);
  unsigned short* qkvwt_lo = (unsigned short*)allocB((size_t)QKVN * DM * 2);
  unsigned short* wot_hi = (unsigned short*)allocB((size_t)DM * DM * 2);
  unsigned short* wot_lo = (unsigned short*)allocB((size_t)DM * DM * 2);
  unsigned short* w1t_hi = (unsigned short*)allocB((size_t)FF * DM * 2);
  unsigned short* w1t_lo = (unsigned short*)allocB((size_t)FF * DM * 2);
  unsigned short* w2t_hi = (unsigned short*)allocB((size_t)DM * FF * 2);
  unsigned short* w2t_lo = (unsigned short*)allocB((size_t)DM * FF * 2);
  unsigned short* xhi = (unsigned short*)allocB((size_t)ROWS * DM * 2);
  unsigned short* xlo = (unsigned short*)allocB((size_t)ROWS * DM * 2);
  unsigned short* ctxhi = (unsigned short*)allocB((size_t)ROWS * DM * 2);
  unsigned short* ctxlo = (unsigned short*)allocB((size_t)ROWS * DM * 2);
  unsigned short* hhi = (unsigned short*)qkvb;
  unsigned short* hlo = hhi + (size_t)ROWS * FF;

  const float* xcur = x_in;

  for (int i = 0; i < NLAYERS; ++i) {
    td_kernel<<<dim3(16, 16), 256, 0, stream>>>(wq + (size_t)i * DM * DM, qkvwt_hi, qkvwt_lo, DM, DM);
    td_kernel<<<dim3(16, 16), 256, 0, stream>>>(wk + (size_t)i * DM * DM, qkvwt_hi + (size_t)DM * DM, qkvwt_lo + (size_t)DM * DM, DM, DM);
    td_kernel<<<dim3(16, 16), 256, 0, stream>>>(wv + (size_t)i * DM * DM, qkvwt_hi + (size_t)2 * DM * DM, qkvwt_lo + (size_t)2 * DM * DM, DM, DM);
    td_kernel<<<dim3(16, 16), 256, 0, stream>>>(wo + (size_t)i * DM * DM, wot_hi, wot_lo, DM, DM);
    td_kernel<<<dim3(16, 64), 256, 0, stream>>>(w1 + (size_t)i * DM * FF, w1t_hi, w1t_lo, DM, FF);
    td_kernel<<<dim3(64, 16), 256, 0, stream>>>(w2 + (size_t)i * FF * DM, w2t_hi, w2t_lo, FF, DM);
    qkvbias_kernel<<<(QKVN + 255) / 256, 256, 0, stream>>>(bq + i * DM, bk + i * DM, bv + i * DM, qkvbias);

    small_ffn_kernel<<<ROWS / 256, 256, 0, stream>>>(
        t, pw1 + i * TD, pb1 + i * TD, pw2 + i * TD * TD, pb2 + i * TD,
        sw1 + i * TD, sb1 + i * TD, sw2 + i * TD * TD, sb2 + i * TD,
        bw1 + i * TD, bb1 + i * TD, bw2 + i * TD * TD, bb2 + i * TD,
        tpb, sgb, beb);
    kern_kernel<<<dim3(LL / 256, LL, BB), 256, 0, stream>>>(t, tpb, sgb, beb, kernS);

    if (i == 0) {
      decomp_kernel<<<(ROWS * DM / 4 + 255) / 256, 256, 0, stream>>>(x_in, xhi, xlo, ROWS * DM / 4);
    }

    gemm_mfma<128, false, false><<<dim3(QKVN / 128, ROWS / 128), 256, 0, stream>>>(
        xhi, xlo, qkvwt_hi, qkvwt_lo, qkvbias, qkvb, nullptr, nullptr, ROWS, QKVN, DM);

    txp_kernel<<<dim3(LL / 32, DHD / 32, BB * NH), 256, 0, stream>>>(qkvb, ktb);

    attn_kernel<<<dim3(NH, LL / TQ, BB), 256, 0, stream>>>(qkvb, ktb, kernS, ctxhi, ctxlo);

    gemm_mfma<64, false, false><<<dim3(DM / 64, ROWS / 128), 256, 0, stream>>>(
        ctxhi, ctxlo, wot_hi, wot_lo, bo + i * DM, ao, nullptr, nullptr, ROWS, DM, DM);

    resid_ln_kernel<<<ROWS / 4, 256, 0, stream>>>(
        xcur, ao, ln1g + i * DM, ln1b + i * DM, xb, xhi, xlo);

    gemm_mfma<128, true, true><<<dim3(FF / 128, ROWS / 128), 256, 0, stream>>>(
        xhi, xlo, w1t_hi, w1t_lo, b1 + i * FF, nullptr, hhi, hlo, ROWS, FF, DM);

    gemm_mfma<64, false, false><<<dim3(DM / 64, ROWS / 128), 256, 0, stream>>>(
        hhi, hlo, w2t_hi, w2t_lo, b2 + i * DM, fb, nullptr, nullptr, ROWS, DM, FF);

    float* ln2_out = (i == NLAYERS - 1) ? (float*)d_out : xn;
    resid_ln_kernel<<<ROWS / 4, 256, 0, stream>>>(
        xb, fb, ln2g + i * DM, ln2b + i * DM, ln2_out, xhi, xlo);

    xcur = xn;
  }
}

// Round 7
// 851.192 us; speedup vs baseline: 1.3486x; 1.0250x over previous
//
#include <hip/hip_runtime.h>
#include <hip/hip_bf16.h>

#define DEV_INLINE __device__ __forceinline__

constexpr int NLAYERS = 2;
constexpr int DM = 512;
constexpr int NH = 8;
constexpr int DHD = 64;
constexpr int FF = 2048;
constexpr int TD = 8;
constexpr int BB = 8;
constexpr int LL = 512;
constexpr int ROWS = BB * LL;  // 4096
constexpr int QKVN = 3 * DM;   // 1536

constexpr float TWO_PI_F = 6.28318530717958647692f;
constexpr float INV_E8 = 3.3546262790251185e-4f;  // e^-8

typedef __attribute__((ext_vector_type(8))) short short8v;
typedef __attribute__((ext_vector_type(4))) float f32x4;

DEV_INLINE unsigned short bf16_rne(float x) {
  unsigned int u = __float_as_uint(x);
  unsigned int r = (u + 0x7fffu + ((u >> 16) & 1u)) >> 16;
  return (unsigned short)r;
}
DEV_INLINE float bf16_to_f(unsigned short h) {
  return __uint_as_float(((unsigned int)h) << 16);
}
DEV_INLINE void split_bf16(float x, unsigned short& h, unsigned short& l) {
  h = bf16_rne(x);
  float lo = x - bf16_to_f(h);
  l = bf16_rne(lo);
}

// ---------------------------------------------------------------------------
// Small FFNs on t
// ---------------------------------------------------------------------------
DEV_INLINE void ffn2_small(float tv,
                           const float* __restrict__ w1, const float* __restrict__ b1,
                           const float* __restrict__ w2, const float* __restrict__ b2,
                           float* out) {
  float h[TD];
#pragma unroll
  for (int d = 0; d < TD; ++d) h[d] = fmaxf(tv * w1[d] + b1[d], 0.f);
#pragma unroll
  for (int j = 0; j < TD; ++j) {
    float acc = b2[j];
#pragma unroll
    for (int d = 0; d < TD; ++d) acc += h[d] * w2[d * TD + j];
    out[j] = fmaxf(acc, 0.f);
  }
}

__global__ __launch_bounds__(256) void small_ffn_kernel(
    const float* __restrict__ t,
    const float* __restrict__ pw1, const float* __restrict__ pb1,
    const float* __restrict__ pw2, const float* __restrict__ pb2,
    const float* __restrict__ sw1, const float* __restrict__ sb1,
    const float* __restrict__ sw2, const float* __restrict__ sb2,
    const float* __restrict__ bw1, const float* __restrict__ bb1,
    const float* __restrict__ bw2, const float* __restrict__ bb2,
    float* __restrict__ tp, float* __restrict__ sg, float* __restrict__ be) {
  const int i = blockIdx.x * 256 + threadIdx.x;
  if (i >= ROWS) return;
  const float tv = t[i];
  float o[TD];
  ffn2_small(tv, pw1, pb1, pw2, pb2, o);
#pragma unroll
  for (int d = 0; d < TD; ++d) tp[(size_t)i * TD + d] = TWO_PI_F * o[d] * tv;
  ffn2_small(tv, sw1, sb1, sw2, sb2, o);
#pragma unroll
  for (int d = 0; d < TD; ++d) sg[(size_t)i * TD + d] = o[d] + 1e-6f;
  ffn2_small(tv, bw1, bb1, bw2, bb2, o);
#pragma unroll
  for (int d = 0; d < TD; ++d) be[(size_t)i * TD + d] = o[d];
}

// ---------------------------------------------------------------------------
// kern kernel
// ---------------------------------------------------------------------------
DEV_INLINE void load8(const float* __restrict__ p, float* o) {
  float4 a = *reinterpret_cast<const float4*>(p);
  float4 b = *reinterpret_cast<const float4*>(p + 4);
  o[0] = a.x; o[1] = a.y; o[2] = a.z; o[3] = a.w;
  o[4] = b.x; o[5] = b.y; o[6] = b.z; o[7] = b.w;
}

__global__ __launch_bounds__(256) void kern_kernel(
    const float* __restrict__ t, const float* __restrict__ tp,
    const float* __restrict__ sg, const float* __restrict__ be,
    float* __restrict__ kernS) {
  const int k = blockIdx.x * 256 + threadIdx.x;
  const int q = blockIdx.y;
  const int b = blockIdx.z;
  const size_t iq = (size_t)b * LL + q;
  const size_t ik = (size_t)b * LL + k;
  const float tq = t[iq], tk = t[ik];
  const float diff = tq - tk;
  const float d2 = diff * diff;

  float tpq[TD], sgq[TD], beq[TD], tpk[TD], sgk[TD], bek[TD];
  load8(tp + iq * TD, tpq);
  load8(sg + iq * TD, sgq);
  load8(be + iq * TD, beq);
  load8(tp + ik * TD, tpk);
  load8(sg + ik * TD, sgk);
  load8(be + ik * TD, bek);

  float acc = 0.f;
#pragma unroll
  for (int d = 0; d < TD; ++d) {
    const float sq = sgq[d], sk = sgk[d];
    const float denom = sq * sq + sk * sk;
    const float inv = 1.0f / denom;
    const float e = __expf(-d2 * inv);
    const float loc = sqrtf(2.0f * sq * sk * inv);
    const float c = __cosf(tpq[d] - tpk[d]);
    acc += beq[d] * bek[d] * loc * e * c;
  }
  kernS[((size_t)b * LL + q) * LL + k] = acc * INV_E8;
}

// ---------------------------------------------------------------------------
// Weight transpose + hi/lo bf16 decompose: W[K][N] fp32 -> Thi/Tlo[N][K] bf16
// ---------------------------------------------------------------------------
__global__ __launch_bounds__(256) void td_kernel(
    const float* __restrict__ W, unsigned short* __restrict__ Thi,
    unsigned short* __restrict__ Tlo, int K, int N) {
  __shared__ float tile[32][33];
  const int k0 = blockIdx.x * 32, n0 = blockIdx.y * 32;
  const int tx = threadIdx.x & 31, ty = threadIdx.x >> 5;
#pragma unroll
  for (int i = 0; i < 4; ++i)
    tile[ty + i * 8][tx] = W[(size_t)(k0 + ty + i * 8) * N + n0 + tx];
  __syncthreads();
#pragma unroll
  for (int i = 0; i < 4; ++i) {
    const int n = n0 + ty + i * 8;
    const float v = tile[tx][ty + i * 8];
    unsigned short h, l;
    split_bf16(v, h, l);
    Thi[(size_t)n * K + k0 + tx] = h;
    Tlo[(size_t)n * K + k0 + tx] = l;
  }
}

// ---------------------------------------------------------------------------
// Elementwise hi/lo decompose (for layer-0 x). 4 elems/thread.
// ---------------------------------------------------------------------------
__global__ __launch_bounds__(256) void decomp_kernel(
    const float* __restrict__ X, unsigned short* __restrict__ Hi,
    unsigned short* __restrict__ Lo, int n4) {
  const int i = blockIdx.x * 256 + threadIdx.x;
  if (i >= n4) return;
  const float4 v = *reinterpret_cast<const float4*>(X + (size_t)i * 4);
  unsigned short h0, h1, h2, h3, l0, l1, l2, l3;
  split_bf16(v.x, h0, l0);
  split_bf16(v.y, h1, l1);
  split_bf16(v.z, h2, l2);
  split_bf16(v.w, h3, l3);
  uint2 hv, lv;
  hv.x = (unsigned)h0 | ((unsigned)h1 << 16);
  hv.y = (unsigned)h2 | ((unsigned)h3 << 16);
  lv.x = (unsigned)l0 | ((unsigned)l1 << 16);
  lv.y = (unsigned)l2 | ((unsigned)l3 << 16);
  *reinterpret_cast<uint2*>(Hi + (size_t)i * 4) = hv;
  *reinterpret_cast<uint2*>(Lo + (size_t)i * 4) = lv;
}

__global__ __launch_bounds__(256) void qkvbias_kernel(
    const float* __restrict__ bq, const float* __restrict__ bk,
    const float* __restrict__ bv, float* __restrict__ out) {
  const int i = blockIdx.x * 256 + threadIdx.x;
  if (i >= QKVN) return;
  out[i] = i < DM ? bq[i] : (i < 2 * DM ? bk[i - DM] : bv[i - 2 * DM]);
}

// ---------------------------------------------------------------------------
// Split-bf16 MFMA GEMM: C = Ahi@Bhi + Alo@Bhi + Ahi@Blo (+bias, opt relu)
// BK=32, double-buffered LDS, one barrier per k-tile, reg prefetch 2 ahead.
// ---------------------------------------------------------------------------
template <int BN, bool RELU, bool SPLIT_OUT>
__global__ __launch_bounds__(256) void gemm_mfma(
    const unsigned short* __restrict__ Ahi, const unsigned short* __restrict__ Alo,
    const unsigned short* __restrict__ Bhi, const unsigned short* __restrict__ Blo,
    const float* __restrict__ bias, float* __restrict__ C,
    unsigned short* __restrict__ Chi, unsigned short* __restrict__ Clo,
    int M, int N, int K) {
  constexpr int BM = 128, BK = 32;
  constexpr int WT_M = 64;
  constexpr int WT_N = BN / 2;
  constexpr int MI = WT_M / 16;   // 4
  constexpr int NI = WT_N / 16;   // 4 or 2
  constexpr int A_IT = BM * BK / (256 * 8);  // 2
  constexpr int B_IT = BN * BK / (256 * 8);  // 2 or 1

  __shared__ unsigned short AsH[2][BM * BK];
  __shared__ unsigned short AsL[2][BM * BK];
  __shared__ unsigned short BsH[2][BN * BK];
  __shared__ unsigned short BsL[2][BN * BK];

  const int nwg = gridDim.x * gridDim.y;
  const int orig = blockIdx.y * gridDim.x + blockIdx.x;
  const int swz = (orig & 7) * (nwg >> 3) + (orig >> 3);
  const int bx = swz % gridDim.x;
  const int by = swz / gridDim.x;

  const int tid = threadIdx.x;
  const int lane = tid & 63;
  const int wid = tid >> 6;
  const int wr = wid >> 1, wc = wid & 1;
  const int rowBase = by * BM;
  const int colBase = bx * BN;
  const int l15 = lane & 15, l4 = lane >> 4;

  const int sg_ = tid & 3;
  const int srA = tid >> 2;
  const int swg = sg_ ^ (srA & 3) ^ ((srA >> 2) & 3);

  f32x4 acc[MI][NI] = {};
  const int nt = K / BK;

  uint4 ahR[A_IT], alR[A_IT], bhR[B_IT], blR[B_IT];

  auto loadRegs = [&](int kt) {
    const int k0 = kt * BK;
#pragma unroll
    for (int it = 0; it < A_IT; ++it) {
      const size_t base = (size_t)(rowBase + it * 64 + srA) * K + k0 + sg_ * 8;
      ahR[it] = *reinterpret_cast<const uint4*>(Ahi + base);
      alR[it] = *reinterpret_cast<const uint4*>(Alo + base);
    }
#pragma unroll
    for (int it = 0; it < B_IT; ++it) {
      const size_t base = (size_t)(colBase + it * 64 + srA) * K + k0 + sg_ * 8;
      bhR[it] = *reinterpret_cast<const uint4*>(Bhi + base);
      blR[it] = *reinterpret_cast<const uint4*>(Blo + base);
    }
  };

  auto writeLDS = [&](int buf) {
#pragma unroll
    for (int it = 0; it < A_IT; ++it) {
      const int off = ((it * 64 + srA) << 5) + (swg << 3);
      *reinterpret_cast<uint4*>(&AsH[buf][off]) = ahR[it];
      *reinterpret_cast<uint4*>(&AsL[buf][off]) = alR[it];
    }
#pragma unroll
    for (int it = 0; it < B_IT; ++it) {
      const int off = ((it * 64 + srA) << 5) + (swg << 3);
      *reinterpret_cast<uint4*>(&BsH[buf][off]) = bhR[it];
      *reinterpret_cast<uint4*>(&BsL[buf][off]) = blR[it];
    }
  };

  loadRegs(0);
  writeLDS(0);
  if (nt > 1) loadRegs(1);

  for (int t = 0; t < nt; ++t) {
    __syncthreads();
    const int cur = t & 1;
    if (t + 1 < nt) writeLDS(cur ^ 1);
    if (t + 2 < nt) loadRegs(t + 2);

    short8v ah[MI], al[MI], bh[NI], bl[NI];
#pragma unroll
    for (int mi = 0; mi < MI; ++mi) {
      const int r = wr * WT_M + mi * 16 + l15;
      const int g = l4 ^ (r & 3) ^ ((r >> 2) & 3);
      const int off = (r << 5) + (g << 3);
      ah[mi] = *reinterpret_cast<const short8v*>(&AsH[cur][off]);
      al[mi] = *reinterpret_cast<const short8v*>(&AsL[cur][off]);
    }
#pragma unroll
    for (int ni = 0; ni < NI; ++ni) {
      const int r = wc * WT_N + ni * 16 + l15;
      const int g = l4 ^ (r & 3) ^ ((r >> 2) & 3);
      const int off = (r << 5) + (g << 3);
      bh[ni] = *reinterpret_cast<const short8v*>(&BsH[cur][off]);
      bl[ni] = *reinterpret_cast<const short8v*>(&BsL[cur][off]);
    }
#pragma unroll
    for (int mi = 0; mi < MI; ++mi)
#pragma unroll
      for (int ni = 0; ni < NI; ++ni) {
        acc[mi][ni] = __builtin_amdgcn_mfma_f32_16x16x32_bf16(ah[mi], bh[ni], acc[mi][ni], 0, 0, 0);
        acc[mi][ni] = __builtin_amdgcn_mfma_f32_16x16x32_bf16(al[mi], bh[ni], acc[mi][ni], 0, 0, 0);
        acc[mi][ni] = __builtin_amdgcn_mfma_f32_16x16x32_bf16(ah[mi], bl[ni], acc[mi][ni], 0, 0, 0);
      }
  }

#pragma unroll
  for (int mi = 0; mi < MI; ++mi) {
#pragma unroll
    for (int ni = 0; ni < NI; ++ni) {
      const int col = colBase + wc * WT_N + ni * 16 + l15;
      const float bv = bias[col];
#pragma unroll
      for (int j = 0; j < 4; ++j) {
        const int row = rowBase + wr * WT_M + mi * 16 + l4 * 4 + j;
        float v = acc[mi][ni][j] + bv;
        if (RELU) v = fmaxf(v, 0.f);
        if (SPLIT_OUT) {
          unsigned short h, l;
          split_bf16(v, h, l);
          Chi[(size_t)row * N + col] = h;
          Clo[(size_t)row * N + col] = l;
        } else {
          C[(size_t)row * N + col] = v;
        }
      }
    }
  }
}

// ---------------------------------------------------------------------------
// V transpose (bf16 hi/lo): qkv V-slice -> vtb[bh][d][kk]
// grid (LL/32, DHD/32, BB*NH), 256 threads
// ---------------------------------------------------------------------------
__global__ __launch_bounds__(256) void vtxp_kernel(
    const unsigned short* __restrict__ qkvhi, const unsigned short* __restrict__ qkvlo,
    unsigned short* __restrict__ vtbhi, unsigned short* __restrict__ vtblo) {
  __shared__ unsigned short th[32][33], tl[32][33];
  const int bh = blockIdx.z;
  const int b = bh >> 3, h = bh & 7;
  const int kk0 = blockIdx.x * 32, d0 = blockIdx.y * 32;
  const int tx = threadIdx.x & 31, ty = threadIdx.x >> 5;
#pragma unroll
  for (int i = 0; i < 4; ++i) {
    const int kk = kk0 + ty + i * 8;
    const size_t src = (size_t)(b * LL + kk) * QKVN + 2 * DM + h * DHD + d0 + tx;
    th[ty + i * 8][tx] = qkvhi[src];
    tl[ty + i * 8][tx] = qkvlo[src];
  }
  __syncthreads();
#pragma unroll
  for (int i = 0; i < 4; ++i) {
    const int d = d0 + ty + i * 8;
    const size_t dst = ((size_t)bh * DHD + d) * LL + kk0 + tx;
    vtbhi[dst] = th[tx][ty + i * 8];
    vtblo[dst] = tl[tx][ty + i * 8];
  }
}

// ---------------------------------------------------------------------------
// MFMA attention: block = 16 q rows of one (b,h). 256 threads (4 waves).
// Phase A: S = split-bf16 MFMA QK^T * 0.125 + kern  -> LDS (f32)
// Phase B: softmax (rowwise), P split to bf16 hi/lo in LDS
// Phase C: O = P@V via MFMA with V^T[bh][d][kk]; normalize; split write ctx.
// XCD remap keeps kernS/K/V of one b on one XCD's L2.
// ---------------------------------------------------------------------------
constexpr int ATQ = 16;

__global__ __launch_bounds__(256) void attn_mfma(
    const unsigned short* __restrict__ qkvhi, const unsigned short* __restrict__ qkvlo,
    const unsigned short* __restrict__ vtbhi, const unsigned short* __restrict__ vtblo,
    const float* __restrict__ kernS,
    unsigned short* __restrict__ ctxhi, unsigned short* __restrict__ ctxlo) {
  const int id = blockIdx.x;
  const int w = (id & 7) * 256 + (id >> 3);  // 2048 blocks, bijective
  const int h = w & 7;
  const int qt = (w >> 3) & 31;
  const int b = w >> 8;
  const int tid = threadIdx.x;
  const int lane = tid & 63;
  const int wv = tid >> 6;
  const int l15 = lane & 15, l4 = lane >> 4;
  const int q0 = qt * ATQ;

  __shared__ float S[ATQ][521];             // 33.3 KB, stride 521 (~2-way banks)
  __shared__ unsigned short Phi[ATQ][520];  // 16.6 KB, 1040B rows (16B-aligned)
  __shared__ unsigned short Plo[ATQ][520];
  __shared__ float sinv[ATQ];

  // Q fragments (A operand), held in regs for all of phase A
  short8v qh[2], ql[2];
  {
    const size_t qbase = (size_t)(b * LL + q0 + l15) * QKVN + h * DHD;
#pragma unroll
    for (int ks = 0; ks < 2; ++ks) {
      qh[ks] = *reinterpret_cast<const short8v*>(qkvhi + qbase + ks * 32 + l4 * 8);
      ql[ks] = *reinterpret_cast<const short8v*>(qkvlo + qbase + ks * 32 + l4 * 8);
    }
  }

  // phase A: wave wv covers kk in [wv*128, wv*128+128), 8 tiles of 16
  for (int nt = 0; nt < 8; ++nt) {
    const int kk0 = wv * 128 + nt * 16;
    const size_t kbase = (size_t)(b * LL + kk0 + l15) * QKVN + DM + h * DHD;
    f32x4 acc = {};
#pragma unroll
    for (int ks = 0; ks < 2; ++ks) {
      const short8v kh = *reinterpret_cast<const short8v*>(qkvhi + kbase + ks * 32 + l4 * 8);
      const short8v kl = *reinterpret_cast<const short8v*>(qkvlo + kbase + ks * 32 + l4 * 8);
      acc = __builtin_amdgcn_mfma_f32_16x16x32_bf16(qh[ks], kh, acc, 0, 0, 0);
      acc = __builtin_amdgcn_mfma_f32_16x16x32_bf16(ql[ks], kh, acc, 0, 0, 0);
      acc = __builtin_amdgcn_mfma_f32_16x16x32_bf16(qh[ks], kl, acc, 0, 0, 0);
    }
#pragma unroll
    for (int j = 0; j < 4; ++j) {
      const int row = l4 * 4 + j;
      S[row][kk0 + l15] =
          acc[j] * 0.125f + kernS[((size_t)b * LL + q0 + row) * LL + kk0 + l15];
    }
  }
  __syncthreads();

  // phase B: softmax; thread (r = tid>>4, c = tid&15) handles 32 cols
  {
    const int r = tid >> 4, c = tid & 15;
    float m = -1e30f;
#pragma unroll
    for (int j = 0; j < 32; ++j) m = fmaxf(m, S[r][c + j * 16]);
#pragma unroll
    for (int s = 8; s; s >>= 1) m = fmaxf(m, __shfl_xor(m, s, 16));
    float sum = 0.f;
#pragma unroll
    for (int j = 0; j < 32; ++j) {
      const float e = __expf(S[r][c + j * 16] - m);
      unsigned short hh, ll;
      split_bf16(e, hh, ll);
      Phi[r][c + j * 16] = hh;
      Plo[r][c + j * 16] = ll;
      sum += e;
    }
#pragma unroll
    for (int s = 8; s; s >>= 1) sum += __shfl_xor(sum, s, 16);
    if (c == 0) sinv[r] = 1.0f / sum;
  }
  __syncthreads();

  // phase C: O = P@V; wave wv owns d-cols [wv*16, wv*16+16)
  {
    const int d0 = wv * 16;
    const size_t vbase = ((size_t)(b * NH + h) * DHD + d0 + l15) * LL;
    f32x4 acc = {};
    for (int kt = 0; kt < 16; ++kt) {
      const int kk0 = kt * 32;
      const short8v ph = *reinterpret_cast<const short8v*>(&Phi[l15][kk0 + l4 * 8]);
      const short8v pl = *reinterpret_cast<const short8v*>(&Plo[l15][kk0 + l4 * 8]);
      const short8v vh = *reinterpret_cast<const short8v*>(vtbhi + vbase + kk0 + l4 * 8);
      const short8v vl = *reinterpret_cast<const short8v*>(vtblo + vbase + kk0 + l4 * 8);
      acc = __builtin_amdgcn_mfma_f32_16x16x32_bf16(ph, vh, acc, 0, 0, 0);
      acc = __builtin_amdgcn_mfma_f32_16x16x32_bf16(pl, vh, acc, 0, 0, 0);
      acc = __builtin_amdgcn_mfma_f32_16x16x32_bf16(ph, vl, acc, 0, 0, 0);
    }
#pragma unroll
    for (int j = 0; j < 4; ++j) {
      const int row = l4 * 4 + j;
      const float o = acc[j] * sinv[row];
      unsigned short hh, ll;
      split_bf16(o, hh, ll);
      const size_t oo = (size_t)(b * LL + q0 + row) * DM + h * DHD + d0 + l15;
      ctxhi[oo] = hh;
      ctxlo[oo] = ll;
    }
  }
}

// ---------------------------------------------------------------------------
// Fused residual + LayerNorm; writes fp32 + bf16 hi/lo decomposition.
// ---------------------------------------------------------------------------
__global__ __launch_bounds__(256) void resid_ln_kernel(
    const float* __restrict__ X, const float* __restrict__ R,
    const float* __restrict__ g, const float* __restrict__ bta,
    float* __restrict__ Out, unsigned short* __restrict__ OutHi,
    unsigned short* __restrict__ OutLo) {
  const int row = blockIdx.x * 4 + (threadIdx.x >> 6);
  const int lane = threadIdx.x & 63;
  const float* x = X + (size_t)row * DM;
  const float* r = R + (size_t)row * DM;

  float v[8];
  float s = 0.f;
#pragma unroll
  for (int j = 0; j < 2; ++j) {
    const float4 a = *reinterpret_cast<const float4*>(x + lane * 8 + j * 4);
    const float4 c = *reinterpret_cast<const float4*>(r + lane * 8 + j * 4);
    v[j * 4 + 0] = a.x + c.x;
    v[j * 4 + 1] = a.y + c.y;
    v[j * 4 + 2] = a.z + c.z;
    v[j * 4 + 3] = a.w + c.w;
    s += v[j * 4 + 0] + v[j * 4 + 1] + v[j * 4 + 2] + v[j * 4 + 3];
  }
#pragma unroll
  for (int m = 1; m < 64; m <<= 1) s += __shfl_xor(s, m, 64);
  const float mean = s * (1.f / DM);
  float var = 0.f;
#pragma unroll
  for (int j = 0; j < 8; ++j) {
    const float dlt = v[j] - mean;
    var += dlt * dlt;
  }
#pragma unroll
  for (int m = 1; m < 64; m <<= 1) var += __shfl_xor(var, m, 64);
  var *= (1.f / DM);
  const float inv = 1.0f / sqrtf(var + 1e-6f);

  unsigned short hs[8], ls[8];
#pragma unroll
  for (int j = 0; j < 2; ++j) {
    const float4 gg = *reinterpret_cast<const float4*>(g + lane * 8 + j * 4);
    const float4 bb = *reinterpret_cast<const float4*>(bta + lane * 8 + j * 4);
    float4 o;
    o.x = (v[j * 4 + 0] - mean) * inv * gg.x + bb.x;
    o.y = (v[j * 4 + 1] - mean) * inv * gg.y + bb.y;
    o.z = (v[j * 4 + 2] - mean) * inv * gg.z + bb.z;
    o.w = (v[j * 4 + 3] - mean) * inv * gg.w + bb.w;
    *reinterpret_cast<float4*>(Out + (size_t)row * DM + lane * 8 + j * 4) = o;
    split_bf16(o.x, hs[j * 4 + 0], ls[j * 4 + 0]);
    split_bf16(o.y, hs[j * 4 + 1], ls[j * 4 + 1]);
    split_bf16(o.z, hs[j * 4 + 2], ls[j * 4 + 2]);
    split_bf16(o.w, hs[j * 4 + 3], ls[j * 4 + 3]);
  }
  uint4 hv, lv;
  hv.x = (unsigned)hs[0] | ((unsigned)hs[1] << 16);
  hv.y = (unsigned)hs[2] | ((unsigned)hs[3] << 16);
  hv.z = (unsigned)hs[4] | ((unsigned)hs[5] << 16);
  hv.w = (unsigned)hs[6] | ((unsigned)hs[7] << 16);
  lv.x = (unsigned)ls[0] | ((unsigned)ls[1] << 16);
  lv.y = (unsigned)ls[2] | ((unsigned)ls[3] << 16);
  lv.z = (unsigned)ls[4] | ((unsigned)ls[5] << 16);
  lv.w = (unsigned)ls[6] | ((unsigned)ls[7] << 16);
  *reinterpret_cast<uint4*>(OutHi + (size_t)row * DM + lane * 8) = hv;
  *reinterpret_cast<uint4*>(OutLo + (size_t)row * DM + lane * 8) = lv;
}

// ---------------------------------------------------------------------------
// launch
// ---------------------------------------------------------------------------
extern "C" void kernel_launch(void* const* d_in, const int* in_sizes, int n_in,
                              void* d_out, int out_size, void* d_ws, size_t ws_size,
                              hipStream_t stream) {
  const float* x_in = (const float*)d_in[0];
  const float* t = (const float*)d_in[1];
  const float* wq = (const float*)d_in[2];
  const float* bq = (const float*)d_in[3];
  const float* wk = (const float*)d_in[4];
  const float* bk = (const float*)d_in[5];
  const float* wv = (const float*)d_in[6];
  const float* bv = (const float*)d_in[7];
  const float* wo = (const float*)d_in[8];
  const float* bo = (const float*)d_in[9];
  const float* w1 = (const float*)d_in[10];
  const float* b1 = (const float*)d_in[11];
  const float* w2 = (const float*)d_in[12];
  const float* b2 = (const float*)d_in[13];
  const float* ln1g = (const float*)d_in[14];
  const float* ln1b = (const float*)d_in[15];
  const float* ln2g = (const float*)d_in[16];
  const float* ln2b = (const float*)d_in[17];
  const float* pw1 = (const float*)d_in[18];
  const float* pb1 = (const float*)d_in[19];
  const float* pw2 = (const float*)d_in[20];
  const float* pb2 = (const float*)d_in[21];
  const float* sw1 = (const float*)d_in[22];
  const float* sb1 = (const float*)d_in[23];
  const float* sw2 = (const float*)d_in[24];
  const float* sb2 = (const float*)d_in[25];
  const float* bw1 = (const float*)d_in[26];
  const float* bb1 = (const float*)d_in[27];
  const float* bw2 = (const float*)d_in[28];
  const float* bb2 = (const float*)d_in[29];

  char* wsb = (char*)d_ws;
  size_t off = 0;
  auto allocB = [&](size_t bytes) {
    char* p = wsb + off;
    off += (bytes + 255) & ~(size_t)255;
    return p;
  };
  float* tpb = (float*)allocB(ROWS * TD * 4);
  float* sgb = (float*)allocB(ROWS * TD * 4);
  float* beb = (float*)allocB(ROWS * TD * 4);
  float* kernS = (float*)allocB((size_t)BB * LL * LL * 4);
  // contiguous region: qkvhi | qkvlo | vtbhi | vtblo  (33.55 MB) — aliased by h
  unsigned short* qkvhi = (unsigned short*)allocB(
      ((size_t)ROWS * QKVN * 2 + (size_t)BB * NH * DHD * LL * 2) * 2);
  unsigned short* qkvlo = qkvhi + (size_t)ROWS * QKVN;
  unsigned short* vtbhi = qkvlo + (size_t)ROWS * QKVN;
  unsigned short* vtblo = vtbhi + (size_t)BB * NH * DHD * LL;
  float* ao = (float*)allocB((size_t)ROWS * DM * 4);
  float* xb = (float*)allocB((size_t)ROWS * DM * 4);
  float* fb = (float*)allocB((size_t)ROWS * DM * 4);
  float* xn = (float*)allocB((size_t)ROWS * DM * 4);
  float* qkvbias = (float*)allocB(QKVN * 4);
  unsigned short* qkvwt_hi = (unsigned short*)allocB((size_t)QKVN * DM * 2);
  unsigned short* qkvwt_lo = (unsigned short*)allocB((size_t)QKVN * DM * 2);
  unsigned short* wot_hi = (unsigned short*)allocB((size_t)DM * DM * 2);
  unsigned short* wot_lo = (unsigned short*)allocB((size_t)DM * DM * 2);
  unsigned short* w1t_hi = (unsigned short*)allocB((size_t)FF * DM * 2);
  unsigned short* w1t_lo = (unsigned short*)allocB((size_t)FF * DM * 2);
  unsigned short* w2t_hi = (unsigned short*)allocB((size_t)DM * FF * 2);
  unsigned short* w2t_lo = (unsigned short*)allocB((size_t)DM * FF * 2);
  unsigned short* xhi = (unsigned short*)allocB((size_t)ROWS * DM * 2);
  unsigned short* xlo = (unsigned short*)allocB((size_t)ROWS * DM * 2);
  unsigned short* ctxhi = (unsigned short*)allocB((size_t)ROWS * DM * 2);
  unsigned short* ctxlo = (unsigned short*)allocB((size_t)ROWS * DM * 2);
  // h hi/lo alias over [qkvhi..vtblo] (dead by FFN1 time; 33.55 MB exact)
  unsigned short* hhi = qkvhi;
  unsigned short* hlo = hhi + (size_t)ROWS * FF;

  const float* xcur = x_in;

  for (int i = 0; i < NLAYERS; ++i) {
    td_kernel<<<dim3(16, 16), 256, 0, stream>>>(wq + (size_t)i * DM * DM, qkvwt_hi, qkvwt_lo, DM, DM);
    td_kernel<<<dim3(16, 16), 256, 0, stream>>>(wk + (size_t)i * DM * DM, qkvwt_hi + (size_t)DM * DM, qkvwt_lo + (size_t)DM * DM, DM, DM);
    td_kernel<<<dim3(16, 16), 256, 0, stream>>>(wv + (size_t)i * DM * DM, qkvwt_hi + (size_t)2 * DM * DM, qkvwt_lo + (size_t)2 * DM * DM, DM, DM);
    td_kernel<<<dim3(16, 16), 256, 0, stream>>>(wo + (size_t)i * DM * DM, wot_hi, wot_lo, DM, DM);
    td_kernel<<<dim3(16, 64), 256, 0, stream>>>(w1 + (size_t)i * DM * FF, w1t_hi, w1t_lo, DM, FF);
    td_kernel<<<dim3(64, 16), 256, 0, stream>>>(w2 + (size_t)i * FF * DM, w2t_hi, w2t_lo, FF, DM);
    qkvbias_kernel<<<(QKVN + 255) / 256, 256, 0, stream>>>(bq + i * DM, bk + i * DM, bv + i * DM, qkvbias);

    small_ffn_kernel<<<ROWS / 256, 256, 0, stream>>>(
        t, pw1 + i * TD, pb1 + i * TD, pw2 + i * TD * TD, pb2 + i * TD,
        sw1 + i * TD, sb1 + i * TD, sw2 + i * TD * TD, sb2 + i * TD,
        bw1 + i * TD, bb1 + i * TD, bw2 + i * TD * TD, bb2 + i * TD,
        tpb, sgb, beb);
    kern_kernel<<<dim3(LL / 256, LL, BB), 256, 0, stream>>>(t, tpb, sgb, beb, kernS);

    if (i == 0) {
      decomp_kernel<<<(ROWS * DM / 4 + 255) / 256, 256, 0, stream>>>(x_in, xhi, xlo, ROWS * DM / 4);
    }

    // QKV fused GEMM -> split bf16 output
    gemm_mfma<128, false, true><<<dim3(QKVN / 128, ROWS / 128), 256, 0, stream>>>(
        xhi, xlo, qkvwt_hi, qkvwt_lo, qkvbias, nullptr, qkvhi, qkvlo, ROWS, QKVN, DM);

    vtxp_kernel<<<dim3(LL / 32, DHD / 32, BB * NH), 256, 0, stream>>>(
        qkvhi, qkvlo, vtbhi, vtblo);

    attn_mfma<<<dim3(BB * NH * (LL / ATQ)), 256, 0, stream>>>(
        qkvhi, qkvlo, vtbhi, vtblo, kernS, ctxhi, ctxlo);

    gemm_mfma<64, false, false><<<dim3(DM / 64, ROWS / 128), 256, 0, stream>>>(
        ctxhi, ctxlo, wot_hi, wot_lo, bo + i * DM, ao, nullptr, nullptr, ROWS, DM, DM);

    resid_ln_kernel<<<ROWS / 4, 256, 0, stream>>>(
        xcur, ao, ln1g + i * DM, ln1b + i * DM, xb, xhi, xlo);

    gemm_mfma<128, true, true><<<dim3(FF / 128, ROWS / 128), 256, 0, stream>>>(
        xhi, xlo, w1t_hi, w1t_lo, b1 + i * FF, nullptr, hhi, hlo, ROWS, FF, DM);

    gemm_mfma<64, false, false><<<dim3(DM / 64, ROWS / 128), 256, 0, stream>>>(
        hhi, hlo, w2t_hi, w2t_lo, b2 + i * DM, fb, nullptr, nullptr, ROWS, DM, FF);

    float* ln2_out = (i == NLAYERS - 1) ? (float*)d_out : xn;
    resid_ln_kernel<<<ROWS / 4, 256, 0, stream>>>(
        xb, fb, ln2g + i * DM, ln2b + i * DM, ln2_out, xhi, xlo);

    xcur = xn;
  }
}

// Round 8
// 797.309 us; speedup vs baseline: 1.4398x; 1.0676x over previous
//
#include <hip/hip_runtime.h>
#include <hip/hip_bf16.h>

#define DEV_INLINE __device__ __forceinline__

constexpr int NLAYERS = 2;
constexpr int DM = 512;
constexpr int NH = 8;
constexpr int DHD = 64;
constexpr int FF = 2048;
constexpr int TD = 8;
constexpr int BB = 8;
constexpr int LL = 512;
constexpr int ROWS = BB * LL;  // 4096
constexpr int QKVN = 3 * DM;   // 1536

constexpr float TWO_PI_F = 6.28318530717958647692f;
constexpr float INV_E8 = 3.3546262790251185e-4f;  // e^-8

typedef __attribute__((ext_vector_type(8))) short short8v;
typedef __attribute__((ext_vector_type(4))) float f32x4;

DEV_INLINE unsigned short bf16_rne(float x) {
  unsigned int u = __float_as_uint(x);
  unsigned int r = (u + 0x7fffu + ((u >> 16) & 1u)) >> 16;
  return (unsigned short)r;
}
DEV_INLINE float bf16_to_f(unsigned short h) {
  return __uint_as_float(((unsigned int)h) << 16);
}
DEV_INLINE void split_bf16(float x, unsigned short& h, unsigned short& l) {
  h = bf16_rne(x);
  float lo = x - bf16_to_f(h);
  l = bf16_rne(lo);
}

// ---------------------------------------------------------------------------
// Small FFNs on t
// ---------------------------------------------------------------------------
DEV_INLINE void ffn2_small(float tv,
                           const float* __restrict__ w1, const float* __restrict__ b1,
                           const float* __restrict__ w2, const float* __restrict__ b2,
                           float* out) {
  float h[TD];
#pragma unroll
  for (int d = 0; d < TD; ++d) h[d] = fmaxf(tv * w1[d] + b1[d], 0.f);
#pragma unroll
  for (int j = 0; j < TD; ++j) {
    float acc = b2[j];
#pragma unroll
    for (int d = 0; d < TD; ++d) acc += h[d] * w2[d * TD + j];
    out[j] = fmaxf(acc, 0.f);
  }
}

__global__ __launch_bounds__(256) void small_ffn_kernel(
    const float* __restrict__ t,
    const float* __restrict__ pw1, const float* __restrict__ pb1,
    const float* __restrict__ pw2, const float* __restrict__ pb2,
    const float* __restrict__ sw1, const float* __restrict__ sb1,
    const float* __restrict__ sw2, const float* __restrict__ sb2,
    const float* __restrict__ bw1, const float* __restrict__ bb1,
    const float* __restrict__ bw2, const float* __restrict__ bb2,
    float* __restrict__ tp, float* __restrict__ sg, float* __restrict__ be) {
  const int i = blockIdx.x * 256 + threadIdx.x;
  if (i >= ROWS) return;
  const float tv = t[i];
  float o[TD];
  ffn2_small(tv, pw1, pb1, pw2, pb2, o);
#pragma unroll
  for (int d = 0; d < TD; ++d) tp[(size_t)i * TD + d] = TWO_PI_F * o[d] * tv;
  ffn2_small(tv, sw1, sb1, sw2, sb2, o);
#pragma unroll
  for (int d = 0; d < TD; ++d) sg[(size_t)i * TD + d] = o[d] + 1e-6f;
  ffn2_small(tv, bw1, bb1, bw2, bb2, o);
#pragma unroll
  for (int d = 0; d < TD; ++d) be[(size_t)i * TD + d] = o[d];
}

// ---------------------------------------------------------------------------
// kern kernel
// ---------------------------------------------------------------------------
DEV_INLINE void load8(const float* __restrict__ p, float* o) {
  float4 a = *reinterpret_cast<const float4*>(p);
  float4 b = *reinterpret_cast<const float4*>(p + 4);
  o[0] = a.x; o[1] = a.y; o[2] = a.z; o[3] = a.w;
  o[4] = b.x; o[5] = b.y; o[6] = b.z; o[7] = b.w;
}

__global__ __launch_bounds__(256) void kern_kernel(
    const float* __restrict__ t, const float* __restrict__ tp,
    const float* __restrict__ sg, const float* __restrict__ be,
    float* __restrict__ kernS) {
  const int k = blockIdx.x * 256 + threadIdx.x;
  const int q = blockIdx.y;
  const int b = blockIdx.z;
  const size_t iq = (size_t)b * LL + q;
  const size_t ik = (size_t)b * LL + k;
  const float tq = t[iq], tk = t[ik];
  const float diff = tq - tk;
  const float d2 = diff * diff;

  float tpq[TD], sgq[TD], beq[TD], tpk[TD], sgk[TD], bek[TD];
  load8(tp + iq * TD, tpq);
  load8(sg + iq * TD, sgq);
  load8(be + iq * TD, beq);
  load8(tp + ik * TD, tpk);
  load8(sg + ik * TD, sgk);
  load8(be + ik * TD, bek);

  float acc = 0.f;
#pragma unroll
  for (int d = 0; d < TD; ++d) {
    const float sq = sgq[d], sk = sgk[d];
    const float denom = sq * sq + sk * sk;
    const float inv = 1.0f / denom;
    const float e = __expf(-d2 * inv);
    const float loc = sqrtf(2.0f * sq * sk * inv);
    const float c = __cosf(tpq[d] - tpk[d]);
    acc += beq[d] * bek[d] * loc * e * c;
  }
  kernS[((size_t)b * LL + q) * LL + k] = acc * INV_E8;
}

// ---------------------------------------------------------------------------
// Weight transpose + hi/lo bf16 decompose: W[K][N] fp32 -> Thi/Tlo[N][K] bf16
// ---------------------------------------------------------------------------
__global__ __launch_bounds__(256) void td_kernel(
    const float* __restrict__ W, unsigned short* __restrict__ Thi,
    unsigned short* __restrict__ Tlo, int K, int N) {
  __shared__ float tile[32][33];
  const int k0 = blockIdx.x * 32, n0 = blockIdx.y * 32;
  const int tx = threadIdx.x & 31, ty = threadIdx.x >> 5;
#pragma unroll
  for (int i = 0; i < 4; ++i)
    tile[ty + i * 8][tx] = W[(size_t)(k0 + ty + i * 8) * N + n0 + tx];
  __syncthreads();
#pragma unroll
  for (int i = 0; i < 4; ++i) {
    const int n = n0 + ty + i * 8;
    const float v = tile[tx][ty + i * 8];
    unsigned short h, l;
    split_bf16(v, h, l);
    Thi[(size_t)n * K + k0 + tx] = h;
    Tlo[(size_t)n * K + k0 + tx] = l;
  }
}

// ---------------------------------------------------------------------------
// Elementwise hi/lo decompose (for layer-0 x). 4 elems/thread.
// ---------------------------------------------------------------------------
__global__ __launch_bounds__(256) void decomp_kernel(
    const float* __restrict__ X, unsigned short* __restrict__ Hi,
    unsigned short* __restrict__ Lo, int n4) {
  const int i = blockIdx.x * 256 + threadIdx.x;
  if (i >= n4) return;
  const float4 v = *reinterpret_cast<const float4*>(X + (size_t)i * 4);
  unsigned short h0, h1, h2, h3, l0, l1, l2, l3;
  split_bf16(v.x, h0, l0);
  split_bf16(v.y, h1, l1);
  split_bf16(v.z, h2, l2);
  split_bf16(v.w, h3, l3);
  uint2 hv, lv;
  hv.x = (unsigned)h0 | ((unsigned)h1 << 16);
  hv.y = (unsigned)h2 | ((unsigned)h3 << 16);
  lv.x = (unsigned)l0 | ((unsigned)l1 << 16);
  lv.y = (unsigned)l2 | ((unsigned)l3 << 16);
  *reinterpret_cast<uint2*>(Hi + (size_t)i * 4) = hv;
  *reinterpret_cast<uint2*>(Lo + (size_t)i * 4) = lv;
}

__global__ __launch_bounds__(256) void qkvbias_kernel(
    const float* __restrict__ bq, const float* __restrict__ bk,
    const float* __restrict__ bv, float* __restrict__ out) {
  const int i = blockIdx.x * 256 + threadIdx.x;
  if (i >= QKVN) return;
  out[i] = i < DM ? bq[i] : (i < 2 * DM ? bk[i - DM] : bv[i - 2 * DM]);
}

// ---------------------------------------------------------------------------
// Split-bf16 MFMA GEMM: C = Ahi@Bhi + Alo@Bhi + Ahi@Blo (+bias, opt relu)
// BM template {64,128}, BK=32, double-buffered LDS, one barrier per k-tile,
// reg prefetch 2 ahead. Optional split-K via gridDim.z (PARTIAL: raw f32
// partials, no bias). 4 waves as 2x2; XCD-bijective block swizzle per z-slice.
// ---------------------------------------------------------------------------
template <int BM, int BN, bool RELU, bool SPLIT_OUT, bool PARTIAL>
__global__ __launch_bounds__(256) void gemm_mfma(
    const unsigned short* __restrict__ Ahi, const unsigned short* __restrict__ Alo,
    const unsigned short* __restrict__ Bhi, const unsigned short* __restrict__ Blo,
    const float* __restrict__ bias, float* __restrict__ C,
    unsigned short* __restrict__ Chi, unsigned short* __restrict__ Clo,
    int M, int N, int K) {
  constexpr int BK = 32;
  constexpr int WT_M = BM / 2;
  constexpr int WT_N = BN / 2;
  constexpr int MI = WT_M / 16;              // 2 or 4
  constexpr int NI = WT_N / 16;              // 2 or 4
  constexpr int A_IT = BM * BK / (256 * 8);  // 1 or 2
  constexpr int B_IT = BN * BK / (256 * 8);  // 1 or 2

  __shared__ unsigned short AsH[2][BM * BK];
  __shared__ unsigned short AsL[2][BM * BK];
  __shared__ unsigned short BsH[2][BN * BK];
  __shared__ unsigned short BsL[2][BN * BK];

  const int nwg = gridDim.x * gridDim.y;
  const int orig = blockIdx.y * gridDim.x + blockIdx.x;
  const int swz = (orig & 7) * (nwg >> 3) + (orig >> 3);
  const int bx = swz % gridDim.x;
  const int by = swz / gridDim.x;

  const int tid = threadIdx.x;
  const int lane = tid & 63;
  const int wid = tid >> 6;
  const int wr = wid >> 1, wc = wid & 1;
  const int rowBase = by * BM;
  const int colBase = bx * BN;
  const int l15 = lane & 15, l4 = lane >> 4;

  const int sg_ = tid & 3;
  const int srA = tid >> 2;
  const int swg = sg_ ^ (srA & 3) ^ ((srA >> 2) & 3);

  // split-K bounds
  const int Keff = K / gridDim.z;
  const int koff = blockIdx.z * Keff;

  f32x4 acc[MI][NI] = {};
  const int nt = Keff / BK;

  uint4 ahR[A_IT], alR[A_IT], bhR[B_IT], blR[B_IT];

  auto loadRegs = [&](int kt) {
    const int k0 = koff + kt * BK;
#pragma unroll
    for (int it = 0; it < A_IT; ++it) {
      const size_t base = (size_t)(rowBase + it * 64 + srA) * K + k0 + sg_ * 8;
      ahR[it] = *reinterpret_cast<const uint4*>(Ahi + base);
      alR[it] = *reinterpret_cast<const uint4*>(Alo + base);
    }
#pragma unroll
    for (int it = 0; it < B_IT; ++it) {
      const size_t base = (size_t)(colBase + it * 64 + srA) * K + k0 + sg_ * 8;
      bhR[it] = *reinterpret_cast<const uint4*>(Bhi + base);
      blR[it] = *reinterpret_cast<const uint4*>(Blo + base);
    }
  };

  auto writeLDS = [&](int buf) {
#pragma unroll
    for (int it = 0; it < A_IT; ++it) {
      const int off = ((it * 64 + srA) << 5) + (swg << 3);
      *reinterpret_cast<uint4*>(&AsH[buf][off]) = ahR[it];
      *reinterpret_cast<uint4*>(&AsL[buf][off]) = alR[it];
    }
#pragma unroll
    for (int it = 0; it < B_IT; ++it) {
      const int off = ((it * 64 + srA) << 5) + (swg << 3);
      *reinterpret_cast<uint4*>(&BsH[buf][off]) = bhR[it];
      *reinterpret_cast<uint4*>(&BsL[buf][off]) = blR[it];
    }
  };

  loadRegs(0);
  writeLDS(0);
  if (nt > 1) loadRegs(1);

  for (int t = 0; t < nt; ++t) {
    __syncthreads();
    const int cur = t & 1;
    if (t + 1 < nt) writeLDS(cur ^ 1);
    if (t + 2 < nt) loadRegs(t + 2);

    short8v ah[MI], al[MI], bh[NI], bl[NI];
#pragma unroll
    for (int mi = 0; mi < MI; ++mi) {
      const int r = wr * WT_M + mi * 16 + l15;
      const int g = l4 ^ (r & 3) ^ ((r >> 2) & 3);
      const int off = (r << 5) + (g << 3);
      ah[mi] = *reinterpret_cast<const short8v*>(&AsH[cur][off]);
      al[mi] = *reinterpret_cast<const short8v*>(&AsL[cur][off]);
    }
#pragma unroll
    for (int ni = 0; ni < NI; ++ni) {
      const int r = wc * WT_N + ni * 16 + l15;
      const int g = l4 ^ (r & 3) ^ ((r >> 2) & 3);
      const int off = (r << 5) + (g << 3);
      bh[ni] = *reinterpret_cast<const short8v*>(&BsH[cur][off]);
      bl[ni] = *reinterpret_cast<const short8v*>(&BsL[cur][off]);
    }
#pragma unroll
    for (int mi = 0; mi < MI; ++mi)
#pragma unroll
      for (int ni = 0; ni < NI; ++ni) {
        acc[mi][ni] = __builtin_amdgcn_mfma_f32_16x16x32_bf16(ah[mi], bh[ni], acc[mi][ni], 0, 0, 0);
        acc[mi][ni] = __builtin_amdgcn_mfma_f32_16x16x32_bf16(al[mi], bh[ni], acc[mi][ni], 0, 0, 0);
        acc[mi][ni] = __builtin_amdgcn_mfma_f32_16x16x32_bf16(ah[mi], bl[ni], acc[mi][ni], 0, 0, 0);
      }
  }

  float* Cout = PARTIAL ? (C + (size_t)blockIdx.z * M * N) : C;
#pragma unroll
  for (int mi = 0; mi < MI; ++mi) {
#pragma unroll
    for (int ni = 0; ni < NI; ++ni) {
      const int col = colBase + wc * WT_N + ni * 16 + l15;
      const float bv = PARTIAL ? 0.f : bias[col];
#pragma unroll
      for (int j = 0; j < 4; ++j) {
        const int row = rowBase + wr * WT_M + mi * 16 + l4 * 4 + j;
        float v = acc[mi][ni][j] + bv;
        if (RELU) v = fmaxf(v, 0.f);
        if (SPLIT_OUT) {
          unsigned short h, l;
          split_bf16(v, h, l);
          Chi[(size_t)row * N + col] = h;
          Clo[(size_t)row * N + col] = l;
        } else {
          Cout[(size_t)row * N + col] = v;
        }
      }
    }
  }
}

// ---------------------------------------------------------------------------
// Split-K reduce: out = part0 + part1 + bias (fp32), 4 elems/thread
// ---------------------------------------------------------------------------
__global__ __launch_bounds__(256) void redk_kernel(
    const float* __restrict__ part, const float* __restrict__ bias,
    float* __restrict__ out, int total4, int N) {
  const int i = blockIdx.x * 256 + threadIdx.x;
  if (i >= total4) return;
  const size_t idx = (size_t)i * 4;
  const int col = (int)(idx & (N - 1));
  const float4 a = *reinterpret_cast<const float4*>(part + idx);
  const float4 b = *reinterpret_cast<const float4*>(part + (size_t)ROWS * DM + idx);
  const float4 bi = *reinterpret_cast<const float4*>(bias + col);
  float4 o;
  o.x = a.x + b.x + bi.x;
  o.y = a.y + b.y + bi.y;
  o.z = a.z + b.z + bi.z;
  o.w = a.w + b.w + bi.w;
  *reinterpret_cast<float4*>(out + idx) = o;
}

// ---------------------------------------------------------------------------
// V transpose (bf16 hi/lo): qkv V-slice -> vtb[bh][d][kk]
// ---------------------------------------------------------------------------
__global__ __launch_bounds__(256) void vtxp_kernel(
    const unsigned short* __restrict__ qkvhi, const unsigned short* __restrict__ qkvlo,
    unsigned short* __restrict__ vtbhi, unsigned short* __restrict__ vtblo) {
  __shared__ unsigned short th[32][33], tl[32][33];
  const int bh = blockIdx.z;
  const int b = bh >> 3, h = bh & 7;
  const int kk0 = blockIdx.x * 32, d0 = blockIdx.y * 32;
  const int tx = threadIdx.x & 31, ty = threadIdx.x >> 5;
#pragma unroll
  for (int i = 0; i < 4; ++i) {
    const int kk = kk0 + ty + i * 8;
    const size_t src = (size_t)(b * LL + kk) * QKVN + 2 * DM + h * DHD + d0 + tx;
    th[ty + i * 8][tx] = qkvhi[src];
    tl[ty + i * 8][tx] = qkvlo[src];
  }
  __syncthreads();
#pragma unroll
  for (int i = 0; i < 4; ++i) {
    const int d = d0 + ty + i * 8;
    const size_t dst = ((size_t)bh * DHD + d) * LL + kk0 + tx;
    vtbhi[dst] = th[tx][ty + i * 8];
    vtblo[dst] = tl[tx][ty + i * 8];
  }
}

// ---------------------------------------------------------------------------
// MFMA attention: block = 16 q rows of one (b,h). 256 threads (4 waves).
// ---------------------------------------------------------------------------
constexpr int ATQ = 16;

__global__ __launch_bounds__(256) void attn_mfma(
    const unsigned short* __restrict__ qkvhi, const unsigned short* __restrict__ qkvlo,
    const unsigned short* __restrict__ vtbhi, const unsigned short* __restrict__ vtblo,
    const float* __restrict__ kernS,
    unsigned short* __restrict__ ctxhi, unsigned short* __restrict__ ctxlo) {
  const int id = blockIdx.x;
  const int w = (id & 7) * 256 + (id >> 3);  // 2048 blocks, bijective
  const int h = w & 7;
  const int qt = (w >> 3) & 31;
  const int b = w >> 8;
  const int tid = threadIdx.x;
  const int lane = tid & 63;
  const int wv = tid >> 6;
  const int l15 = lane & 15, l4 = lane >> 4;
  const int q0 = qt * ATQ;

  __shared__ float S[ATQ][521];
  __shared__ unsigned short Phi[ATQ][520];
  __shared__ unsigned short Plo[ATQ][520];
  __shared__ float sinv[ATQ];

  short8v qh[2], ql[2];
  {
    const size_t qbase = (size_t)(b * LL + q0 + l15) * QKVN + h * DHD;
#pragma unroll
    for (int ks = 0; ks < 2; ++ks) {
      qh[ks] = *reinterpret_cast<const short8v*>(qkvhi + qbase + ks * 32 + l4 * 8);
      ql[ks] = *reinterpret_cast<const short8v*>(qkvlo + qbase + ks * 32 + l4 * 8);
    }
  }

  for (int nt = 0; nt < 8; ++nt) {
    const int kk0 = wv * 128 + nt * 16;
    const size_t kbase = (size_t)(b * LL + kk0 + l15) * QKVN + DM + h * DHD;
    f32x4 acc = {};
#pragma unroll
    for (int ks = 0; ks < 2; ++ks) {
      const short8v kh = *reinterpret_cast<const short8v*>(qkvhi + kbase + ks * 32 + l4 * 8);
      const short8v kl = *reinterpret_cast<const short8v*>(qkvlo + kbase + ks * 32 + l4 * 8);
      acc = __builtin_amdgcn_mfma_f32_16x16x32_bf16(qh[ks], kh, acc, 0, 0, 0);
      acc = __builtin_amdgcn_mfma_f32_16x16x32_bf16(ql[ks], kh, acc, 0, 0, 0);
      acc = __builtin_amdgcn_mfma_f32_16x16x32_bf16(qh[ks], kl, acc, 0, 0, 0);
    }
#pragma unroll
    for (int j = 0; j < 4; ++j) {
      const int row = l4 * 4 + j;
      S[row][kk0 + l15] =
          acc[j] * 0.125f + kernS[((size_t)b * LL + q0 + row) * LL + kk0 + l15];
    }
  }
  __syncthreads();

  {
    const int r = tid >> 4, c = tid & 15;
    float m = -1e30f;
#pragma unroll
    for (int j = 0; j < 32; ++j) m = fmaxf(m, S[r][c + j * 16]);
#pragma unroll
    for (int s = 8; s; s >>= 1) m = fmaxf(m, __shfl_xor(m, s, 16));
    float sum = 0.f;
#pragma unroll
    for (int j = 0; j < 32; ++j) {
      const float e = __expf(S[r][c + j * 16] - m);
      unsigned short hh, ll;
      split_bf16(e, hh, ll);
      Phi[r][c + j * 16] = hh;
      Plo[r][c + j * 16] = ll;
      sum += e;
    }
#pragma unroll
    for (int s = 8; s; s >>= 1) sum += __shfl_xor(sum, s, 16);
    if (c == 0) sinv[r] = 1.0f / sum;
  }
  __syncthreads();

  {
    const int d0 = wv * 16;
    const size_t vbase = ((size_t)(b * NH + h) * DHD + d0 + l15) * LL;
    f32x4 acc = {};
    for (int kt = 0; kt < 16; ++kt) {
      const int kk0 = kt * 32;
      const short8v ph = *reinterpret_cast<const short8v*>(&Phi[l15][kk0 + l4 * 8]);
      const short8v pl = *reinterpret_cast<const short8v*>(&Plo[l15][kk0 + l4 * 8]);
      const short8v vh = *reinterpret_cast<const short8v*>(vtbhi + vbase + kk0 + l4 * 8);
      const short8v vl = *reinterpret_cast<const short8v*>(vtblo + vbase + kk0 + l4 * 8);
      acc = __builtin_amdgcn_mfma_f32_16x16x32_bf16(ph, vh, acc, 0, 0, 0);
      acc = __builtin_amdgcn_mfma_f32_16x16x32_bf16(pl, vh, acc, 0, 0, 0);
      acc = __builtin_amdgcn_mfma_f32_16x16x32_bf16(ph, vl, acc, 0, 0, 0);
    }
#pragma unroll
    for (int j = 0; j < 4; ++j) {
      const int row = l4 * 4 + j;
      const float o = acc[j] * sinv[row];
      unsigned short hh, ll;
      split_bf16(o, hh, ll);
      const size_t oo = (size_t)(b * LL + q0 + row) * DM + h * DHD + d0 + l15;
      ctxhi[oo] = hh;
      ctxlo[oo] = ll;
    }
  }
}

// ---------------------------------------------------------------------------
// Fused residual + LayerNorm; writes fp32 + bf16 hi/lo decomposition.
// ---------------------------------------------------------------------------
__global__ __launch_bounds__(256) void resid_ln_kernel(
    const float* __restrict__ X, const float* __restrict__ R,
    const float* __restrict__ g, const float* __restrict__ bta,
    float* __restrict__ Out, unsigned short* __restrict__ OutHi,
    unsigned short* __restrict__ OutLo) {
  const int row = blockIdx.x * 4 + (threadIdx.x >> 6);
  const int lane = threadIdx.x & 63;
  const float* x = X + (size_t)row * DM;
  const float* r = R + (size_t)row * DM;

  float v[8];
  float s = 0.f;
#pragma unroll
  for (int j = 0; j < 2; ++j) {
    const float4 a = *reinterpret_cast<const float4*>(x + lane * 8 + j * 4);
    const float4 c = *reinterpret_cast<const float4*>(r + lane * 8 + j * 4);
    v[j * 4 + 0] = a.x + c.x;
    v[j * 4 + 1] = a.y + c.y;
    v[j * 4 + 2] = a.z + c.z;
    v[j * 4 + 3] = a.w + c.w;
    s += v[j * 4 + 0] + v[j * 4 + 1] + v[j * 4 + 2] + v[j * 4 + 3];
  }
#pragma unroll
  for (int m = 1; m < 64; m <<= 1) s += __shfl_xor(s, m, 64);
  const float mean = s * (1.f / DM);
  float var = 0.f;
#pragma unroll
  for (int j = 0; j < 8; ++j) {
    const float dlt = v[j] - mean;
    var += dlt * dlt;
  }
#pragma unroll
  for (int m = 1; m < 64; m <<= 1) var += __shfl_xor(var, m, 64);
  var *= (1.f / DM);
  const float inv = 1.0f / sqrtf(var + 1e-6f);

  unsigned short hs[8], ls[8];
#pragma unroll
  for (int j = 0; j < 2; ++j) {
    const float4 gg = *reinterpret_cast<const float4*>(g + lane * 8 + j * 4);
    const float4 bb = *reinterpret_cast<const float4*>(bta + lane * 8 + j * 4);
    float4 o;
    o.x = (v[j * 4 + 0] - mean) * inv * gg.x + bb.x;
    o.y = (v[j * 4 + 1] - mean) * inv * gg.y + bb.y;
    o.z = (v[j * 4 + 2] - mean) * inv * gg.z + bb.z;
    o.w = (v[j * 4 + 3] - mean) * inv * gg.w + bb.w;
    *reinterpret_cast<float4*>(Out + (size_t)row * DM + lane * 8 + j * 4) = o;
    split_bf16(o.x, hs[j * 4 + 0], ls[j * 4 + 0]);
    split_bf16(o.y, hs[j * 4 + 1], ls[j * 4 + 1]);
    split_bf16(o.z, hs[j * 4 + 2], ls[j * 4 + 2]);
    split_bf16(o.w, hs[j * 4 + 3], ls[j * 4 + 3]);
  }
  uint4 hv, lv;
  hv.x = (unsigned)hs[0] | ((unsigned)hs[1] << 16);
  hv.y = (unsigned)hs[2] | ((unsigned)hs[3] << 16);
  hv.z = (unsigned)hs[4] | ((unsigned)hs[5] << 16);
  hv.w = (unsigned)hs[6] | ((unsigned)hs[7] << 16);
  lv.x = (unsigned)ls[0] | ((unsigned)ls[1] << 16);
  lv.y = (unsigned)ls[2] | ((unsigned)ls[3] << 16);
  lv.z = (unsigned)ls[4] | ((unsigned)ls[5] << 16);
  lv.w = (unsigned)ls[6] | ((unsigned)ls[7] << 16);
  *reinterpret_cast<uint4*>(OutHi + (size_t)row * DM + lane * 8) = hv;
  *reinterpret_cast<uint4*>(OutLo + (size_t)row * DM + lane * 8) = lv;
}

// ---------------------------------------------------------------------------
// launch
// ---------------------------------------------------------------------------
extern "C" void kernel_launch(void* const* d_in, const int* in_sizes, int n_in,
                              void* d_out, int out_size, void* d_ws, size_t ws_size,
                              hipStream_t stream) {
  const float* x_in = (const float*)d_in[0];
  const float* t = (const float*)d_in[1];
  const float* wq = (const float*)d_in[2];
  const float* bq = (const float*)d_in[3];
  const float* wk = (const float*)d_in[4];
  const float* bk = (const float*)d_in[5];
  const float* wv = (const float*)d_in[6];
  const float* bv = (const float*)d_in[7];
  const float* wo = (const float*)d_in[8];
  const float* bo = (const float*)d_in[9];
  const float* w1 = (const float*)d_in[10];
  const float* b1 = (const float*)d_in[11];
  const float* w2 = (const float*)d_in[12];
  const float* b2 = (const float*)d_in[13];
  const float* ln1g = (const float*)d_in[14];
  const float* ln1b = (const float*)d_in[15];
  const float* ln2g = (const float*)d_in[16];
  const float* ln2b = (const float*)d_in[17];
  const float* pw1 = (const float*)d_in[18];
  const float* pb1 = (const float*)d_in[19];
  const float* pw2 = (const float*)d_in[20];
  const float* pb2 = (const float*)d_in[21];
  const float* sw1 = (const float*)d_in[22];
  const float* sb1 = (const float*)d_in[23];
  const float* sw2 = (const float*)d_in[24];
  const float* sb2 = (const float*)d_in[25];
  const float* bw1 = (const float*)d_in[26];
  const float* bb1 = (const float*)d_in[27];
  const float* bw2 = (const float*)d_in[28];
  const float* bb2 = (const float*)d_in[29];

  char* wsb = (char*)d_ws;
  size_t off = 0;
  auto allocB = [&](size_t bytes) {
    char* p = wsb + off;
    off += (bytes + 255) & ~(size_t)255;
    return p;
  };
  float* tpb = (float*)allocB(ROWS * TD * 4);
  float* sgb = (float*)allocB(ROWS * TD * 4);
  float* beb = (float*)allocB(ROWS * TD * 4);
  float* kernS = (float*)allocB((size_t)BB * LL * LL * 4);
  // contiguous region: qkvhi | qkvlo | vtbhi | vtblo  (33.55 MB) — aliased by h
  unsigned short* qkvhi = (unsigned short*)allocB(
      ((size_t)ROWS * QKVN * 2 + (size_t)BB * NH * DHD * LL * 2) * 2);
  unsigned short* qkvlo = qkvhi + (size_t)ROWS * QKVN;
  unsigned short* vtbhi = qkvlo + (size_t)ROWS * QKVN;
  unsigned short* vtblo = vtbhi + (size_t)BB * NH * DHD * LL;
  float* ao = (float*)allocB((size_t)ROWS * DM * 4);
  float* xb = (float*)allocB((size_t)ROWS * DM * 4);
  float* fb = (float*)allocB((size_t)ROWS * DM * 4);
  float* xn = (float*)allocB((size_t)ROWS * DM * 4);
  float* part = (float*)allocB((size_t)2 * ROWS * DM * 4);  // split-K partials
  float* qkvbias = (float*)allocB(QKVN * 4);
  unsigned short* qkvwt_hi = (unsigned short*)allocB((size_t)QKVN * DM * 2);
  unsigned short* qkvwt_lo = (unsigned short*)allocB((size_t)QKVN * DM * 2);
  unsigned short* wot_hi = (unsigned short*)allocB((size_t)DM * DM * 2);
  unsigned short* wot_lo = (unsigned short*)allocB((size_t)DM * DM * 2);
  unsigned short* w1t_hi = (unsigned short*)allocB((size_t)FF * DM * 2);
  unsigned short* w1t_lo = (unsigned short*)allocB((size_t)FF * DM * 2);
  unsigned short* w2t_hi = (unsigned short*)allocB((size_t)DM * FF * 2);
  unsigned short* w2t_lo = (unsigned short*)allocB((size_t)DM * FF * 2);
  unsigned short* xhi = (unsigned short*)allocB((size_t)ROWS * DM * 2);
  unsigned short* xlo = (unsigned short*)allocB((size_t)ROWS * DM * 2);
  unsigned short* ctxhi = (unsigned short*)allocB((size_t)ROWS * DM * 2);
  unsigned short* ctxlo = (unsigned short*)allocB((size_t)ROWS * DM * 2);
  // h hi/lo alias over [qkvhi..vtblo] (dead by FFN1 time; 33.55 MB exact)
  unsigned short* hhi = qkvhi;
  unsigned short* hlo = hhi + (size_t)ROWS * FF;

  const float* xcur = x_in;

  for (int i = 0; i < NLAYERS; ++i) {
    td_kernel<<<dim3(16, 16), 256, 0, stream>>>(wq + (size_t)i * DM * DM, qkvwt_hi, qkvwt_lo, DM, DM);
    td_kernel<<<dim3(16, 16), 256, 0, stream>>>(wk + (size_t)i * DM * DM, qkvwt_hi + (size_t)DM * DM, qkvwt_lo + (size_t)DM * DM, DM, DM);
    td_kernel<<<dim3(16, 16), 256, 0, stream>>>(wv + (size_t)i * DM * DM, qkvwt_hi + (size_t)2 * DM * DM, qkvwt_lo + (size_t)2 * DM * DM, DM, DM);
    td_kernel<<<dim3(16, 16), 256, 0, stream>>>(wo + (size_t)i * DM * DM, wot_hi, wot_lo, DM, DM);
    td_kernel<<<dim3(16, 64), 256, 0, stream>>>(w1 + (size_t)i * DM * FF, w1t_hi, w1t_lo, DM, FF);
    td_kernel<<<dim3(64, 16), 256, 0, stream>>>(w2 + (size_t)i * FF * DM, w2t_hi, w2t_lo, FF, DM);
    qkvbias_kernel<<<(QKVN + 255) / 256, 256, 0, stream>>>(bq + i * DM, bk + i * DM, bv + i * DM, qkvbias);

    small_ffn_kernel<<<ROWS / 256, 256, 0, stream>>>(
        t, pw1 + i * TD, pb1 + i * TD, pw2 + i * TD * TD, pb2 + i * TD,
        sw1 + i * TD, sb1 + i * TD, sw2 + i * TD * TD, sb2 + i * TD,
        bw1 + i * TD, bb1 + i * TD, bw2 + i * TD * TD, bb2 + i * TD,
        tpb, sgb, beb);
    kern_kernel<<<dim3(LL / 256, LL, BB), 256, 0, stream>>>(t, tpb, sgb, beb, kernS);

    if (i == 0) {
      decomp_kernel<<<(ROWS * DM / 4 + 255) / 256, 256, 0, stream>>>(x_in, xhi, xlo, ROWS * DM / 4);
    }

    // QKV fused GEMM -> split bf16 output. grid 12x64 = 768 blocks.
    gemm_mfma<64, 128, false, true, false><<<dim3(QKVN / 128, ROWS / 64), 256, 0, stream>>>(
        xhi, xlo, qkvwt_hi, qkvwt_lo, qkvbias, nullptr, qkvhi, qkvlo, ROWS, QKVN, DM);

    vtxp_kernel<<<dim3(LL / 32, DHD / 32, BB * NH), 256, 0, stream>>>(
        qkvhi, qkvlo, vtbhi, vtblo);

    attn_mfma<<<dim3(BB * NH * (LL / ATQ)), 256, 0, stream>>>(
        qkvhi, qkvlo, vtbhi, vtblo, kernS, ctxhi, ctxlo);

    // O projection: grid 8x64 = 512 blocks
    gemm_mfma<64, 64, false, false, false><<<dim3(DM / 64, ROWS / 64), 256, 0, stream>>>(
        ctxhi, ctxlo, wot_hi, wot_lo, bo + i * DM, ao, nullptr, nullptr, ROWS, DM, DM);

    resid_ln_kernel<<<ROWS / 4, 256, 0, stream>>>(
        xcur, ao, ln1g + i * DM, ln1b + i * DM, xb, xhi, xlo);

    // FFN1 (relu, split bf16 out): grid 16x64 = 1024 blocks
    gemm_mfma<64, 128, true, true, false><<<dim3(FF / 128, ROWS / 64), 256, 0, stream>>>(
        xhi, xlo, w1t_hi, w1t_lo, b1 + i * FF, nullptr, hhi, hlo, ROWS, FF, DM);

    // FFN2: split-K=2, grid 8x64x2 = 1024 blocks, then reduce (+bias)
    gemm_mfma<64, 64, false, false, true><<<dim3(DM / 64, ROWS / 64, 2), 256, 0, stream>>>(
        hhi, hlo, w2t_hi, w2t_lo, nullptr, part, nullptr, nullptr, ROWS, DM, FF);
    redk_kernel<<<(ROWS * DM / 4 + 255) / 256, 256, 0, stream>>>(
        part, b2 + i * DM, fb, ROWS * DM / 4, DM);

    float* ln2_out = (i == NLAYERS - 1) ? (float*)d_out : xn;
    resid_ln_kernel<<<ROWS / 4, 256, 0, stream>>>(
        xb, fb, ln2g + i * DM, ln2b + i * DM, ln2_out, xhi, xlo);

    xcur = xn;
  }
}

// Round 9
// 794.323 us; speedup vs baseline: 1.4452x; 1.0038x over previous
//
#include <hip/hip_runtime.h>
#include <hip/hip_bf16.h>

#define DEV_INLINE __device__ __forceinline__

constexpr int NLAYERS = 2;
constexpr int DM = 512;
constexpr int NH = 8;
constexpr int DHD = 64;
constexpr int FF = 2048;
constexpr int TD = 8;
constexpr int BB = 8;
constexpr int LL = 512;
constexpr int ROWS = BB * LL;  // 4096
constexpr int QKVN = 3 * DM;   // 1536

constexpr float TWO_PI_F = 6.28318530717958647692f;
constexpr float INV_E8 = 3.3546262790251185e-4f;  // e^-8

typedef __attribute__((ext_vector_type(8))) short short8v;
typedef __attribute__((ext_vector_type(4))) float f32x4;

DEV_INLINE unsigned short bf16_rne(float x) {
  unsigned int u = __float_as_uint(x);
  unsigned int r = (u + 0x7fffu + ((u >> 16) & 1u)) >> 16;
  return (unsigned short)r;
}
DEV_INLINE float bf16_to_f(unsigned short h) {
  return __uint_as_float(((unsigned int)h) << 16);
}
DEV_INLINE void split_bf16(float x, unsigned short& h, unsigned short& l) {
  h = bf16_rne(x);
  float lo = x - bf16_to_f(h);
  l = bf16_rne(lo);
}

// ---------------------------------------------------------------------------
// Small FFNs on t
// ---------------------------------------------------------------------------
DEV_INLINE void ffn2_small(float tv,
                           const float* __restrict__ w1, const float* __restrict__ b1,
                           const float* __restrict__ w2, const float* __restrict__ b2,
                           float* out) {
  float h[TD];
#pragma unroll
  for (int d = 0; d < TD; ++d) h[d] = fmaxf(tv * w1[d] + b1[d], 0.f);
#pragma unroll
  for (int j = 0; j < TD; ++j) {
    float acc = b2[j];
#pragma unroll
    for (int d = 0; d < TD; ++d) acc += h[d] * w2[d * TD + j];
    out[j] = fmaxf(acc, 0.f);
  }
}

__global__ __launch_bounds__(256) void small_ffn_kernel(
    const float* __restrict__ t,
    const float* __restrict__ pw1, const float* __restrict__ pb1,
    const float* __restrict__ pw2, const float* __restrict__ pb2,
    const float* __restrict__ sw1, const float* __restrict__ sb1,
    const float* __restrict__ sw2, const float* __restrict__ sb2,
    const float* __restrict__ bw1, const float* __restrict__ bb1,
    const float* __restrict__ bw2, const float* __restrict__ bb2,
    float* __restrict__ tp, float* __restrict__ sg, float* __restrict__ be) {
  const int i = blockIdx.x * 256 + threadIdx.x;
  if (i >= ROWS) return;
  const float tv = t[i];
  float o[TD];
  ffn2_small(tv, pw1, pb1, pw2, pb2, o);
#pragma unroll
  for (int d = 0; d < TD; ++d) tp[(size_t)i * TD + d] = TWO_PI_F * o[d] * tv;
  ffn2_small(tv, sw1, sb1, sw2, sb2, o);
#pragma unroll
  for (int d = 0; d < TD; ++d) sg[(size_t)i * TD + d] = o[d] + 1e-6f;
  ffn2_small(tv, bw1, bb1, bw2, bb2, o);
#pragma unroll
  for (int d = 0; d < TD; ++d) be[(size_t)i * TD + d] = o[d];
}

// ---------------------------------------------------------------------------
// kern kernel
// ---------------------------------------------------------------------------
DEV_INLINE void load8(const float* __restrict__ p, float* o) {
  float4 a = *reinterpret_cast<const float4*>(p);
  float4 b = *reinterpret_cast<const float4*>(p + 4);
  o[0] = a.x; o[1] = a.y; o[2] = a.z; o[3] = a.w;
  o[4] = b.x; o[5] = b.y; o[6] = b.z; o[7] = b.w;
}

__global__ __launch_bounds__(256) void kern_kernel(
    const float* __restrict__ t, const float* __restrict__ tp,
    const float* __restrict__ sg, const float* __restrict__ be,
    float* __restrict__ kernS) {
  const int k = blockIdx.x * 256 + threadIdx.x;
  const int q = blockIdx.y;
  const int b = blockIdx.z;
  const size_t iq = (size_t)b * LL + q;
  const size_t ik = (size_t)b * LL + k;
  const float tq = t[iq], tk = t[ik];
  const float diff = tq - tk;
  const float d2 = diff * diff;

  float tpq[TD], sgq[TD], beq[TD], tpk[TD], sgk[TD], bek[TD];
  load8(tp + iq * TD, tpq);
  load8(sg + iq * TD, sgq);
  load8(be + iq * TD, beq);
  load8(tp + ik * TD, tpk);
  load8(sg + ik * TD, sgk);
  load8(be + ik * TD, bek);

  float acc = 0.f;
#pragma unroll
  for (int d = 0; d < TD; ++d) {
    const float sq = sgq[d], sk = sgk[d];
    const float denom = sq * sq + sk * sk;
    const float inv = 1.0f / denom;
    const float e = __expf(-d2 * inv);
    const float loc = sqrtf(2.0f * sq * sk * inv);
    const float c = __cosf(tpq[d] - tpk[d]);
    acc += beq[d] * bek[d] * loc * e * c;
  }
  kernS[((size_t)b * LL + q) * LL + k] = acc * INV_E8;
}

// ---------------------------------------------------------------------------
// Weight transpose + hi/lo bf16 decompose: W[K][N] fp32 -> Thi/Tlo[N][K] bf16
// ---------------------------------------------------------------------------
__global__ __launch_bounds__(256) void td_kernel(
    const float* __restrict__ W, unsigned short* __restrict__ Thi,
    unsigned short* __restrict__ Tlo, int K, int N) {
  __shared__ float tile[32][33];
  const int k0 = blockIdx.x * 32, n0 = blockIdx.y * 32;
  const int tx = threadIdx.x & 31, ty = threadIdx.x >> 5;
#pragma unroll
  for (int i = 0; i < 4; ++i)
    tile[ty + i * 8][tx] = W[(size_t)(k0 + ty + i * 8) * N + n0 + tx];
  __syncthreads();
#pragma unroll
  for (int i = 0; i < 4; ++i) {
    const int n = n0 + ty + i * 8;
    const float v = tile[tx][ty + i * 8];
    unsigned short h, l;
    split_bf16(v, h, l);
    Thi[(size_t)n * K + k0 + tx] = h;
    Tlo[(size_t)n * K + k0 + tx] = l;
  }
}

// ---------------------------------------------------------------------------
// Elementwise hi/lo decompose (for layer-0 x). 4 elems/thread.
// ---------------------------------------------------------------------------
__global__ __launch_bounds__(256) void decomp_kernel(
    const float* __restrict__ X, unsigned short* __restrict__ Hi,
    unsigned short* __restrict__ Lo, int n4) {
  const int i = blockIdx.x * 256 + threadIdx.x;
  if (i >= n4) return;
  const float4 v = *reinterpret_cast<const float4*>(X + (size_t)i * 4);
  unsigned short h0, h1, h2, h3, l0, l1, l2, l3;
  split_bf16(v.x, h0, l0);
  split_bf16(v.y, h1, l1);
  split_bf16(v.z, h2, l2);
  split_bf16(v.w, h3, l3);
  uint2 hv, lv;
  hv.x = (unsigned)h0 | ((unsigned)h1 << 16);
  hv.y = (unsigned)h2 | ((unsigned)h3 << 16);
  lv.x = (unsigned)l0 | ((unsigned)l1 << 16);
  lv.y = (unsigned)l2 | ((unsigned)l3 << 16);
  *reinterpret_cast<uint2*>(Hi + (size_t)i * 4) = hv;
  *reinterpret_cast<uint2*>(Lo + (size_t)i * 4) = lv;
}

__global__ __launch_bounds__(256) void qkvbias_kernel(
    const float* __restrict__ bq, const float* __restrict__ bk,
    const float* __restrict__ bv, float* __restrict__ out) {
  const int i = blockIdx.x * 256 + threadIdx.x;
  if (i >= QKVN) return;
  out[i] = i < DM ? bq[i] : (i < 2 * DM ? bk[i - DM] : bv[i - 2 * DM]);
}

// ---------------------------------------------------------------------------
// Split-bf16 MFMA GEMM: C = Ahi@Bhi + Alo@Bhi + Ahi@Blo (+bias, opt relu)
// BK=32, double-buffered LDS, one barrier per k-tile, reg prefetch 2 ahead.
// SPLIT_OUT epilogue stages the C-tile in (reused) LDS then issues coalesced
// uint4 stores — fixes 5.4x HBM write amplification from scalar ushort stores.
// ---------------------------------------------------------------------------
template <int BM, int BN, bool RELU, bool SPLIT_OUT, bool PARTIAL>
__global__ __launch_bounds__(256) void gemm_mfma(
    const unsigned short* __restrict__ Ahi, const unsigned short* __restrict__ Alo,
    const unsigned short* __restrict__ Bhi, const unsigned short* __restrict__ Blo,
    const float* __restrict__ bias, float* __restrict__ C,
    unsigned short* __restrict__ Chi, unsigned short* __restrict__ Clo,
    int M, int N, int K) {
  constexpr int BK = 32;
  constexpr int WT_M = BM / 2;
  constexpr int WT_N = BN / 2;
  constexpr int MI = WT_M / 16;              // 2 or 4
  constexpr int NI = WT_N / 16;              // 2 or 4
  constexpr int A_IT = BM * BK / (256 * 8);  // 1 or 2
  constexpr int B_IT = BN * BK / (256 * 8);  // 1 or 2
  constexpr int SMEM_E = 4 * BK * (BM + BN);  // all four dbuf arrays, flattened

  __shared__ unsigned short smem[SMEM_E];
  unsigned short* AsH = smem;                  // [2][BM*BK]
  unsigned short* AsL = AsH + 2 * BM * BK;
  unsigned short* BsH = AsL + 2 * BM * BK;     // [2][BN*BK]
  unsigned short* BsL = BsH + 2 * BN * BK;

  const int nwg = gridDim.x * gridDim.y;
  const int orig = blockIdx.y * gridDim.x + blockIdx.x;
  const int swz = (orig & 7) * (nwg >> 3) + (orig >> 3);
  const int bx = swz % gridDim.x;
  const int by = swz / gridDim.x;

  const int tid = threadIdx.x;
  const int lane = tid & 63;
  const int wid = tid >> 6;
  const int wr = wid >> 1, wc = wid & 1;
  const int rowBase = by * BM;
  const int colBase = bx * BN;
  const int l15 = lane & 15, l4 = lane >> 4;

  const int sg_ = tid & 3;
  const int srA = tid >> 2;
  const int swg = sg_ ^ (srA & 3) ^ ((srA >> 2) & 3);

  const int Keff = K / gridDim.z;
  const int koff = blockIdx.z * Keff;

  f32x4 acc[MI][NI] = {};
  const int nt = Keff / BK;

  uint4 ahR[A_IT], alR[A_IT], bhR[B_IT], blR[B_IT];

  auto loadRegs = [&](int kt) {
    const int k0 = koff + kt * BK;
#pragma unroll
    for (int it = 0; it < A_IT; ++it) {
      const size_t base = (size_t)(rowBase + it * 64 + srA) * K + k0 + sg_ * 8;
      ahR[it] = *reinterpret_cast<const uint4*>(Ahi + base);
      alR[it] = *reinterpret_cast<const uint4*>(Alo + base);
    }
#pragma unroll
    for (int it = 0; it < B_IT; ++it) {
      const size_t base = (size_t)(colBase + it * 64 + srA) * K + k0 + sg_ * 8;
      bhR[it] = *reinterpret_cast<const uint4*>(Bhi + base);
      blR[it] = *reinterpret_cast<const uint4*>(Blo + base);
    }
  };

  auto writeLDS = [&](int buf) {
#pragma unroll
    for (int it = 0; it < A_IT; ++it) {
      const int off = buf * BM * BK + ((it * 64 + srA) << 5) + (swg << 3);
      *reinterpret_cast<uint4*>(&AsH[off]) = ahR[it];
      *reinterpret_cast<uint4*>(&AsL[off]) = alR[it];
    }
#pragma unroll
    for (int it = 0; it < B_IT; ++it) {
      const int off = buf * BN * BK + ((it * 64 + srA) << 5) + (swg << 3);
      *reinterpret_cast<uint4*>(&BsH[off]) = bhR[it];
      *reinterpret_cast<uint4*>(&BsL[off]) = blR[it];
    }
  };

  loadRegs(0);
  writeLDS(0);
  if (nt > 1) loadRegs(1);

  for (int t = 0; t < nt; ++t) {
    __syncthreads();
    const int cur = t & 1;
    if (t + 1 < nt) writeLDS(cur ^ 1);
    if (t + 2 < nt) loadRegs(t + 2);

    short8v ah[MI], al[MI], bh[NI], bl[NI];
#pragma unroll
    for (int mi = 0; mi < MI; ++mi) {
      const int r = wr * WT_M + mi * 16 + l15;
      const int g = l4 ^ (r & 3) ^ ((r >> 2) & 3);
      const int off = cur * BM * BK + (r << 5) + (g << 3);
      ah[mi] = *reinterpret_cast<const short8v*>(&AsH[off]);
      al[mi] = *reinterpret_cast<const short8v*>(&AsL[off]);
    }
#pragma unroll
    for (int ni = 0; ni < NI; ++ni) {
      const int r = wc * WT_N + ni * 16 + l15;
      const int g = l4 ^ (r & 3) ^ ((r >> 2) & 3);
      const int off = cur * BN * BK + (r << 5) + (g << 3);
      bh[ni] = *reinterpret_cast<const short8v*>(&BsH[off]);
      bl[ni] = *reinterpret_cast<const short8v*>(&BsL[off]);
    }
#pragma unroll
    for (int mi = 0; mi < MI; ++mi)
#pragma unroll
      for (int ni = 0; ni < NI; ++ni) {
        acc[mi][ni] = __builtin_amdgcn_mfma_f32_16x16x32_bf16(ah[mi], bh[ni], acc[mi][ni], 0, 0, 0);
        acc[mi][ni] = __builtin_amdgcn_mfma_f32_16x16x32_bf16(al[mi], bh[ni], acc[mi][ni], 0, 0, 0);
        acc[mi][ni] = __builtin_amdgcn_mfma_f32_16x16x32_bf16(ah[mi], bl[ni], acc[mi][ni], 0, 0, 0);
      }
  }

  if (SPLIT_OUT) {
    // stage hi/lo C tile in LDS (padded stride), then coalesced uint4 stores
    constexpr int CP = BN + 8;
    static_assert(2 * BM * CP <= SMEM_E, "epilogue staging exceeds LDS");
    unsigned short* Ch = smem;
    unsigned short* Cl = smem + BM * CP;
    __syncthreads();  // done with k-loop LDS
#pragma unroll
    for (int mi = 0; mi < MI; ++mi) {
#pragma unroll
      for (int ni = 0; ni < NI; ++ni) {
        const int colL = wc * WT_N + ni * 16 + l15;
        const float bv = bias[colBase + colL];
#pragma unroll
        for (int j = 0; j < 4; ++j) {
          const int rowL = wr * WT_M + mi * 16 + l4 * 4 + j;
          float v = acc[mi][ni][j] + bv;
          if (RELU) v = fmaxf(v, 0.f);
          unsigned short h, l;
          split_bf16(v, h, l);
          Ch[rowL * CP + colL] = h;
          Cl[rowL * CP + colL] = l;
        }
      }
    }
    __syncthreads();
    constexpr int ITERS = BM * BN / (256 * 8);
#pragma unroll
    for (int it = 0; it < ITERS; ++it) {
      const int idx = it * 256 + tid;
      const int r = idx / (BN / 8);
      const int c8 = idx % (BN / 8);
      const uint4 vh = *reinterpret_cast<const uint4*>(&Ch[r * CP + c8 * 8]);
      const uint4 vl = *reinterpret_cast<const uint4*>(&Cl[r * CP + c8 * 8]);
      const size_t g = (size_t)(rowBase + r) * N + colBase + c8 * 8;
      *reinterpret_cast<uint4*>(Chi + g) = vh;
      *reinterpret_cast<uint4*>(Clo + g) = vl;
    }
  } else {
    float* Cout = PARTIAL ? (C + (size_t)blockIdx.z * M * N) : C;
#pragma unroll
    for (int mi = 0; mi < MI; ++mi) {
#pragma unroll
      for (int ni = 0; ni < NI; ++ni) {
        const int col = colBase + wc * WT_N + ni * 16 + l15;
        const float bv = PARTIAL ? 0.f : bias[col];
#pragma unroll
        for (int j = 0; j < 4; ++j) {
          const int row = rowBase + wr * WT_M + mi * 16 + l4 * 4 + j;
          float v = acc[mi][ni][j] + bv;
          if (RELU) v = fmaxf(v, 0.f);
          Cout[(size_t)row * N + col] = v;
        }
      }
    }
  }
}

// ---------------------------------------------------------------------------
// Split-K reduce: out = part0 + part1 + bias (fp32), 4 elems/thread
// ---------------------------------------------------------------------------
__global__ __launch_bounds__(256) void redk_kernel(
    const float* __restrict__ part, const float* __restrict__ bias,
    float* __restrict__ out, int total4, int N) {
  const int i = blockIdx.x * 256 + threadIdx.x;
  if (i >= total4) return;
  const size_t idx = (size_t)i * 4;
  const int col = (int)(idx & (N - 1));
  const float4 a = *reinterpret_cast<const float4*>(part + idx);
  const float4 b = *reinterpret_cast<const float4*>(part + (size_t)ROWS * DM + idx);
  const float4 bi = *reinterpret_cast<const float4*>(bias + col);
  float4 o;
  o.x = a.x + b.x + bi.x;
  o.y = a.y + b.y + bi.y;
  o.z = a.z + b.z + bi.z;
  o.w = a.w + b.w + bi.w;
  *reinterpret_cast<float4*>(out + idx) = o;
}

// ---------------------------------------------------------------------------
// V transpose (bf16 hi/lo): qkv V-slice -> vtb[bh][d][kk]
// ---------------------------------------------------------------------------
__global__ __launch_bounds__(256) void vtxp_kernel(
    const unsigned short* __restrict__ qkvhi, const unsigned short* __restrict__ qkvlo,
    unsigned short* __restrict__ vtbhi, unsigned short* __restrict__ vtblo) {
  __shared__ unsigned short th[32][33], tl[32][33];
  const int bh = blockIdx.z;
  const int b = bh >> 3, h = bh & 7;
  const int kk0 = blockIdx.x * 32, d0 = blockIdx.y * 32;
  const int tx = threadIdx.x & 31, ty = threadIdx.x >> 5;
#pragma unroll
  for (int i = 0; i < 4; ++i) {
    const int kk = kk0 + ty + i * 8;
    const size_t src = (size_t)(b * LL + kk) * QKVN + 2 * DM + h * DHD + d0 + tx;
    th[ty + i * 8][tx] = qkvhi[src];
    tl[ty + i * 8][tx] = qkvlo[src];
  }
  __syncthreads();
#pragma unroll
  for (int i = 0; i < 4; ++i) {
    const int d = d0 + ty + i * 8;
    const size_t dst = ((size_t)bh * DHD + d) * LL + kk0 + tx;
    vtbhi[dst] = th[tx][ty + i * 8];
    vtblo[dst] = tl[tx][ty + i * 8];
  }
}

// ---------------------------------------------------------------------------
// MFMA attention: block = 16 q rows of one (b,h). 256 threads (4 waves).
// ---------------------------------------------------------------------------
constexpr int ATQ = 16;

__global__ __launch_bounds__(256) void attn_mfma(
    const unsigned short* __restrict__ qkvhi, const unsigned short* __restrict__ qkvlo,
    const unsigned short* __restrict__ vtbhi, const unsigned short* __restrict__ vtblo,
    const float* __restrict__ kernS,
    unsigned short* __restrict__ ctxhi, unsigned short* __restrict__ ctxlo) {
  const int id = blockIdx.x;
  const int w = (id & 7) * 256 + (id >> 3);  // 2048 blocks, bijective
  const int h = w & 7;
  const int qt = (w >> 3) & 31;
  const int b = w >> 8;
  const int tid = threadIdx.x;
  const int lane = tid & 63;
  const int wv = tid >> 6;
  const int l15 = lane & 15, l4 = lane >> 4;
  const int q0 = qt * ATQ;

  __shared__ float S[ATQ][521];
  __shared__ unsigned short Phi[ATQ][520];
  __shared__ unsigned short Plo[ATQ][520];
  __shared__ float sinv[ATQ];

  short8v qh[2], ql[2];
  {
    const size_t qbase = (size_t)(b * LL + q0 + l15) * QKVN + h * DHD;
#pragma unroll
    for (int ks = 0; ks < 2; ++ks) {
      qh[ks] = *reinterpret_cast<const short8v*>(qkvhi + qbase + ks * 32 + l4 * 8);
      ql[ks] = *reinterpret_cast<const short8v*>(qkvlo + qbase + ks * 32 + l4 * 8);
    }
  }

  for (int nt = 0; nt < 8; ++nt) {
    const int kk0 = wv * 128 + nt * 16;
    const size_t kbase = (size_t)(b * LL + kk0 + l15) * QKVN + DM + h * DHD;
    f32x4 acc = {};
#pragma unroll
    for (int ks = 0; ks < 2; ++ks) {
      const short8v kh = *reinterpret_cast<const short8v*>(qkvhi + kbase + ks * 32 + l4 * 8);
      const short8v kl = *reinterpret_cast<const short8v*>(qkvlo + kbase + ks * 32 + l4 * 8);
      acc = __builtin_amdgcn_mfma_f32_16x16x32_bf16(qh[ks], kh, acc, 0, 0, 0);
      acc = __builtin_amdgcn_mfma_f32_16x16x32_bf16(ql[ks], kh, acc, 0, 0, 0);
      acc = __builtin_amdgcn_mfma_f32_16x16x32_bf16(qh[ks], kl, acc, 0, 0, 0);
    }
#pragma unroll
    for (int j = 0; j < 4; ++j) {
      const int row = l4 * 4 + j;
      S[row][kk0 + l15] =
          acc[j] * 0.125f + kernS[((size_t)b * LL + q0 + row) * LL + kk0 + l15];
    }
  }
  __syncthreads();

  {
    const int r = tid >> 4, c = tid & 15;
    float m = -1e30f;
#pragma unroll
    for (int j = 0; j < 32; ++j) m = fmaxf(m, S[r][c + j * 16]);
#pragma unroll
    for (int s = 8; s; s >>= 1) m = fmaxf(m, __shfl_xor(m, s, 16));
    float sum = 0.f;
#pragma unroll
    for (int j = 0; j < 32; ++j) {
      const float e = __expf(S[r][c + j * 16] - m);
      unsigned short hh, ll;
      split_bf16(e, hh, ll);
      Phi[r][c + j * 16] = hh;
      Plo[r][c + j * 16] = ll;
      sum += e;
    }
#pragma unroll
    for (int s = 8; s; s >>= 1) sum += __shfl_xor(sum, s, 16);
    if (c == 0) sinv[r] = 1.0f / sum;
  }
  __syncthreads();

  {
    const int d0 = wv * 16;
    const size_t vbase = ((size_t)(b * NH + h) * DHD + d0 + l15) * LL;
    f32x4 acc = {};
    for (int kt = 0; kt < 16; ++kt) {
      const int kk0 = kt * 32;
      const short8v ph = *reinterpret_cast<const short8v*>(&Phi[l15][kk0 + l4 * 8]);
      const short8v pl = *reinterpret_cast<const short8v*>(&Plo[l15][kk0 + l4 * 8]);
      const short8v vh = *reinterpret_cast<const short8v*>(vtbhi + vbase + kk0 + l4 * 8);
      const short8v vl = *reinterpret_cast<const short8v*>(vtblo + vbase + kk0 + l4 * 8);
      acc = __builtin_amdgcn_mfma_f32_16x16x32_bf16(ph, vh, acc, 0, 0, 0);
      acc = __builtin_amdgcn_mfma_f32_16x16x32_bf16(pl, vh, acc, 0, 0, 0);
      acc = __builtin_amdgcn_mfma_f32_16x16x32_bf16(ph, vl, acc, 0, 0, 0);
    }
#pragma unroll
    for (int j = 0; j < 4; ++j) {
      const int row = l4 * 4 + j;
      const float o = acc[j] * sinv[row];
      unsigned short hh, ll;
      split_bf16(o, hh, ll);
      const size_t oo = (size_t)(b * LL + q0 + row) * DM + h * DHD + d0 + l15;
      ctxhi[oo] = hh;
      ctxlo[oo] = ll;
    }
  }
}

// ---------------------------------------------------------------------------
// Fused residual + LayerNorm; writes fp32 + bf16 hi/lo decomposition.
// ---------------------------------------------------------------------------
__global__ __launch_bounds__(256) void resid_ln_kernel(
    const float* __restrict__ X, const float* __restrict__ R,
    const float* __restrict__ g, const float* __restrict__ bta,
    float* __restrict__ Out, unsigned short* __restrict__ OutHi,
    unsigned short* __restrict__ OutLo) {
  const int row = blockIdx.x * 4 + (threadIdx.x >> 6);
  const int lane = threadIdx.x & 63;
  const float* x = X + (size_t)row * DM;
  const float* r = R + (size_t)row * DM;

  float v[8];
  float s = 0.f;
#pragma unroll
  for (int j = 0; j < 2; ++j) {
    const float4 a = *reinterpret_cast<const float4*>(x + lane * 8 + j * 4);
    const float4 c = *reinterpret_cast<const float4*>(r + lane * 8 + j * 4);
    v[j * 4 + 0] = a.x + c.x;
    v[j * 4 + 1] = a.y + c.y;
    v[j * 4 + 2] = a.z + c.z;
    v[j * 4 + 3] = a.w + c.w;
    s += v[j * 4 + 0] + v[j * 4 + 1] + v[j * 4 + 2] + v[j * 4 + 3];
  }
#pragma unroll
  for (int m = 1; m < 64; m <<= 1) s += __shfl_xor(s, m, 64);
  const float mean = s * (1.f / DM);
  float var = 0.f;
#pragma unroll
  for (int j = 0; j < 8; ++j) {
    const float dlt = v[j] - mean;
    var += dlt * dlt;
  }
#pragma unroll
  for (int m = 1; m < 64; m <<= 1) var += __shfl_xor(var, m, 64);
  var *= (1.f / DM);
  const float inv = 1.0f / sqrtf(var + 1e-6f);

  unsigned short hs[8], ls[8];
#pragma unroll
  for (int j = 0; j < 2; ++j) {
    const float4 gg = *reinterpret_cast<const float4*>(g + lane * 8 + j * 4);
    const float4 bb = *reinterpret_cast<const float4*>(bta + lane * 8 + j * 4);
    float4 o;
    o.x = (v[j * 4 + 0] - mean) * inv * gg.x + bb.x;
    o.y = (v[j * 4 + 1] - mean) * inv * gg.y + bb.y;
    o.z = (v[j * 4 + 2] - mean) * inv * gg.z + bb.z;
    o.w = (v[j * 4 + 3] - mean) * inv * gg.w + bb.w;
    *reinterpret_cast<float4*>(Out + (size_t)row * DM + lane * 8 + j * 4) = o;
    split_bf16(o.x, hs[j * 4 + 0], ls[j * 4 + 0]);
    split_bf16(o.y, hs[j * 4 + 1], ls[j * 4 + 1]);
    split_bf16(o.z, hs[j * 4 + 2], ls[j * 4 + 2]);
    split_bf16(o.w, hs[j * 4 + 3], ls[j * 4 + 3]);
  }
  uint4 hv, lv;
  hv.x = (unsigned)hs[0] | ((unsigned)hs[1] << 16);
  hv.y = (unsigned)hs[2] | ((unsigned)hs[3] << 16);
  hv.z = (unsigned)hs[4] | ((unsigned)hs[5] << 16);
  hv.w = (unsigned)hs[6] | ((unsigned)hs[7] << 16);
  lv.x = (unsigned)ls[0] | ((unsigned)ls[1] << 16);
  lv.y = (unsigned)ls[2] | ((unsigned)ls[3] << 16);
  lv.z = (unsigned)ls[4] | ((unsigned)ls[5] << 16);
  lv.w = (unsigned)ls[6] | ((unsigned)ls[7] << 16);
  *reinterpret_cast<uint4*>(OutHi + (size_t)row * DM + lane * 8) = hv;
  *reinterpret_cast<uint4*>(OutLo + (size_t)row * DM + lane * 8) = lv;
}

// ---------------------------------------------------------------------------
// launch
// ---------------------------------------------------------------------------
extern "C" void kernel_launch(void* const* d_in, const int* in_sizes, int n_in,
                              void* d_out, int out_size, void* d_ws, size_t ws_size,
                              hipStream_t stream) {
  const float* x_in = (const float*)d_in[0];
  const float* t = (const float*)d_in[1];
  const float* wq = (const float*)d_in[2];
  const float* bq = (const float*)d_in[3];
  const float* wk = (const float*)d_in[4];
  const float* bk = (const float*)d_in[5];
  const float* wv = (const float*)d_in[6];
  const float* bv = (const float*)d_in[7];
  const float* wo = (const float*)d_in[8];
  const float* bo = (const float*)d_in[9];
  const float* w1 = (const float*)d_in[10];
  const float* b1 = (const float*)d_in[11];
  const float* w2 = (const float*)d_in[12];
  const float* b2 = (const float*)d_in[13];
  const float* ln1g = (const float*)d_in[14];
  const float* ln1b = (const float*)d_in[15];
  const float* ln2g = (const float*)d_in[16];
  const float* ln2b = (const float*)d_in[17];
  const float* pw1 = (const float*)d_in[18];
  const float* pb1 = (const float*)d_in[19];
  const float* pw2 = (const float*)d_in[20];
  const float* pb2 = (const float*)d_in[21];
  const float* sw1 = (const float*)d_in[22];
  const float* sb1 = (const float*)d_in[23];
  const float* sw2 = (const float*)d_in[24];
  const float* sb2 = (const float*)d_in[25];
  const float* bw1 = (const float*)d_in[26];
  const float* bb1 = (const float*)d_in[27];
  const float* bw2 = (const float*)d_in[28];
  const float* bb2 = (const float*)d_in[29];

  char* wsb = (char*)d_ws;
  size_t off = 0;
  auto allocB = [&](size_t bytes) {
    char* p = wsb + off;
    off += (bytes + 255) & ~(size_t)255;
    return p;
  };
  float* tpb = (float*)allocB(ROWS * TD * 4);
  float* sgb = (float*)allocB(ROWS * TD * 4);
  float* beb = (float*)allocB(ROWS * TD * 4);
  float* kernS = (float*)allocB((size_t)BB * LL * LL * 4);
  // contiguous region: qkvhi | qkvlo | vtbhi | vtblo  (33.55 MB) — aliased by h
  unsigned short* qkvhi = (unsigned short*)allocB(
      ((size_t)ROWS * QKVN * 2 + (size_t)BB * NH * DHD * LL * 2) * 2);
  unsigned short* qkvlo = qkvhi + (size_t)ROWS * QKVN;
  unsigned short* vtbhi = qkvlo + (size_t)ROWS * QKVN;
  unsigned short* vtblo = vtbhi + (size_t)BB * NH * DHD * LL;
  float* ao = (float*)allocB((size_t)ROWS * DM * 4);
  float* xb = (float*)allocB((size_t)ROWS * DM * 4);
  float* fb = (float*)allocB((size_t)ROWS * DM * 4);
  float* xn = (float*)allocB((size_t)ROWS * DM * 4);
  float* part = (float*)allocB((size_t)2 * ROWS * DM * 4);  // split-K partials
  float* qkvbias = (float*)allocB(QKVN * 4);
  unsigned short* qkvwt_hi = (unsigned short*)allocB((size_t)QKVN * DM * 2);
  unsigned short* qkvwt_lo = (unsigned short*)allocB((size_t)QKVN * DM * 2);
  unsigned short* wot_hi = (unsigned short*)allocB((size_t)DM * DM * 2);
  unsigned short* wot_lo = (unsigned short*)allocB((size_t)DM * DM * 2);
  unsigned short* w1t_hi = (unsigned short*)allocB((size_t)FF * DM * 2);
  unsigned short* w1t_lo = (unsigned short*)allocB((size_t)FF * DM * 2);
  unsigned short* w2t_hi = (unsigned short*)allocB((size_t)DM * FF * 2);
  unsigned short* w2t_lo = (unsigned short*)allocB((size_t)DM * FF * 2);
  unsigned short* xhi = (unsigned short*)allocB((size_t)ROWS * DM * 2);
  unsigned short* xlo = (unsigned short*)allocB((size_t)ROWS * DM * 2);
  unsigned short* ctxhi = (unsigned short*)allocB((size_t)ROWS * DM * 2);
  unsigned short* ctxlo = (unsigned short*)allocB((size_t)ROWS * DM * 2);
  // h hi/lo alias over [qkvhi..vtblo] (dead by FFN1 time; 33.55 MB exact)
  unsigned short* hhi = qkvhi;
  unsigned short* hlo = hhi + (size_t)ROWS * FF;

  const float* xcur = x_in;

  for (int i = 0; i < NLAYERS; ++i) {
    td_kernel<<<dim3(16, 16), 256, 0, stream>>>(wq + (size_t)i * DM * DM, qkvwt_hi, qkvwt_lo, DM, DM);
    td_kernel<<<dim3(16, 16), 256, 0, stream>>>(wk + (size_t)i * DM * DM, qkvwt_hi + (size_t)DM * DM, qkvwt_lo + (size_t)DM * DM, DM, DM);
    td_kernel<<<dim3(16, 16), 256, 0, stream>>>(wv + (size_t)i * DM * DM, qkvwt_hi + (size_t)2 * DM * DM, qkvwt_lo + (size_t)2 * DM * DM, DM, DM);
    td_kernel<<<dim3(16, 16), 256, 0, stream>>>(wo + (size_t)i * DM * DM, wot_hi, wot_lo, DM, DM);
    td_kernel<<<dim3(16, 64), 256, 0, stream>>>(w1 + (size_t)i * DM * FF, w1t_hi, w1t_lo, DM, FF);
    td_kernel<<<dim3(64, 16), 256, 0, stream>>>(w2 + (size_t)i * FF * DM, w2t_hi, w2t_lo, FF, DM);
    qkvbias_kernel<<<(QKVN + 255) / 256, 256, 0, stream>>>(bq + i * DM, bk + i * DM, bv + i * DM, qkvbias);

    small_ffn_kernel<<<ROWS / 256, 256, 0, stream>>>(
        t, pw1 + i * TD, pb1 + i * TD, pw2 + i * TD * TD, pb2 + i * TD,
        sw1 + i * TD, sb1 + i * TD, sw2 + i * TD * TD, sb2 + i * TD,
        bw1 + i * TD, bb1 + i * TD, bw2 + i * TD * TD, bb2 + i * TD,
        tpb, sgb, beb);
    kern_kernel<<<dim3(LL / 256, LL, BB), 256, 0, stream>>>(t, tpb, sgb, beb, kernS);

    if (i == 0) {
      decomp_kernel<<<(ROWS * DM / 4 + 255) / 256, 256, 0, stream>>>(x_in, xhi, xlo, ROWS * DM / 4);
    }

    // QKV fused GEMM -> split bf16 output. grid 12x64 = 768 blocks.
    gemm_mfma<64, 128, false, true, false><<<dim3(QKVN / 128, ROWS / 64), 256, 0, stream>>>(
        xhi, xlo, qkvwt_hi, qkvwt_lo, qkvbias, nullptr, qkvhi, qkvlo, ROWS, QKVN, DM);

    vtxp_kernel<<<dim3(LL / 32, DHD / 32, BB * NH), 256, 0, stream>>>(
        qkvhi, qkvlo, vtbhi, vtblo);

    attn_mfma<<<dim3(BB * NH * (LL / ATQ)), 256, 0, stream>>>(
        qkvhi, qkvlo, vtbhi, vtblo, kernS, ctxhi, ctxlo);

    // O projection: grid 8x64 = 512 blocks
    gemm_mfma<64, 64, false, false, false><<<dim3(DM / 64, ROWS / 64), 256, 0, stream>>>(
        ctxhi, ctxlo, wot_hi, wot_lo, bo + i * DM, ao, nullptr, nullptr, ROWS, DM, DM);

    resid_ln_kernel<<<ROWS / 4, 256, 0, stream>>>(
        xcur, ao, ln1g + i * DM, ln1b + i * DM, xb, xhi, xlo);

    // FFN1 (relu, split bf16 out): grid 16x64 = 1024 blocks
    gemm_mfma<64, 128, true, true, false><<<dim3(FF / 128, ROWS / 64), 256, 0, stream>>>(
        xhi, xlo, w1t_hi, w1t_lo, b1 + i * FF, nullptr, hhi, hlo, ROWS, FF, DM);

    // FFN2: split-K=2, grid 8x64x2 = 1024 blocks, then reduce (+bias)
    gemm_mfma<64, 64, false, false, true><<<dim3(DM / 64, ROWS / 64, 2), 256, 0, stream>>>(
        hhi, hlo, w2t_hi, w2t_lo, nullptr, part, nullptr, nullptr, ROWS, DM, FF);
    redk_kernel<<<(ROWS * DM / 4 + 255) / 256, 256, 0, stream>>>(
        part, b2 + i * DM, fb, ROWS * DM / 4, DM);

    float* ln2_out = (i == NLAYERS - 1) ? (float*)d_out : xn;
    resid_ln_kernel<<<ROWS / 4, 256, 0, stream>>>(
        xb, fb, ln2g + i * DM, ln2b + i * DM, ln2_out, xhi, xlo);

    xcur = xn;
  }
}